// Round 9
// baseline (863.931 us; speedup 1.0000x reference)
//
#include <hip/hip_runtime.h>

// GATClassifier on MI355X — round 18: kernel-count surgery. (1) score2 fused
// into sg2 -> sgf_k: wave-0 per-node MFMA scores (contiguous Y rows x WE2),
// softmax + aggregation with Y L1-hot; kills 4 dispatches + SA round-trip +
// ~134MB Y re-read. (2) segalpha fused into g1b -> sga_g1_k (sg2-style).
// (3) us1+an64 merged (usan_k). Flash/proj/y3/nft/readout frozen (r17).

#define NSd 8192
#define NNd 16384
#define NEd 131072
#define KSPLIT 8

typedef unsigned short u16;
typedef unsigned int   u32;
typedef short bf16x8 __attribute__((ext_vector_type(8)));
typedef float f32x4  __attribute__((ext_vector_type(4)));
typedef float f32x16 __attribute__((ext_vector_type(16)));

__device__ __forceinline__ float bf2f(u16 u){ return __uint_as_float(((u32)u) << 16); }
__device__ __forceinline__ u16 f2bf(float f){
  u32 u = __float_as_uint(f);
  u += 0x7fffu + ((u >> 16) & 1u);
  return (u16)(u >> 16);
}
__device__ __forceinline__ u32 pkbf(float a, float b){
  u32 r;
  asm("v_cvt_pk_bf16_f32 %0, %1, %2" : "=v"(r) : "v"(a), "v"(b));
  return r;
}
__device__ __forceinline__ void pl32swap(u32& a, u32& b){
  auto r = __builtin_amdgcn_permlane32_swap(a, b, false, false);
  a = r[0]; b = r[1];
}
__device__ __forceinline__ float eluf(float x){ return x > 0.f ? x : expm1f(x); }
__device__ __forceinline__ float leaky(float x){ return x > 0.f ? x : 0.2f * x; }
__device__ __forceinline__ float ldin(const void* p, size_t i, int fl){
  return fl ? bf2f(((const u16*)p)[i]) : ((const float*)p)[i];
}
__device__ __forceinline__ void lse_merge(float& m, float& z, float om, float oz){
  float M = fmaxf(m, om);
  z = z * __expf(m - M) + oz * __expf(om - M);
  m = M;
}

// ------------------------- workspace layout (bytes) -------------------------
static constexpr size_t OFF_WF   = 0;
static constexpr size_t OFF_CB   = 1529600;
static constexpr size_t OFF_U    = 1584896;      // 131072*64 bf16 (Ub)
static constexpr size_t OFF_W1B  = 18362112;     // W1T bf16
static constexpr size_t OFF_W2B  = 18427648;     // W2T bf16
static constexpr size_t OFF_WE2B = 18951936;     // 16*512 bf16 (padded WE2)
static constexpr size_t OFF_WE1B = 18968320;     // 16*64 bf16 (padded WE1)
static constexpr size_t OFF_AL1  = 35139328;     // 131072*8 f32 (by CSR pos)
static constexpr size_t OFF_SA   = 39333632;     // 131072*8 f32 (fallback scores)
static constexpr size_t OFF_HNA  = 43527936;     // 16384*512 bf16 (16.78MB)
static constexpr size_t OFF_AN2  = 60305152;     // 16384*16 f32 (in freed HNA tail)
static constexpr size_t OFF_DEG  = 77082368;
static constexpr size_t OFF_RP   = 77147904;
static constexpr size_t OFF_FILL = 77213696;
static constexpr size_t OFF_CIDX = 77279232;
static constexpr size_t OFF_RBIG = 77803520;     // pacc | G1b | HNB[0,16.78M)+G2[16.78,33.55M)
static constexpr size_t OFF_T    = 111357952;    // 32MB union (Y pair in layer 2)
static constexpr size_t OFF_XCAT = 144912384;
static constexpr size_t OFF_FLAG = 144977920;
static constexpr size_t WS_NEED  = 144978176;

static constexpr size_t T_X1A = 0;
static constexpr size_t T_X2A = 2097152;
static constexpr size_t T_HN0 = 4194304;
static constexpr size_t T_PZ  = 4194304;         // pz during flash (hn0 slot, free then)
static constexpr size_t T_AN1 = 8388608;
static constexpr size_t T_S   = 9437184;
static constexpr size_t T_Y   = 0;               // 32768*512 bf16 (slice PAIR, full T)
static constexpr size_t T_Y1G = 0;               // 16*64 f32 (readout, after slices)
static constexpr size_t R_G2  = 16777216;        // RBIG-relative, 2048*8*512 bf16 (exact fit)

static constexpr int WO_PROJ = 0,      WO_W1 = 16384;
static constexpr int WO_AL1 = 49152,   WO_AR1 = 49664,  WO_AE1 = 50176;
static constexpr int WO_W2  = 50688;
static constexpr int WO_AL2 = 312832,  WO_AR2 = 313344, WO_AE2 = 313856;
static constexpr int WO_B1G = 314368,  WO_B1B = 315392;
static constexpr int WO_F1W = 316416,  WO_F1B = 381952;
static constexpr int WO_B2G = 382016,  WO_B2B = 382080;
static constexpr int WO_F2W = 382144,  WO_F2B = 382336;
static constexpr int WO_END = 382339;

static constexpr int CB_WC1 = 0;
static constexpr int CB_WE1 = 1024;
static constexpr int CB_WC2 = 1536;   // rows 0..7 = W2*(al2-ae2)
static constexpr int CB_WE2 = 9728;
static constexpr int CB_END = 13824;

// ------------------------------- dtype detect -------------------------------
__global__ __launch_bounds__(256) void detect_k(const u16* __restrict__ p, int* __restrict__ flag){
  __shared__ int bad;
  if (threadIdx.x == 0) bad = 0;
  __syncthreads();
  int b = 0;
  for (int i = threadIdx.x; i < 1024; i += 256){
    float f = bf2f(p[i]);
    if (!(fabsf(f) <= 100.f)) b++;
  }
  atomicAdd(&bad, b);
  __syncthreads();
  if (threadIdx.x == 0) *flag = (bad == 0) ? 1 : 0;
}

struct P17 { const void* p[17]; };

__global__ __launch_bounds__(256) void convw_k(P17 ps, float* __restrict__ wf, const int* __restrict__ flagp){
  const int i = blockIdx.x * 256 + threadIdx.x;
  if (i >= WO_END) return;
  const int fl = *flagp;
  const int ends[17] = {16384,49152,49664,50176,50688,312832,313344,313856,314368,
                        315392,316416,381952,382016,382080,382144,382336,382339};
  int seg = 0;
  while (i >= ends[seg]) seg++;
  const int start = seg ? ends[seg-1] : 0;
  wf[i] = ldin(ps.p[seg], i - start, fl);
}

// merged: W1T + W2T transposes, combos, WE pads — one dispatch after convw
__global__ __launch_bounds__(256) void wprep_k(const float* __restrict__ wf, u16* __restrict__ w1t,
                                               u16* __restrict__ w2t, float* __restrict__ cb,
                                               u16* __restrict__ we2b, u16* __restrict__ we1b){
  const int i = blockIdx.x * 256 + threadIdx.x;
  if (i < 32768){
    const int c = i >> 6, k = i & 63;
    w1t[i] = f2bf(wf[WO_W1 + k * 512 + c]);
    return;
  }
  if (i < 294912){
    const int j = i - 32768;
    const int c = j >> 9, k = j & 511;
    w2t[j] = f2bf(wf[WO_W2 + k * 512 + c]);
    return;
  }
  const int j = i - 294912;
  if (j >= CB_END + 4096 + 512) return;
  if (j >= CB_END + 4096){ we1b[512 + (j - CB_END - 4096)] = 0; return; }
  if (j >= CB_END){ we2b[4096 + (j - CB_END)] = 0; return; }
  float acc = 0.f;
  if (j < 1024){
    const int o = j >> 6, d = j & 63, h = o & 7;
    const float* a = wf + ((o >> 3) ? WO_AR1 : WO_AL1) + h * 64;
    for (int dp = 0; dp < 64; dp++) acc += wf[WO_W1 + d * 512 + h * 64 + dp] * a[dp];
    cb[CB_WC1 + j] = acc;
  } else if (j < 1536){
    const int jj = j - 1024, h = jj >> 6, d = jj & 63;
    for (int dp = 0; dp < 64; dp++) acc += wf[WO_W1 + d * 512 + h * 64 + dp] * wf[WO_AE1 + h * 64 + dp];
    cb[CB_WE1 + jj] = acc;
    we1b[jj] = f2bf(acc);
  } else if (j < 9728){
    const int jj = j - 1536, o = jj >> 9, c = jj & 511, h = o & 7;
    for (int dp = 0; dp < 64; dp++){
      const float av = (o >> 3) ? wf[WO_AR2 + h * 64 + dp]
                                : (wf[WO_AL2 + h * 64 + dp] - wf[WO_AE2 + h * 64 + dp]);
      acc += wf[WO_W2 + c * 512 + h * 64 + dp] * av;
    }
    cb[CB_WC2 + jj] = acc;
  } else {
    const int jj = j - 9728, h = jj >> 9, c = jj & 511;
    for (int dp = 0; dp < 64; dp++) acc += wf[WO_W2 + c * 512 + h * 64 + dp] * wf[WO_AE2 + h * 64 + dp];
    cb[CB_WE2 + jj] = acc;
    we2b[jj] = f2bf(acc);
  }
}

// --------------------------- flash alignment (MFMA) -------------------------
// Swapped-operand 32x32x16 flash (exact round-11 body, frozen).
__global__ __launch_bounds__(256) void flash_mfma_k(const void* __restrict__ Qp, const void* __restrict__ Kp,
                                                    const int* __restrict__ flagp, float* __restrict__ pacc,
                                                    float* __restrict__ pz){
  const int fl = *flagp;
  __shared__ __align__(16) u16 Ks[2][32][64];   // row-major, 16B slots XOR (row&7)
  __shared__ __align__(16) u16 Kt[2][64][40];   // transposed [d][kc], pitch 40 (16B aligned)
  const int t = threadIdx.x;
  const int w = t >> 6, l = t & 63;
  const int hi = l >> 5, ql = l & 31;
  const int q0 = blockIdx.x * 128;
  const int kbeg = blockIdx.y * 1024;
  // staging roles
  const int sr = t & 31, scg = t >> 5;   // Ks: row sr, cols scg*8..+7
  const int kp = t & 15, dq = t >> 4;    // Kt: k-rows 2kp,2kp+1, d 4dq..+3

  // Q fragments (B operand), held in registers for the whole kernel
  bf16x8 bq[4];
  {
    const int qrow = q0 + w * 32 + ql;
    if (fl){
      const u16* qp = (const u16*)Qp + (size_t)qrow * 64 + hi * 8;
      #pragma unroll
      for (int s = 0; s < 4; s++) bq[s] = *(const bf16x8*)(qp + s * 16);
    } else {
      const float* qp = (const float*)Qp + (size_t)qrow * 64 + hi * 8;
      #pragma unroll
      for (int s = 0; s < 4; s++){
        union { u32 w_[4]; bf16x8 v; } u;
        #pragma unroll
        for (int i = 0; i < 4; i++) u.w_[i] = pkbf(qp[s*16 + 2*i], qp[s*16 + 2*i + 1]);
        bq[s] = u.v;
      }
    }
  }

  f32x16 accO0, accO1;
  #pragma unroll
  for (int i = 0; i < 16; i++){ accO0[i] = 0.f; accO1[i] = 0.f; }
  float lsum = 0.f;

  // prologue: stage tile 0 -> buffer 0
  {
    const int kr = kbeg;
    if (fl){
      const u16* kb = (const u16*)Kp + (size_t)kr * 64;
      const uint4 s0 = *(const uint4*)(kb + (size_t)sr * 64 + scg * 8);
      const uint2 a0 = *(const uint2*)(kb + (size_t)(2*kp) * 64 + dq * 4);
      const uint2 b0 = *(const uint2*)(kb + (size_t)(2*kp + 1) * 64 + dq * 4);
      *(uint4*)((char*)&Ks[0][sr][0] + ((scg * 16) ^ ((sr & 7) << 4))) = s0;
      const u16* pa = (const u16*)&a0; const u16* pb = (const u16*)&b0;
      #pragma unroll
      for (int i = 0; i < 4; i++)
        *(u32*)&Kt[0][4*dq + i][2*kp] = (u32)pa[i] | ((u32)pb[i] << 16);
    } else {
      const float* kf = (const float*)Kp + (size_t)kr * 64;
      const float4 f0 = *(const float4*)(kf + (size_t)sr * 64 + scg * 8);
      const float4 f1 = *(const float4*)(kf + (size_t)sr * 64 + scg * 8 + 4);
      const float4 fa = *(const float4*)(kf + (size_t)(2*kp) * 64 + dq * 4);
      const float4 fb = *(const float4*)(kf + (size_t)(2*kp + 1) * 64 + dq * 4);
      union { u32 w_[4]; uint4 q; } uu;
      uu.w_[0] = pkbf(f0.x, f0.y); uu.w_[1] = pkbf(f0.z, f0.w);
      uu.w_[2] = pkbf(f1.x, f1.y); uu.w_[3] = pkbf(f1.z, f1.w);
      *(uint4*)((char*)&Ks[0][sr][0] + ((scg * 16) ^ ((sr & 7) << 4))) = uu.q;
      const float* faf = &fa.x; const float* fbf = &fb.x;
      #pragma unroll
      for (int i = 0; i < 4; i++)
        *(u32*)&Kt[0][4*dq + i][2*kp] = pkbf(faf[i], fbf[i]);
    }
  }

  for (int it = 0; it < 32; it++){
    const int cur = it & 1;
    __syncthreads();   // staged tile `it` visible; previous compute done

    // T14: issue next-tile global loads early (latency hides under compute)
    uint4 nKs; uint2 nKa, nKb;
    float4 nKsf0, nKsf1, nKaf, nKbf;
    const bool nx = (it + 1 < 32);
    if (nx){
      const int kr = kbeg + (it + 1) * 32;
      if (fl){
        const u16* kb = (const u16*)Kp + (size_t)kr * 64;
        nKs = *(const uint4*)(kb + (size_t)sr * 64 + scg * 8);
        nKa = *(const uint2*)(kb + (size_t)(2*kp) * 64 + dq * 4);
        nKb = *(const uint2*)(kb + (size_t)(2*kp + 1) * 64 + dq * 4);
      } else {
        const float* kf = (const float*)Kp + (size_t)kr * 64;
        nKsf0 = *(const float4*)(kf + (size_t)sr * 64 + scg * 8);
        nKsf1 = *(const float4*)(kf + (size_t)sr * 64 + scg * 8 + 4);
        nKaf  = *(const float4*)(kf + (size_t)(2*kp) * 64 + dq * 4);
        nKbf  = *(const float4*)(kf + (size_t)(2*kp + 1) * 64 + dq * 4);
      }
    }

    // ---- S^T = K . Q^T over this 32-k-col tile ----
    f32x16 accS;
    #pragma unroll
    for (int i = 0; i < 16; i++) accS[i] = 0.f;
    #pragma unroll
    for (int s = 0; s < 4; s++){
      const int byo = (s * 32 + hi * 16) ^ ((ql & 7) << 4);
      const bf16x8 a = *(const bf16x8*)((const char*)&Ks[cur][ql][0] + byo);
      accS = __builtin_amdgcn_mfma_f32_32x32x16_bf16(a, bq[s], accS, 0, 0, 0);
    }
    // p = exp(s-32) = exp2(s*log2e - 46.166); lane-local denominator
    float p[16];
    #pragma unroll
    for (int r = 0; r < 16; r++) p[r] = exp2f(fmaf(accS[r], 1.44269504f, -46.1662413f));
    {
      const float s0 = (p[0] + p[1]) + (p[2] + p[3]);
      const float s1 = (p[4] + p[5]) + (p[6] + p[7]);
      const float s2 = (p[8] + p[9]) + (p[10] + p[11]);
      const float s3 = (p[12] + p[13]) + (p[14] + p[15]);
      lsum += (s0 + s1) + (s2 + s3);
    }
    // in-register P -> bf16 A-fragments (T12: cvt_pk + permlane32_swap)
    u32 pk_[8];
    #pragma unroll
    for (int j = 0; j < 4; j++){
      pk_[2*j]     = pkbf(p[4*j],     p[4*j + 1]);
      pk_[2*j + 1] = pkbf(p[4*j + 2], p[4*j + 3]);
    }
    pl32swap(pk_[0], pk_[2]); pl32swap(pk_[1], pk_[3]);
    pl32swap(pk_[4], pk_[6]); pl32swap(pk_[5], pk_[7]);
    union { u32 w_[4]; bf16x8 v; } ua, ub;
    ua.w_[0] = pk_[0]; ua.w_[1] = pk_[1]; ua.w_[2] = pk_[2]; ua.w_[3] = pk_[3];
    ub.w_[0] = pk_[4]; ub.w_[1] = pk_[5]; ub.w_[2] = pk_[6]; ub.w_[3] = pk_[7];
    // ---- O += P V ----
    {
      const u16* kt0 = &Kt[cur][ql][hi * 8];
      accO0 = __builtin_amdgcn_mfma_f32_32x32x16_bf16(ua.v, *(const bf16x8*)kt0, accO0, 0, 0, 0);
      accO0 = __builtin_amdgcn_mfma_f32_32x32x16_bf16(ub.v, *(const bf16x8*)(kt0 + 16), accO0, 0, 0, 0);
      const u16* kt1 = &Kt[cur][32 + ql][hi * 8];
      accO1 = __builtin_amdgcn_mfma_f32_32x32x16_bf16(ua.v, *(const bf16x8*)kt1, accO1, 0, 0, 0);
      accO1 = __builtin_amdgcn_mfma_f32_32x32x16_bf16(ub.v, *(const bf16x8*)(kt1 + 16), accO1, 0, 0, 0);
    }

    // store staged next tile into the other buffer (vmcnt lands here)
    if (nx){
      char* kd = (char*)&Ks[cur ^ 1][sr][0];
      const int byo = (scg * 16) ^ ((sr & 7) << 4);
      if (fl){
        *(uint4*)(kd + byo) = nKs;
        const u16* pa = (const u16*)&nKa; const u16* pb = (const u16*)&nKb;
        #pragma unroll
        for (int i = 0; i < 4; i++)
          *(u32*)&Kt[cur ^ 1][4*dq + i][2*kp] = (u32)pa[i] | ((u32)pb[i] << 16);
      } else {
        union { u32 w_[4]; uint4 q; } uu;
        uu.w_[0] = pkbf(nKsf0.x, nKsf0.y); uu.w_[1] = pkbf(nKsf0.z, nKsf0.w);
        uu.w_[2] = pkbf(nKsf1.x, nKsf1.y); uu.w_[3] = pkbf(nKsf1.z, nKsf1.w);
        *(uint4*)(kd + byo) = uu.q;
        const float* faf = &nKaf.x; const float* fbf = &nKbf.x;
        #pragma unroll
        for (int i = 0; i < 4; i++)
          *(u32*)&Kt[cur ^ 1][4*dq + i][2*kp] = pkbf(faf[i], fbf[i]);
      }
    }
  }

  // epilogue: O rows m = (r&3)+8*(r>>2)+4*hi; cols = 32*nt + ql
  const float zq = lsum + __shfl_xor(lsum, 32);
  const int rowb = q0 + w * 32;
  #pragma unroll
  for (int r = 0; r < 16; r++){
    const int m = (r & 3) + 8 * (r >> 2) + 4 * hi;
    float* pr = pacc + ((size_t)blockIdx.y * NSd + rowb + m) * 64;
    pr[ql]      = accO0[r];
    pr[32 + ql] = accO1[r];
  }
  if (hi == 0) pz[blockIdx.y * NSd + rowb + ql] = zq;
}

__global__ __launch_bounds__(256) void flash_merge_k(const float* __restrict__ pacc,
                                                     const float* __restrict__ pz, float* __restrict__ outp){
  const int t = threadIdx.x;
  const int r = blockIdx.x * 4 + (t >> 6);
  const int d = t & 63;
  float Zt = 0.f, v = 0.f;
  #pragma unroll
  for (int s = 0; s < KSPLIT; s++){
    Zt += pz[s * NSd + r];
    v  += pacc[((size_t)s * NSd + r) * 64 + d];
  }
  outp[(size_t)r * 64 + d] = v / Zt;
}

// ------------------------------- projection ---------------------------------
__global__ __launch_bounds__(256) void proj_k(const void* __restrict__ nbd1, const void* __restrict__ nbd2,
                                              const float* __restrict__ x1a, const float* __restrict__ x2a,
                                              const float* __restrict__ wf, float* __restrict__ hn0,
                                              const int* __restrict__ flagp){
  const int fl = *flagp;
  __shared__ float At[64][65], Bt[64][65];
  const int t = threadIdx.x, tx = t & 15, ty = t >> 4;
  const int m0 = blockIdx.x * 64;
  float acc[4][4] = {{0.f}};
  for (int kt = 0; kt < 256; kt += 64){
    __syncthreads();
    {
      const int i = t >> 2, c0 = (t & 3) * 16;
      const int mrow = m0 + i;
      const int side = mrow < NSd;
      const int mr = side ? mrow : mrow - NSd;
      const void* nb = side ? nbd1 : nbd2;
      const float* xa = side ? x1a : x2a;
      const int seg = kt >> 6;
      for (int c = 0; c < 16; c++){
        const int kk = c0 + c;
        const float nv = ldin(nb, (size_t)mr * 64 + kk, fl);
        const float av = xa[(size_t)mr * 64 + kk];
        At[i][kk] = (seg == 0) ? nv : (seg == 1) ? av : (seg == 2) ? (nv - av) : (nv * av);
      }
      const int kk = t >> 2;
      for (int c = 0; c < 16; c++) Bt[kk][c0 + c] = wf[WO_PROJ + (kt + kk) * 64 + c0 + c];
    }
    __syncthreads();
    #pragma unroll
    for (int k = 0; k < 64; k++){
      float a0 = At[ty*4+0][k], a1 = At[ty*4+1][k], a2 = At[ty*4+2][k], a3 = At[ty*4+3][k];
      float b0 = Bt[k][tx*4+0], b1 = Bt[k][tx*4+1], b2 = Bt[k][tx*4+2], b3 = Bt[k][tx*4+3];
      acc[0][0] = fmaf(a0,b0,acc[0][0]); acc[0][1] = fmaf(a0,b1,acc[0][1]); acc[0][2] = fmaf(a0,b2,acc[0][2]); acc[0][3] = fmaf(a0,b3,acc[0][3]);
      acc[1][0] = fmaf(a1,b0,acc[1][0]); acc[1][1] = fmaf(a1,b1,acc[1][1]); acc[1][2] = fmaf(a1,b2,acc[1][2]); acc[1][3] = fmaf(a1,b3,acc[1][3]);
      acc[2][0] = fmaf(a2,b0,acc[2][0]); acc[2][1] = fmaf(a2,b1,acc[2][1]); acc[2][2] = fmaf(a2,b2,acc[2][2]); acc[2][3] = fmaf(a2,b3,acc[2][3]);
      acc[3][0] = fmaf(a3,b0,acc[3][0]); acc[3][1] = fmaf(a3,b1,acc[3][1]); acc[3][2] = fmaf(a3,b2,acc[3][2]); acc[3][3] = fmaf(a3,b3,acc[3][3]);
    }
  }
  #pragma unroll
  for (int i = 0; i < 4; i++)
    #pragma unroll
    for (int j = 0; j < 4; j++)
      hn0[(size_t)(m0 + ty*4 + i) * 64 + tx*4 + j] = fmaxf(acc[i][j], 0.f);
}

// ---------------- merged U build + AN1 combos (grid branch) -----------------
__global__ __launch_bounds__(256) void usan_k(const void* __restrict__ ebd, const float* __restrict__ hn0,
                                              const int* __restrict__ src, u16* __restrict__ Ub,
                                              const float* __restrict__ wc, float* __restrict__ an,
                                              const int* __restrict__ flagp){
  const int b = blockIdx.x, t = threadIdx.x;
  if (b < 8192){
    const int fl = *flagp;
    const int id = b * 256 + t;
    const int e = id >> 4, q = id & 15, d0 = q * 4;
    const int sn = src[e];
    float ev[4];
    if (fl){
      const uint2 u = *(const uint2*)((const u16*)ebd + (size_t)e * 64 + d0);
      ev[0] = bf2f((u16)(u.x & 0xffffu)); ev[1] = bf2f((u16)(u.x >> 16));
      ev[2] = bf2f((u16)(u.y & 0xffffu)); ev[3] = bf2f((u16)(u.y >> 16));
    } else {
      const float4 f = *(const float4*)((const float*)ebd + (size_t)e * 64 + d0);
      ev[0] = f.x; ev[1] = f.y; ev[2] = f.z; ev[3] = f.w;
    }
    const float4 hv = *(const float4*)(hn0 + (size_t)sn * 64 + d0);
    ushort4 o;
    o.x = f2bf(ev[0] + hv.x); o.y = f2bf(ev[1] + hv.y);
    o.z = f2bf(ev[2] + hv.z); o.w = f2bf(ev[3] + hv.w);
    *(ushort4*)(Ub + (size_t)e * 64 + d0) = o;
  } else {
    const int id = (b - 8192) * 256 + t;   // < 262144
    const int n = id >> 4, o = id & 15;
    const float* row = hn0 + (size_t)n * 64;
    const float* wp = wc + o * 64;
    float acc = 0.f;
    for (int k = 0; k < 64; k += 4){
      const float4 r4 = *(const float4*)(row + k);
      const float4 w4 = *(const float4*)(wp + k);
      acc += r4.x*w4.x + r4.y*w4.y + r4.z*w4.z + r4.w*w4.w;
    }
    an[id] = acc;
  }
}

// AN2 tiled: 64 nodes/block, WC2 staged in LDS; HNA is bf16
__global__ __launch_bounds__(256) void anw_k(const u16* __restrict__ HNA, const float* __restrict__ wc,
                                             float* __restrict__ an){
  __shared__ float W[16][516];
  const int t = threadIdx.x;
  for (int i = t; i < 8192; i += 256) W[i >> 9][i & 511] = wc[i];
  __syncthreads();
  const int node = blockIdx.x * 64 + (t >> 2);
  const int cb0 = (t & 3) * 4;
  const u16* row = HNA + (size_t)node * 512;
  float acc[4] = {0.f, 0.f, 0.f, 0.f};
  for (int k = 0; k < 512; k += 4){
    const uint2 u = *(const uint2*)(row + k);
    const float r0 = bf2f((u16)(u.x & 0xffffu)), r1 = bf2f((u16)(u.x >> 16));
    const float r2 = bf2f((u16)(u.y & 0xffffu)), r3 = bf2f((u16)(u.y >> 16));
    #pragma unroll
    for (int j = 0; j < 4; j++){
      const float* wr = &W[cb0 + j][k];
      acc[j] += r0 * wr[0] + r1 * wr[1] + r2 * wr[2] + r3 * wr[3];
    }
  }
  #pragma unroll
  for (int j = 0; j < 4; j++) an[node * 16 + cb0 + j] = acc[j];
}

// score1: layer-1 raw scores via MFMA — S[pos][h] = leaky(AN1 + ebd.WE1)
__global__ __launch_bounds__(256) void score1_k(const void* __restrict__ ebd, const u16* __restrict__ we1b,
                                                const float* __restrict__ an, const int* __restrict__ src,
                                                const int* __restrict__ dst, const int* __restrict__ cidx,
                                                float* __restrict__ S, const int* __restrict__ flagp){
  __shared__ int Se[64], De[64], Ee[64];
  const int t = threadIdx.x;
  const int w = t >> 6, lane = t & 63;
  const int col = lane & 15, quad = lane >> 4;
  const int p0 = blockIdx.x * 64;
  if (t < 64){ const int e = cidx[p0 + t]; Ee[t] = e; Se[t] = src[e]; De[t] = dst[e]; }
  __syncthreads();
  const int fl = *flagp;
  const int ea = Ee[w*16 + col];
  bf16x8 a0, a1;
  if (fl){
    const u16* ap = (const u16*)ebd + (size_t)ea * 64;
    a0 = *(const bf16x8*)(ap + quad*8);
    a1 = *(const bf16x8*)(ap + 32 + quad*8);
  } else {
    const float* ap = (const float*)ebd + (size_t)ea * 64;
    union { u32 w_[4]; bf16x8 v; } u0, u1;
    #pragma unroll
    for (int i = 0; i < 4; i++){
      u0.w_[i] = pkbf(ap[quad*8 + 2*i],      ap[quad*8 + 2*i + 1]);
      u1.w_[i] = pkbf(ap[32 + quad*8 + 2*i], ap[32 + quad*8 + 2*i + 1]);
    }
    a0 = u0.v; a1 = u1.v;
  }
  const u16* brow = we1b + (size_t)col * 64;
  const bf16x8 b0 = *(const bf16x8*)(brow + quad*8);
  const bf16x8 b1 = *(const bf16x8*)(brow + 32 + quad*8);
  f32x4 acc = (f32x4){0.f, 0.f, 0.f, 0.f};
  acc = __builtin_amdgcn_mfma_f32_16x16x32_bf16(a0, b0, acc, 0, 0, 0);
  acc = __builtin_amdgcn_mfma_f32_16x16x32_bf16(a1, b1, acc, 0, 0, 0);
  if (col < 8){
    #pragma unroll
    for (int i = 0; i < 4; i++){
      const int rl = w*16 + quad*4 + i;
      S[(size_t)(p0 + rl) * 8 + col] = leaky(an[Se[rl]*16 + col] + acc[i] + an[De[rl]*16 + 8 + col]);
    }
  }
}

// fused layer-1 segment softmax + G1 aggregation — block per node
__global__ __launch_bounds__(256) void sga_g1_k(const float* __restrict__ S, const int* __restrict__ rp,
                                                const int* __restrict__ cidx, const u16* __restrict__ Ub,
                                                float* __restrict__ AL, u16* __restrict__ G1b){
  __shared__ float sc[64][8];
  __shared__ float mh[8], rzh[8];
  const int n = blockIdx.x, t = threadIdx.x;
  const int beg = rp[n], end = rp[n + 1], m = end - beg;
  const bool small = (m <= 64);
  {
    const int h = t >> 5, l32 = t & 31;
    float mm = -1e30f, zz = 0.f;
    for (int i = l32; i < m; i += 32)
      lse_merge(mm, zz, S[(size_t)(beg + i) * 8 + h], 1.f);
    #pragma unroll
    for (int off = 1; off < 32; off <<= 1){
      const float om = __shfl_xor(mm, off), oz = __shfl_xor(zz, off);
      lse_merge(mm, zz, om, oz);
    }
    if (l32 == 0){ mh[h] = mm; rzh[h] = 1.f / fmaxf(zz, 1e-9f); }
  }
  __syncthreads();
  for (int idx = t; idx < m * 8; idx += 256){
    const int i = idx >> 3, h = idx & 7;
    const float al = __expf(S[(size_t)(beg + i) * 8 + h] - mh[h]) * rzh[h];
    AL[(size_t)(beg + i) * 8 + h] = al;
    if (small) sc[i][h] = al;
  }
  __syncthreads();
  const int d = t & 63, hh = t >> 6;
  float a0 = 0.f, a1 = 0.f;
  for (int i = 0; i < m; i++){
    const int e = cidx[beg + i];
    const float uv = bf2f(Ub[(size_t)e * 64 + d]);
    float al0, al1;
    if (small){ al0 = sc[i][hh]; al1 = sc[i][hh + 4]; }
    else { al0 = AL[(size_t)(beg + i) * 8 + hh]; al1 = AL[(size_t)(beg + i) * 8 + hh + 4]; }
    a0 = fmaf(al0, uv, a0);
    a1 = fmaf(al1, uv, a1);
  }
  G1b[(size_t)(n * 8 + hh)     * 64 + d] = f2bf(a0);
  G1b[(size_t)(n * 8 + hh + 4) * 64 + d] = f2bf(a1);
}

// nft1 MFMA — HNA stored bf16
__global__ __launch_bounds__(256) void nft1m_k(const u16* __restrict__ G1b, const u16* __restrict__ W1T,
                                               u16* __restrict__ HNA){
  const int t = threadIdx.x;
  const int w = t >> 6, lane = t & 63;
  const int col = lane & 15, quad = lane >> 4;
  const int h = blockIdx.y;
  const int nl0 = blockIdx.x * 32;
  const int mt = (w & 1) * 16;
  const int nb = (w >> 1) * 2;
  const u16* arow = G1b + ((size_t)(nl0 + mt + col) * 8 + h) * 64;
  const bf16x8 a0 = *(const bf16x8*)(arow + quad*8);
  const bf16x8 a1 = *(const bf16x8*)(arow + 32 + quad*8);
  #pragma unroll
  for (int nn = 0; nn < 2; nn++){
    const int nt = nb + nn;
    const u16* brow = W1T + (size_t)(h*64 + nt*16 + col) * 64;
    const bf16x8 b0 = *(const bf16x8*)(brow + quad*8);
    const bf16x8 b1 = *(const bf16x8*)(brow + 32 + quad*8);
    f32x4 acc = (f32x4){0.f, 0.f, 0.f, 0.f};
    acc = __builtin_amdgcn_mfma_f32_16x16x32_bf16(a0, b0, acc, 0, 0, 0);
    acc = __builtin_amdgcn_mfma_f32_16x16x32_bf16(a1, b1, acc, 0, 0, 0);
    #pragma unroll
    for (int i = 0; i < 4; i++)
      HNA[(size_t)(nl0 + mt + quad*4 + i) * 512 + h*64 + nt*16 + col] = f2bf(eluf(acc[i]));
  }
}

// y3: pure-MFMA Y build — PAIR version (32768 edges per dispatch, grid 1024)
__global__ __launch_bounds__(256) void y3_k(const u16* __restrict__ Ub, const float* __restrict__ AL1,
                                            const u16* __restrict__ HNA, const u16* __restrict__ W1T,
                                            const int* __restrict__ src, const int* __restrict__ cidx,
                                            u16* __restrict__ Y, const int s2){
  __shared__ __align__(16) u16 Us[32][72];
  __shared__ float als[256];
  __shared__ int Es[32], Ss[32];
  const int t = threadIdx.x;
  const int w = t >> 6, lane = t & 63;
  const int col = lane & 15, quad = lane >> 4;
  const int mw = (w & 1) * 16;
  const int hw = (w >> 1) * 4;
  const int ep0 = s2 * 32768 + blockIdx.x * 32;
  if (t < 32){ const int e = cidx[ep0 + t]; Es[t] = e; Ss[t] = src[e]; }
  als[t] = AL1[(size_t)ep0 * 8 + t];
  __syncthreads();
  {
    const int r = t >> 3, seg = (t & 7) * 8;
    *(ushort4*)&Us[r][seg]     = *(const ushort4*)(Ub + (size_t)Es[r] * 64 + seg);
    *(ushort4*)&Us[r][seg + 4] = *(const ushort4*)(Ub + (size_t)Es[r] * 64 + seg + 4);
  }
  __syncthreads();
  const bf16x8 a0 = *(const bf16x8*)&Us[mw + col][quad*8];
  const bf16x8 a1 = *(const bf16x8*)&Us[mw + col][32 + quad*8];
  #pragma unroll
  for (int hh = 0; hh < 4; hh++){
    const int h = hw + hh;
    #pragma unroll
    for (int nt = 0; nt < 4; nt++){
      const u16* brow = W1T + (size_t)(h*64 + nt*16 + col) * 64;
      const bf16x8 b0 = *(const bf16x8*)(brow + quad*8);
      const bf16x8 b1 = *(const bf16x8*)(brow + 32 + quad*8);
      f32x4 acc = (f32x4){0.f, 0.f, 0.f, 0.f};
      acc = __builtin_amdgcn_mfma_f32_16x16x32_bf16(a0, b0, acc, 0, 0, 0);
      acc = __builtin_amdgcn_mfma_f32_16x16x32_bf16(a1, b1, acc, 0, 0, 0);
      #pragma unroll
      for (int i = 0; i < 4; i++){
        const int er = mw + quad*4 + i;
        const float v = eluf(als[er*8 + h] * acc[i])
                      + bf2f(HNA[(size_t)Ss[er] * 512 + h*64 + nt*16 + col]);
        Y[(size_t)(blockIdx.x*32 + er) * 512 + h*64 + nt*16 + col] = f2bf(v);
      }
    }
  }
}

// sgf: fused layer-2 scores (wave-0 MFMA over the node's contiguous Y rows)
// + softmax + aggregation, block per node. Y rows L1-hot for the agg pass.
__global__ __launch_bounds__(256) void sgf_k(const u16* __restrict__ Y, const u16* __restrict__ we2b,
                                             const float* __restrict__ AN2, const int* __restrict__ src,
                                             const int* __restrict__ cidx, const int* __restrict__ rp,
                                             float* __restrict__ SA, u16* __restrict__ G2, const int s){
  __shared__ float sc[64][8];
  __shared__ float mh[8], rzh[8];
  __shared__ int Se[64];
  const int t = threadIdx.x;
  const int w = t >> 6, lane = t & 63;
  const int col = lane & 15, quad = lane >> 4;
  const int nl = blockIdx.x;
  const int n = s * 2048 + nl;
  const int beg = rp[n], end = rp[n + 1], m = end - beg;
  const int base = (s >> 1) * 32768;
  const int lbeg = beg - base;
  const bool small = (m <= 64);
  if (small && t < m) Se[t] = src[cidx[beg + t]];
  __syncthreads();
  if (w == 0){
    for (int t0 = 0; t0 < m; t0 += 16){
      int ar = lbeg + t0 + col; if (ar > 32767) ar = 32767;
      const u16* arow = Y + (size_t)ar * 512;
      const u16* brow = we2b + (size_t)col * 512;
      f32x4 acc = (f32x4){0.f, 0.f, 0.f, 0.f};
      #pragma unroll
      for (int ks = 0; ks < 16; ks++){
        const bf16x8 a = *(const bf16x8*)(arow + ks*32 + quad*8);
        const bf16x8 b = *(const bf16x8*)(brow + ks*32 + quad*8);
        acc = __builtin_amdgcn_mfma_f32_16x16x32_bf16(a, b, acc, 0, 0, 0);
      }
      if (col < 8){
        const float anD = AN2[n * 16 + 8 + col];
        #pragma unroll
        for (int i = 0; i < 4; i++){
          const int r = t0 + quad*4 + i;
          if (r < m){
            const int se = small ? Se[r] : src[cidx[beg + r]];
            const float v = leaky(AN2[se * 16 + col] + acc[i] + anD);
            if (small) sc[r][col] = v;
            else       SA[(size_t)(beg + r) * 8 + col] = v;
          }
        }
      }
    }
  }
  __syncthreads();
  {
    const int h = t >> 5, l32 = t & 31;
    float mm = -1e30f, zz = 0.f;
    for (int i = l32; i < m; i += 32){
      const float v = small ? sc[i][h] : SA[(size_t)(beg + i) * 8 + h];
      lse_merge(mm, zz, v, 1.f);
    }
    #pragma unroll
    for (int off = 1; off < 32; off <<= 1){
      const float om = __shfl_xor(mm, off), oz = __shfl_xor(zz, off);
      lse_merge(mm, zz, om, oz);
    }
    if (l32 == 0){ mh[h] = mm; rzh[h] = 1.f / fmaxf(zz, 1e-9f); }
  }
  __syncthreads();
  if (small){
    for (int idx = t; idx < m * 8; idx += 256){
      const int i = idx >> 3, h = idx & 7;
      sc[i][h] = __expf(sc[i][h] - mh[h]) * rzh[h];
    }
  }
  __syncthreads();
  {
    const int d0 = t * 2;
    float ac[8][2] = {{0.f}};
    for (int i = 0; i < m; i++){
      const u32 yv = *(const u32*)(Y + (size_t)(lbeg + i) * 512 + d0);
      const float y0 = bf2f((u16)(yv & 0xffffu)), y1 = bf2f((u16)(yv >> 16));
      float al[8];
      if (small){
        #pragma unroll
        for (int h = 0; h < 8; h++) al[h] = sc[i][h];
      } else {
        #pragma unroll
        for (int h = 0; h < 8; h++)
          al[h] = __expf(SA[(size_t)(beg + i) * 8 + h] - mh[h]) * rzh[h];
      }
      #pragma unroll
      for (int h = 0; h < 8; h++){
        ac[h][0] = fmaf(al[h], y0, ac[h][0]);
        ac[h][1] = fmaf(al[h], y1, ac[h][1]);
      }
    }
    #pragma unroll
    for (int h = 0; h < 8; h++){
      const u32 o = (u32)f2bf(ac[h][0]) | ((u32)f2bf(ac[h][1]) << 16);
      *(u32*)(G2 + ((size_t)nl * 8 + h) * 512 + d0) = o;
    }
  }
}

// nft2 MFMA
__global__ __launch_bounds__(256) void nft2m_k(const u16* __restrict__ G2, const u16* __restrict__ W2T,
                                               u16* __restrict__ HNB, const int s){
  const int t = threadIdx.x;
  const int w = t >> 6, lane = t & 63;
  const int col = lane & 15, quad = lane >> 4;
  const int h = blockIdx.y;
  const int nl0 = blockIdx.x * 32;
  const int mt = (w & 1) * 16;
  const int nb = (w >> 1) * 2;
  const u16* arow = G2 + ((size_t)((nl0 + mt + col) * 8) + h) * 512;
  #pragma unroll
  for (int nn = 0; nn < 2; nn++){
    const int nt = nb + nn;
    const u16* brow = W2T + (size_t)(h*64 + nt*16 + col) * 512;
    f32x4 acc = (f32x4){0.f, 0.f, 0.f, 0.f};
    #pragma unroll
    for (int ks = 0; ks < 16; ks++){
      const bf16x8 a = *(const bf16x8*)(arow + ks*32 + quad*8);
      const bf16x8 b = *(const bf16x8*)(brow + ks*32 + quad*8);
      acc = __builtin_amdgcn_mfma_f32_16x16x32_bf16(a, b, acc, 0, 0, 0);
    }
    #pragma unroll
    for (int i = 0; i < 4; i++)
      HNB[(size_t)(s*2048 + nl0 + mt + quad*4 + i) * 512 + h*64 + nt*16 + col] = f2bf(eluf(acc[i]));
  }
}

// ---------------------------------- CSR -------------------------------------
__global__ __launch_bounds__(256) void hist_k(const int* __restrict__ dst, int* __restrict__ deg){
  const int e = blockIdx.x * 256 + threadIdx.x;
  if (e < NEd) atomicAdd(&deg[dst[e]], 1);
}
// parallel prefix: per-thread chunk sum -> shfl_up wave scan -> wave combine
__global__ __launch_bounds__(256) void scan_k(const int* __restrict__ deg, int* __restrict__ rp,
                                              int* __restrict__ fill){
  __shared__ int wsum[4];
  const int t = threadIdx.x;
  const int lane = t & 63, wid = t >> 6;
  const int base = t * 64;
  int s = 0;
  for (int i = 0; i < 64; i++) s += deg[base + i];
  int v = s;
  #pragma unroll
  for (int off = 1; off < 64; off <<= 1){
    const int u = __shfl_up(v, off);
    if (lane >= off) v += u;
  }
  if (lane == 63) wsum[wid] = v;
  __syncthreads();
  int add = 0;
  #pragma unroll
  for (int wq = 0; wq < 4; wq++) if (wq < wid) add += wsum[wq];
  int off0 = add + v - s;   // exclusive prefix for this thread's 64-chunk
  for (int i = 0; i < 64; i++){
    rp[base + i] = off0; fill[base + i] = off0;
    off0 += deg[base + i];
  }
  if (t == 255) rp[NNd] = off0;
}
__global__ __launch_bounds__(256) void scatter_k(const int* __restrict__ dst, int* __restrict__ fill,
                                                 int* __restrict__ cidx){
  const int e = blockIdx.x * 256 + threadIdx.x;
  if (e < NEd){
    int pos = atomicAdd(&fill[dst[e]], 1);
    cidx[pos] = e;
  }
}

// ------------------------------- readout ------------------------------------
// mean via atomics: 256 blocks (sg x 8 chunks of 64 rows); xcat pre-zeroed
__global__ __launch_bounds__(256) void mean_k(const u16* __restrict__ HNB, float* __restrict__ xcat){
  const int sg = blockIdx.x >> 3, chunk = blockIdx.x & 7;
  const int t = threadIdx.x;
  const int g = (sg < 16) ? sg : sg - 16;
  const int half = (sg < 16) ? 0 : 1;
  const int c0 = t * 2;
  float s0 = 0.f, s1 = 0.f;
  const u16* base = HNB + ((size_t)sg * 512 + chunk * 64) * 512;
  for (int n = 0; n < 64; n++){
    const u32 u = *(const u32*)(base + (size_t)n * 512 + c0);
    s0 += bf2f((u16)(u & 0xffffu));
    s1 += bf2f((u16)(u >> 16));
  }
  atomicAdd(&xcat[g * 1024 + half * 512 + c0],     s0 * (1.f / 512.f));
  atomicAdd(&xcat[g * 1024 + half * 512 + c0 + 1], s1 * (1.f / 512.f));
}

// FC1 with BN1 fused (per-block recomputed column stats; xcat stays raw means)
__global__ __launch_bounds__(256) void fc1_k(const float* __restrict__ xcat, const float* __restrict__ wf,
                                             float* __restrict__ y1g){
  __shared__ float xs[1024];
  __shared__ float ps[4][64];
  const int t = threadIdx.x, g = blockIdx.x;
  for (int j = t; j < 1024; j += 256){
    float mu = 0.f;
    #pragma unroll
    for (int gg = 0; gg < 16; gg++) mu += xcat[gg * 1024 + j];
    mu *= (1.f / 16.f);
    float var = 0.f;
    #pragma unroll
    for (int gg = 0; gg < 16; gg++){ const float d = xcat[gg * 1024 + j] - mu; var += d * d; }
    var *= (1.f / 16.f);
    const float sc = rsqrtf(var + 1e-5f) * wf[WO_B1G + j];
    xs[j] = (xcat[g * 1024 + j] - mu) * sc + wf[WO_B1B + j];
  }
  __syncthreads();
  const int c = t & 63, kq = t >> 6;
  float acc = 0.f;
  #pragma unroll 4
  for (int k = kq * 256; k < kq * 256 + 256; k++)
    acc = fmaf(xs[k], wf[WO_F1W + k * 64 + c], acc);
  ps[kq][c] = acc;
  __syncthreads();
  if (t < 64){
    const float a = ps[0][t] + ps[1][t] + ps[2][t] + ps[3][t] + wf[WO_F1B + t];
    y1g[g * 64 + t] = fmaxf(a, 0.f);
  }
}

// BN2 + FC2 tail (tiny)
__global__ __launch_bounds__(256) void head2_k(const float* __restrict__ y1g, const float* __restrict__ wf,
                                               void* __restrict__ outp, const int* __restrict__ flagp){
  __shared__ float y1s[16][64];
  __shared__ float mu2s[64], sc2s[64];
  const int t = threadIdx.x;
  for (int i = t; i < 1024; i += 256) y1s[i >> 6][i & 63] = y1g[i];
  __syncthreads();
  if (t < 64){
    float mu = 0.f;
    #pragma unroll
    for (int g = 0; g < 16; g++) mu += y1s[g][t];
    mu *= (1.f / 16.f);
    float var = 0.f;
    #pragma unroll
    for (int g = 0; g < 16; g++){ const float d = y1s[g][t] - mu; var += d * d; }
    var *= (1.f / 16.f);
    mu2s[t] = mu; sc2s[t] = rsqrtf(var + 1e-5f) * wf[WO_B2G + t];
  }
  __syncthreads();
  if (t < 48){
    const int gg = t / 3, c = t % 3;
    float acc = wf[WO_F2B + c];
    #pragma unroll
    for (int k = 0; k < 64; k++){
      const float y2 = (y1s[gg][k] - mu2s[k]) * sc2s[k] + wf[WO_B2B + k];
      acc = fmaf(y2, wf[WO_F2W + k * 3 + c], acc);
    }
    if (*flagp) ((u16*)outp)[t] = f2bf(acc);
    else        ((float*)outp)[t] = acc;
  }
}

// --------------------------------- launch -----------------------------------
extern "C" void kernel_launch(void* const* d_in, const int* in_sizes, int n_in,
                              void* d_out, int out_size, void* d_ws, size_t ws_size,
                              hipStream_t stream) {
  (void)in_sizes; (void)n_in; (void)out_size;
  if (ws_size < WS_NEED) return;

  const int* src = (const int*)d_in[3];
  const int* dst = (const int*)d_in[4];
  char* w = (char*)d_ws;

  float* wf   = (float*)(w + OFF_WF);
  float* cb   = (float*)(w + OFF_CB);
  u16*   Ub   = (u16*)(w + OFF_U);
  u16*   W1T  = (u16*)(w + OFF_W1B);
  u16*   W2T  = (u16*)(w + OFF_W2B);
  u16*   we2b = (u16*)(w + OFF_WE2B);
  u16*   we1b = (u16*)(w + OFF_WE1B);
  float* AL1  = (float*)(w + OFF_AL1);
  float* SA   = (float*)(w + OFF_SA);
  u16*   HNA  = (u16*)(w + OFF_HNA);
  float* AN2  = (float*)(w + OFF_AN2);
  int*   deg  = (int*)(w + OFF_DEG);
  int*   rp   = (int*)(w + OFF_RP);
  int*   fill = (int*)(w + OFF_FILL);
  int*   cidx = (int*)(w + OFF_CIDX);
  float* rbig = (float*)(w + OFF_RBIG);
  float* xcat = (float*)(w + OFF_XCAT);
  int*   flag = (int*)(w + OFF_FLAG);

  float* x1a  = (float*)(w + OFF_T + T_X1A);
  float* x2a  = (float*)(w + OFF_T + T_X2A);
  float* hn0  = (float*)(w + OFF_T + T_HN0);
  float* AN1  = (float*)(w + OFF_T + T_AN1);
  float* S    = (float*)(w + OFF_T + T_S);
  u16*   Y    = (u16*)(w + OFF_T + T_Y);       // pair buffer, 32768 rows
  float* y1g  = (float*)(w + OFF_T + T_Y1G);   // readout scratch (after slices)

  float* pacc = rbig;                           // 8*8192*64*4 = 16.7MB
  float* pz   = (float*)(w + OFF_T + T_PZ);     // in hn0 slot during flash
  u16*   G1b  = (u16*)(w + OFF_RBIG);
  u16*   HNB  = (u16*)(w + OFF_RBIG);           // [0, 16.78MB)
  u16*   G2   = (u16*)(w + OFF_RBIG + R_G2);    // [16.78, 33.55MB) — exact fit

  // 0. detect + weights + combos
  detect_k<<<1, 256, 0, stream>>>((const u16*)d_in[0], flag);
  P17 ps;
  for (int i = 0; i < 17; i++) ps.p[i] = d_in[6 + i];
  convw_k<<<(WO_END + 255) / 256, 256, 0, stream>>>(ps, wf, flag);
  wprep_k<<<(294912 + CB_END + 4096 + 512 + 255) / 256, 256, 0, stream>>>(wf, W1T, W2T, cb, we2b, we1b);

  // 1. CSR over dst
  hipMemsetAsync(deg, 0, NNd * sizeof(int), stream);
  hist_k<<<NEd / 256, 256, 0, stream>>>(dst, deg);
  scan_k<<<1, 256, 0, stream>>>(deg, rp, fill);
  scatter_k<<<NEd / 256, 256, 0, stream>>>(dst, fill, cidx);

  // 2. alignment (swapped 32x32 MFMA flash, 8 key-splits)
  flash_mfma_k<<<dim3(64, KSPLIT), 256, 0, stream>>>(d_in[0], d_in[1], flag, pacc, pz);
  flash_merge_k<<<NSd / 4, 256, 0, stream>>>(pacc, pz, x1a);
  flash_mfma_k<<<dim3(64, KSPLIT), 256, 0, stream>>>(d_in[1], d_in[0], flag, pacc, pz);
  flash_merge_k<<<NSd / 4, 256, 0, stream>>>(pacc, pz, x2a);

  // 3. projection
  proj_k<<<NNd / 64, 256, 0, stream>>>(d_in[0], d_in[1], x1a, x2a, wf, hn0, flag);

  // 4. GAT layer 1 (merged: Ub build + AN1; MFMA scores; fused softmax+G1)
  usan_k<<<8192 + 1024, 256, 0, stream>>>(d_in[2], hn0, src, Ub, cb + CB_WC1, AN1, flag);
  score1_k<<<NEd / 64, 256, 0, stream>>>(d_in[2], we1b, AN1, src, dst, cidx, S, flag);
  sga_g1_k<<<NNd, 256, 0, stream>>>(S, rp, cidx, Ub, AL1, G1b);
  nft1m_k<<<dim3(NNd / 32, 8), 256, 0, stream>>>(G1b, W1T, HNA);

  // 5. layer-2 per-node combos
  anw_k<<<NNd / 64, 256, 0, stream>>>(HNA, cb + CB_WC2, AN2);

  // 6. layer-2: 4 slice-pairs x (y3 + per-slice (sgf, nft2m))
  for (int s2 = 0; s2 < 4; s2++){
    y3_k<<<1024, 256, 0, stream>>>(Ub, AL1, HNA, W1T, src, cidx, Y, s2);
    for (int sub = 0; sub < 2; sub++){
      const int s = s2 * 2 + sub;
      sgf_k<<<2048, 256, 0, stream>>>(Y, we2b, AN2, src, cidx, rp, SA, G2, s);
      nft2m_k<<<dim3(64, 8), 256, 0, stream>>>(G2, W2T, HNB, s);
    }
  }

  // 7. readout (mean via atomics -> fused BN1+FC1 -> BN2+FC2)
  hipMemsetAsync(xcat, 0, 16 * 1024 * sizeof(float), stream);
  mean_k<<<256, 256, 0, stream>>>(HNB, xcat);
  fc1_k<<<16, 256, 0, stream>>>(xcat, wf, y1g);
  head2_k<<<1, 256, 0, stream>>>(y1g, wf, d_out, flag);
}

// Round 10
// 818.951 us; speedup vs baseline: 1.0549x; 1.0549x over previous
//
#include <hip/hip_runtime.h>

// GATClassifier on MI355X — round 19: revert r18's harmful fusions. sgf_k
// (per-node wave-0 MFMA scores: ~4x wasted tile work + 3/4-block idle) and
// sga_g1_k regressed +53us; restore r17's dense score2_k + sg2_k and
// segalpha + g1b. Keep usan_k (us1+an64 merge — shape-identical, -1
// dispatch). Everything else = r17 exactly (810.5us proven).

#define NSd 8192
#define NNd 16384
#define NEd 131072
#define KSPLIT 8

typedef unsigned short u16;
typedef unsigned int   u32;
typedef short bf16x8 __attribute__((ext_vector_type(8)));
typedef float f32x4  __attribute__((ext_vector_type(4)));
typedef float f32x16 __attribute__((ext_vector_type(16)));

__device__ __forceinline__ float bf2f(u16 u){ return __uint_as_float(((u32)u) << 16); }
__device__ __forceinline__ u16 f2bf(float f){
  u32 u = __float_as_uint(f);
  u += 0x7fffu + ((u >> 16) & 1u);
  return (u16)(u >> 16);
}
__device__ __forceinline__ u32 pkbf(float a, float b){
  u32 r;
  asm("v_cvt_pk_bf16_f32 %0, %1, %2" : "=v"(r) : "v"(a), "v"(b));
  return r;
}
__device__ __forceinline__ void pl32swap(u32& a, u32& b){
  auto r = __builtin_amdgcn_permlane32_swap(a, b, false, false);
  a = r[0]; b = r[1];
}
__device__ __forceinline__ float eluf(float x){ return x > 0.f ? x : expm1f(x); }
__device__ __forceinline__ float leaky(float x){ return x > 0.f ? x : 0.2f * x; }
__device__ __forceinline__ float ldin(const void* p, size_t i, int fl){
  return fl ? bf2f(((const u16*)p)[i]) : ((const float*)p)[i];
}
__device__ __forceinline__ void lse_merge(float& m, float& z, float om, float oz){
  float M = fmaxf(m, om);
  z = z * __expf(m - M) + oz * __expf(om - M);
  m = M;
}

// ------------------------- workspace layout (bytes) -------------------------
static constexpr size_t OFF_WF   = 0;
static constexpr size_t OFF_CB   = 1529600;
static constexpr size_t OFF_U    = 1584896;      // 131072*64 bf16 (Ub)
static constexpr size_t OFF_W1B  = 18362112;     // W1T bf16
static constexpr size_t OFF_W2B  = 18427648;     // W2T bf16
static constexpr size_t OFF_WE2B = 18951936;     // 16*512 bf16 (padded WE2)
static constexpr size_t OFF_WE1B = 18968320;     // 16*64 bf16 (padded WE1)
static constexpr size_t OFF_AL1  = 35139328;     // 131072*8 f32 (by CSR pos)
static constexpr size_t OFF_SA   = 39333632;     // 131072*8 f32 (layer-2 scores)
static constexpr size_t OFF_HNA  = 43527936;     // 16384*512 bf16 (16.78MB)
static constexpr size_t OFF_AN2  = 60305152;     // 16384*16 f32 (in freed HNA tail)
static constexpr size_t OFF_DEG  = 77082368;
static constexpr size_t OFF_RP   = 77147904;
static constexpr size_t OFF_FILL = 77213696;
static constexpr size_t OFF_CIDX = 77279232;
static constexpr size_t OFF_RBIG = 77803520;     // pacc | G1b | HNB[0,16.78M)+G2[16.78,33.55M)
static constexpr size_t OFF_T    = 111357952;    // 32MB union (Y pair in layer 2)
static constexpr size_t OFF_XCAT = 144912384;
static constexpr size_t OFF_FLAG = 144977920;
static constexpr size_t WS_NEED  = 144978176;

static constexpr size_t T_X1A = 0;
static constexpr size_t T_X2A = 2097152;
static constexpr size_t T_HN0 = 4194304;
static constexpr size_t T_PZ  = 4194304;         // pz during flash (hn0 slot, free then)
static constexpr size_t T_AN1 = 8388608;
static constexpr size_t T_S   = 9437184;
static constexpr size_t T_Y   = 0;               // 32768*512 bf16 (slice PAIR, full T)
static constexpr size_t T_Y1G = 0;               // 16*64 f32 (readout, after slices)
static constexpr size_t R_G2  = 16777216;        // RBIG-relative, 2048*8*512 bf16 (exact fit)

static constexpr int WO_PROJ = 0,      WO_W1 = 16384;
static constexpr int WO_AL1 = 49152,   WO_AR1 = 49664,  WO_AE1 = 50176;
static constexpr int WO_W2  = 50688;
static constexpr int WO_AL2 = 312832,  WO_AR2 = 313344, WO_AE2 = 313856;
static constexpr int WO_B1G = 314368,  WO_B1B = 315392;
static constexpr int WO_F1W = 316416,  WO_F1B = 381952;
static constexpr int WO_B2G = 382016,  WO_B2B = 382080;
static constexpr int WO_F2W = 382144,  WO_F2B = 382336;
static constexpr int WO_END = 382339;

static constexpr int CB_WC1 = 0;
static constexpr int CB_WE1 = 1024;
static constexpr int CB_WC2 = 1536;   // rows 0..7 = W2*(al2-ae2)
static constexpr int CB_WE2 = 9728;
static constexpr int CB_END = 13824;

// ------------------------------- dtype detect -------------------------------
__global__ __launch_bounds__(256) void detect_k(const u16* __restrict__ p, int* __restrict__ flag){
  __shared__ int bad;
  if (threadIdx.x == 0) bad = 0;
  __syncthreads();
  int b = 0;
  for (int i = threadIdx.x; i < 1024; i += 256){
    float f = bf2f(p[i]);
    if (!(fabsf(f) <= 100.f)) b++;
  }
  atomicAdd(&bad, b);
  __syncthreads();
  if (threadIdx.x == 0) *flag = (bad == 0) ? 1 : 0;
}

struct P17 { const void* p[17]; };

__global__ __launch_bounds__(256) void convw_k(P17 ps, float* __restrict__ wf, const int* __restrict__ flagp){
  const int i = blockIdx.x * 256 + threadIdx.x;
  if (i >= WO_END) return;
  const int fl = *flagp;
  const int ends[17] = {16384,49152,49664,50176,50688,312832,313344,313856,314368,
                        315392,316416,381952,382016,382080,382144,382336,382339};
  int seg = 0;
  while (i >= ends[seg]) seg++;
  const int start = seg ? ends[seg-1] : 0;
  wf[i] = ldin(ps.p[seg], i - start, fl);
}

// merged: W1T + W2T transposes, combos, WE pads — one dispatch after convw
__global__ __launch_bounds__(256) void wprep_k(const float* __restrict__ wf, u16* __restrict__ w1t,
                                               u16* __restrict__ w2t, float* __restrict__ cb,
                                               u16* __restrict__ we2b, u16* __restrict__ we1b){
  const int i = blockIdx.x * 256 + threadIdx.x;
  if (i < 32768){
    const int c = i >> 6, k = i & 63;
    w1t[i] = f2bf(wf[WO_W1 + k * 512 + c]);
    return;
  }
  if (i < 294912){
    const int j = i - 32768;
    const int c = j >> 9, k = j & 511;
    w2t[j] = f2bf(wf[WO_W2 + k * 512 + c]);
    return;
  }
  const int j = i - 294912;
  if (j >= CB_END + 4096 + 512) return;
  if (j >= CB_END + 4096){ we1b[512 + (j - CB_END - 4096)] = 0; return; }
  if (j >= CB_END){ we2b[4096 + (j - CB_END)] = 0; return; }
  float acc = 0.f;
  if (j < 1024){
    const int o = j >> 6, d = j & 63, h = o & 7;
    const float* a = wf + ((o >> 3) ? WO_AR1 : WO_AL1) + h * 64;
    for (int dp = 0; dp < 64; dp++) acc += wf[WO_W1 + d * 512 + h * 64 + dp] * a[dp];
    cb[CB_WC1 + j] = acc;
  } else if (j < 1536){
    const int jj = j - 1024, h = jj >> 6, d = jj & 63;
    for (int dp = 0; dp < 64; dp++) acc += wf[WO_W1 + d * 512 + h * 64 + dp] * wf[WO_AE1 + h * 64 + dp];
    cb[CB_WE1 + jj] = acc;
    we1b[jj] = f2bf(acc);
  } else if (j < 9728){
    const int jj = j - 1536, o = jj >> 9, c = jj & 511, h = o & 7;
    for (int dp = 0; dp < 64; dp++){
      const float av = (o >> 3) ? wf[WO_AR2 + h * 64 + dp]
                                : (wf[WO_AL2 + h * 64 + dp] - wf[WO_AE2 + h * 64 + dp]);
      acc += wf[WO_W2 + c * 512 + h * 64 + dp] * av;
    }
    cb[CB_WC2 + jj] = acc;
  } else {
    const int jj = j - 9728, h = jj >> 9, c = jj & 511;
    for (int dp = 0; dp < 64; dp++) acc += wf[WO_W2 + c * 512 + h * 64 + dp] * wf[WO_AE2 + h * 64 + dp];
    cb[CB_WE2 + jj] = acc;
    we2b[jj] = f2bf(acc);
  }
}

// --------------------------- flash alignment (MFMA) -------------------------
// Swapped-operand 32x32x16 flash (exact round-11 body, frozen).
__global__ __launch_bounds__(256) void flash_mfma_k(const void* __restrict__ Qp, const void* __restrict__ Kp,
                                                    const int* __restrict__ flagp, float* __restrict__ pacc,
                                                    float* __restrict__ pz){
  const int fl = *flagp;
  __shared__ __align__(16) u16 Ks[2][32][64];   // row-major, 16B slots XOR (row&7)
  __shared__ __align__(16) u16 Kt[2][64][40];   // transposed [d][kc], pitch 40 (16B aligned)
  const int t = threadIdx.x;
  const int w = t >> 6, l = t & 63;
  const int hi = l >> 5, ql = l & 31;
  const int q0 = blockIdx.x * 128;
  const int kbeg = blockIdx.y * 1024;
  // staging roles
  const int sr = t & 31, scg = t >> 5;   // Ks: row sr, cols scg*8..+7
  const int kp = t & 15, dq = t >> 4;    // Kt: k-rows 2kp,2kp+1, d 4dq..+3

  // Q fragments (B operand), held in registers for the whole kernel
  bf16x8 bq[4];
  {
    const int qrow = q0 + w * 32 + ql;
    if (fl){
      const u16* qp = (const u16*)Qp + (size_t)qrow * 64 + hi * 8;
      #pragma unroll
      for (int s = 0; s < 4; s++) bq[s] = *(const bf16x8*)(qp + s * 16);
    } else {
      const float* qp = (const float*)Qp + (size_t)qrow * 64 + hi * 8;
      #pragma unroll
      for (int s = 0; s < 4; s++){
        union { u32 w_[4]; bf16x8 v; } u;
        #pragma unroll
        for (int i = 0; i < 4; i++) u.w_[i] = pkbf(qp[s*16 + 2*i], qp[s*16 + 2*i + 1]);
        bq[s] = u.v;
      }
    }
  }

  f32x16 accO0, accO1;
  #pragma unroll
  for (int i = 0; i < 16; i++){ accO0[i] = 0.f; accO1[i] = 0.f; }
  float lsum = 0.f;

  // prologue: stage tile 0 -> buffer 0
  {
    const int kr = kbeg;
    if (fl){
      const u16* kb = (const u16*)Kp + (size_t)kr * 64;
      const uint4 s0 = *(const uint4*)(kb + (size_t)sr * 64 + scg * 8);
      const uint2 a0 = *(const uint2*)(kb + (size_t)(2*kp) * 64 + dq * 4);
      const uint2 b0 = *(const uint2*)(kb + (size_t)(2*kp + 1) * 64 + dq * 4);
      *(uint4*)((char*)&Ks[0][sr][0] + ((scg * 16) ^ ((sr & 7) << 4))) = s0;
      const u16* pa = (const u16*)&a0; const u16* pb = (const u16*)&b0;
      #pragma unroll
      for (int i = 0; i < 4; i++)
        *(u32*)&Kt[0][4*dq + i][2*kp] = (u32)pa[i] | ((u32)pb[i] << 16);
    } else {
      const float* kf = (const float*)Kp + (size_t)kr * 64;
      const float4 f0 = *(const float4*)(kf + (size_t)sr * 64 + scg * 8);
      const float4 f1 = *(const float4*)(kf + (size_t)sr * 64 + scg * 8 + 4);
      const float4 fa = *(const float4*)(kf + (size_t)(2*kp) * 64 + dq * 4);
      const float4 fb = *(const float4*)(kf + (size_t)(2*kp + 1) * 64 + dq * 4);
      union { u32 w_[4]; uint4 q; } uu;
      uu.w_[0] = pkbf(f0.x, f0.y); uu.w_[1] = pkbf(f0.z, f0.w);
      uu.w_[2] = pkbf(f1.x, f1.y); uu.w_[3] = pkbf(f1.z, f1.w);
      *(uint4*)((char*)&Ks[0][sr][0] + ((scg * 16) ^ ((sr & 7) << 4))) = uu.q;
      const float* faf = &fa.x; const float* fbf = &fb.x;
      #pragma unroll
      for (int i = 0; i < 4; i++)
        *(u32*)&Kt[0][4*dq + i][2*kp] = pkbf(faf[i], fbf[i]);
    }
  }

  for (int it = 0; it < 32; it++){
    const int cur = it & 1;
    __syncthreads();   // staged tile `it` visible; previous compute done

    // T14: issue next-tile global loads early (latency hides under compute)
    uint4 nKs; uint2 nKa, nKb;
    float4 nKsf0, nKsf1, nKaf, nKbf;
    const bool nx = (it + 1 < 32);
    if (nx){
      const int kr = kbeg + (it + 1) * 32;
      if (fl){
        const u16* kb = (const u16*)Kp + (size_t)kr * 64;
        nKs = *(const uint4*)(kb + (size_t)sr * 64 + scg * 8);
        nKa = *(const uint2*)(kb + (size_t)(2*kp) * 64 + dq * 4);
        nKb = *(const uint2*)(kb + (size_t)(2*kp + 1) * 64 + dq * 4);
      } else {
        const float* kf = (const float*)Kp + (size_t)kr * 64;
        nKsf0 = *(const float4*)(kf + (size_t)sr * 64 + scg * 8);
        nKsf1 = *(const float4*)(kf + (size_t)sr * 64 + scg * 8 + 4);
        nKaf  = *(const float4*)(kf + (size_t)(2*kp) * 64 + dq * 4);
        nKbf  = *(const float4*)(kf + (size_t)(2*kp + 1) * 64 + dq * 4);
      }
    }

    // ---- S^T = K . Q^T over this 32-k-col tile ----
    f32x16 accS;
    #pragma unroll
    for (int i = 0; i < 16; i++) accS[i] = 0.f;
    #pragma unroll
    for (int s = 0; s < 4; s++){
      const int byo = (s * 32 + hi * 16) ^ ((ql & 7) << 4);
      const bf16x8 a = *(const bf16x8*)((const char*)&Ks[cur][ql][0] + byo);
      accS = __builtin_amdgcn_mfma_f32_32x32x16_bf16(a, bq[s], accS, 0, 0, 0);
    }
    // p = exp(s-32) = exp2(s*log2e - 46.166); lane-local denominator
    float p[16];
    #pragma unroll
    for (int r = 0; r < 16; r++) p[r] = exp2f(fmaf(accS[r], 1.44269504f, -46.1662413f));
    {
      const float s0 = (p[0] + p[1]) + (p[2] + p[3]);
      const float s1 = (p[4] + p[5]) + (p[6] + p[7]);
      const float s2 = (p[8] + p[9]) + (p[10] + p[11]);
      const float s3 = (p[12] + p[13]) + (p[14] + p[15]);
      lsum += (s0 + s1) + (s2 + s3);
    }
    // in-register P -> bf16 A-fragments (T12: cvt_pk + permlane32_swap)
    u32 pk_[8];
    #pragma unroll
    for (int j = 0; j < 4; j++){
      pk_[2*j]     = pkbf(p[4*j],     p[4*j + 1]);
      pk_[2*j + 1] = pkbf(p[4*j + 2], p[4*j + 3]);
    }
    pl32swap(pk_[0], pk_[2]); pl32swap(pk_[1], pk_[3]);
    pl32swap(pk_[4], pk_[6]); pl32swap(pk_[5], pk_[7]);
    union { u32 w_[4]; bf16x8 v; } ua, ub;
    ua.w_[0] = pk_[0]; ua.w_[1] = pk_[1]; ua.w_[2] = pk_[2]; ua.w_[3] = pk_[3];
    ub.w_[0] = pk_[4]; ub.w_[1] = pk_[5]; ub.w_[2] = pk_[6]; ub.w_[3] = pk_[7];
    // ---- O += P V ----
    {
      const u16* kt0 = &Kt[cur][ql][hi * 8];
      accO0 = __builtin_amdgcn_mfma_f32_32x32x16_bf16(ua.v, *(const bf16x8*)kt0, accO0, 0, 0, 0);
      accO0 = __builtin_amdgcn_mfma_f32_32x32x16_bf16(ub.v, *(const bf16x8*)(kt0 + 16), accO0, 0, 0, 0);
      const u16* kt1 = &Kt[cur][32 + ql][hi * 8];
      accO1 = __builtin_amdgcn_mfma_f32_32x32x16_bf16(ua.v, *(const bf16x8*)kt1, accO1, 0, 0, 0);
      accO1 = __builtin_amdgcn_mfma_f32_32x32x16_bf16(ub.v, *(const bf16x8*)(kt1 + 16), accO1, 0, 0, 0);
    }

    // store staged next tile into the other buffer (vmcnt lands here)
    if (nx){
      char* kd = (char*)&Ks[cur ^ 1][sr][0];
      const int byo = (scg * 16) ^ ((sr & 7) << 4);
      if (fl){
        *(uint4*)(kd + byo) = nKs;
        const u16* pa = (const u16*)&nKa; const u16* pb = (const u16*)&nKb;
        #pragma unroll
        for (int i = 0; i < 4; i++)
          *(u32*)&Kt[cur ^ 1][4*dq + i][2*kp] = (u32)pa[i] | ((u32)pb[i] << 16);
      } else {
        union { u32 w_[4]; uint4 q; } uu;
        uu.w_[0] = pkbf(nKsf0.x, nKsf0.y); uu.w_[1] = pkbf(nKsf0.z, nKsf0.w);
        uu.w_[2] = pkbf(nKsf1.x, nKsf1.y); uu.w_[3] = pkbf(nKsf1.z, nKsf1.w);
        *(uint4*)(kd + byo) = uu.q;
        const float* faf = &nKaf.x; const float* fbf = &nKbf.x;
        #pragma unroll
        for (int i = 0; i < 4; i++)
          *(u32*)&Kt[cur ^ 1][4*dq + i][2*kp] = pkbf(faf[i], fbf[i]);
      }
    }
  }

  // epilogue: O rows m = (r&3)+8*(r>>2)+4*hi; cols = 32*nt + ql
  const float zq = lsum + __shfl_xor(lsum, 32);
  const int rowb = q0 + w * 32;
  #pragma unroll
  for (int r = 0; r < 16; r++){
    const int m = (r & 3) + 8 * (r >> 2) + 4 * hi;
    float* pr = pacc + ((size_t)blockIdx.y * NSd + rowb + m) * 64;
    pr[ql]      = accO0[r];
    pr[32 + ql] = accO1[r];
  }
  if (hi == 0) pz[blockIdx.y * NSd + rowb + ql] = zq;
}

__global__ __launch_bounds__(256) void flash_merge_k(const float* __restrict__ pacc,
                                                     const float* __restrict__ pz, float* __restrict__ outp){
  const int t = threadIdx.x;
  const int r = blockIdx.x * 4 + (t >> 6);
  const int d = t & 63;
  float Zt = 0.f, v = 0.f;
  #pragma unroll
  for (int s = 0; s < KSPLIT; s++){
    Zt += pz[s * NSd + r];
    v  += pacc[((size_t)s * NSd + r) * 64 + d];
  }
  outp[(size_t)r * 64 + d] = v / Zt;
}

// ------------------------------- projection ---------------------------------
__global__ __launch_bounds__(256) void proj_k(const void* __restrict__ nbd1, const void* __restrict__ nbd2,
                                              const float* __restrict__ x1a, const float* __restrict__ x2a,
                                              const float* __restrict__ wf, float* __restrict__ hn0,
                                              const int* __restrict__ flagp){
  const int fl = *flagp;
  __shared__ float At[64][65], Bt[64][65];
  const int t = threadIdx.x, tx = t & 15, ty = t >> 4;
  const int m0 = blockIdx.x * 64;
  float acc[4][4] = {{0.f}};
  for (int kt = 0; kt < 256; kt += 64){
    __syncthreads();
    {
      const int i = t >> 2, c0 = (t & 3) * 16;
      const int mrow = m0 + i;
      const int side = mrow < NSd;
      const int mr = side ? mrow : mrow - NSd;
      const void* nb = side ? nbd1 : nbd2;
      const float* xa = side ? x1a : x2a;
      const int seg = kt >> 6;
      for (int c = 0; c < 16; c++){
        const int kk = c0 + c;
        const float nv = ldin(nb, (size_t)mr * 64 + kk, fl);
        const float av = xa[(size_t)mr * 64 + kk];
        At[i][kk] = (seg == 0) ? nv : (seg == 1) ? av : (seg == 2) ? (nv - av) : (nv * av);
      }
      const int kk = t >> 2;
      for (int c = 0; c < 16; c++) Bt[kk][c0 + c] = wf[WO_PROJ + (kt + kk) * 64 + c0 + c];
    }
    __syncthreads();
    #pragma unroll
    for (int k = 0; k < 64; k++){
      float a0 = At[ty*4+0][k], a1 = At[ty*4+1][k], a2 = At[ty*4+2][k], a3 = At[ty*4+3][k];
      float b0 = Bt[k][tx*4+0], b1 = Bt[k][tx*4+1], b2 = Bt[k][tx*4+2], b3 = Bt[k][tx*4+3];
      acc[0][0] = fmaf(a0,b0,acc[0][0]); acc[0][1] = fmaf(a0,b1,acc[0][1]); acc[0][2] = fmaf(a0,b2,acc[0][2]); acc[0][3] = fmaf(a0,b3,acc[0][3]);
      acc[1][0] = fmaf(a1,b0,acc[1][0]); acc[1][1] = fmaf(a1,b1,acc[1][1]); acc[1][2] = fmaf(a1,b2,acc[1][2]); acc[1][3] = fmaf(a1,b3,acc[1][3]);
      acc[2][0] = fmaf(a2,b0,acc[2][0]); acc[2][1] = fmaf(a2,b1,acc[2][1]); acc[2][2] = fmaf(a2,b2,acc[2][2]); acc[2][3] = fmaf(a2,b3,acc[2][3]);
      acc[3][0] = fmaf(a3,b0,acc[3][0]); acc[3][1] = fmaf(a3,b1,acc[3][1]); acc[3][2] = fmaf(a3,b2,acc[3][2]); acc[3][3] = fmaf(a3,b3,acc[3][3]);
    }
  }
  #pragma unroll
  for (int i = 0; i < 4; i++)
    #pragma unroll
    for (int j = 0; j < 4; j++)
      hn0[(size_t)(m0 + ty*4 + i) * 64 + tx*4 + j] = fmaxf(acc[i][j], 0.f);
}

// ---------------- merged U build + AN1 combos (grid branch) -----------------
__global__ __launch_bounds__(256) void usan_k(const void* __restrict__ ebd, const float* __restrict__ hn0,
                                              const int* __restrict__ src, u16* __restrict__ Ub,
                                              const float* __restrict__ wc, float* __restrict__ an,
                                              const int* __restrict__ flagp){
  const int b = blockIdx.x, t = threadIdx.x;
  if (b < 8192){
    const int fl = *flagp;
    const int id = b * 256 + t;
    const int e = id >> 4, q = id & 15, d0 = q * 4;
    const int sn = src[e];
    float ev[4];
    if (fl){
      const uint2 u = *(const uint2*)((const u16*)ebd + (size_t)e * 64 + d0);
      ev[0] = bf2f((u16)(u.x & 0xffffu)); ev[1] = bf2f((u16)(u.x >> 16));
      ev[2] = bf2f((u16)(u.y & 0xffffu)); ev[3] = bf2f((u16)(u.y >> 16));
    } else {
      const float4 f = *(const float4*)((const float*)ebd + (size_t)e * 64 + d0);
      ev[0] = f.x; ev[1] = f.y; ev[2] = f.z; ev[3] = f.w;
    }
    const float4 hv = *(const float4*)(hn0 + (size_t)sn * 64 + d0);
    ushort4 o;
    o.x = f2bf(ev[0] + hv.x); o.y = f2bf(ev[1] + hv.y);
    o.z = f2bf(ev[2] + hv.z); o.w = f2bf(ev[3] + hv.w);
    *(ushort4*)(Ub + (size_t)e * 64 + d0) = o;
  } else {
    const int id = (b - 8192) * 256 + t;   // < 262144
    const int n = id >> 4, o = id & 15;
    const float* row = hn0 + (size_t)n * 64;
    const float* wp = wc + o * 64;
    float acc = 0.f;
    for (int k = 0; k < 64; k += 4){
      const float4 r4 = *(const float4*)(row + k);
      const float4 w4 = *(const float4*)(wp + k);
      acc += r4.x*w4.x + r4.y*w4.y + r4.z*w4.z + r4.w*w4.w;
    }
    an[id] = acc;
  }
}

// AN2 tiled: 64 nodes/block, WC2 staged in LDS; HNA is bf16
__global__ __launch_bounds__(256) void anw_k(const u16* __restrict__ HNA, const float* __restrict__ wc,
                                             float* __restrict__ an){
  __shared__ float W[16][516];
  const int t = threadIdx.x;
  for (int i = t; i < 8192; i += 256) W[i >> 9][i & 511] = wc[i];
  __syncthreads();
  const int node = blockIdx.x * 64 + (t >> 2);
  const int cb0 = (t & 3) * 4;
  const u16* row = HNA + (size_t)node * 512;
  float acc[4] = {0.f, 0.f, 0.f, 0.f};
  for (int k = 0; k < 512; k += 4){
    const uint2 u = *(const uint2*)(row + k);
    const float r0 = bf2f((u16)(u.x & 0xffffu)), r1 = bf2f((u16)(u.x >> 16));
    const float r2 = bf2f((u16)(u.y & 0xffffu)), r3 = bf2f((u16)(u.y >> 16));
    #pragma unroll
    for (int j = 0; j < 4; j++){
      const float* wr = &W[cb0 + j][k];
      acc[j] += r0 * wr[0] + r1 * wr[1] + r2 * wr[2] + r3 * wr[3];
    }
  }
  #pragma unroll
  for (int j = 0; j < 4; j++) an[node * 16 + cb0 + j] = acc[j];
}

// score1: layer-1 raw scores via MFMA — S[pos][h] = leaky(AN1 + ebd.WE1)
__global__ __launch_bounds__(256) void score1_k(const void* __restrict__ ebd, const u16* __restrict__ we1b,
                                                const float* __restrict__ an, const int* __restrict__ src,
                                                const int* __restrict__ dst, const int* __restrict__ cidx,
                                                float* __restrict__ S, const int* __restrict__ flagp){
  __shared__ int Se[64], De[64], Ee[64];
  const int t = threadIdx.x;
  const int w = t >> 6, lane = t & 63;
  const int col = lane & 15, quad = lane >> 4;
  const int p0 = blockIdx.x * 64;
  if (t < 64){ const int e = cidx[p0 + t]; Ee[t] = e; Se[t] = src[e]; De[t] = dst[e]; }
  __syncthreads();
  const int fl = *flagp;
  const int ea = Ee[w*16 + col];
  bf16x8 a0, a1;
  if (fl){
    const u16* ap = (const u16*)ebd + (size_t)ea * 64;
    a0 = *(const bf16x8*)(ap + quad*8);
    a1 = *(const bf16x8*)(ap + 32 + quad*8);
  } else {
    const float* ap = (const float*)ebd + (size_t)ea * 64;
    union { u32 w_[4]; bf16x8 v; } u0, u1;
    #pragma unroll
    for (int i = 0; i < 4; i++){
      u0.w_[i] = pkbf(ap[quad*8 + 2*i],      ap[quad*8 + 2*i + 1]);
      u1.w_[i] = pkbf(ap[32 + quad*8 + 2*i], ap[32 + quad*8 + 2*i + 1]);
    }
    a0 = u0.v; a1 = u1.v;
  }
  const u16* brow = we1b + (size_t)col * 64;
  const bf16x8 b0 = *(const bf16x8*)(brow + quad*8);
  const bf16x8 b1 = *(const bf16x8*)(brow + 32 + quad*8);
  f32x4 acc = (f32x4){0.f, 0.f, 0.f, 0.f};
  acc = __builtin_amdgcn_mfma_f32_16x16x32_bf16(a0, b0, acc, 0, 0, 0);
  acc = __builtin_amdgcn_mfma_f32_16x16x32_bf16(a1, b1, acc, 0, 0, 0);
  if (col < 8){
    #pragma unroll
    for (int i = 0; i < 4; i++){
      const int rl = w*16 + quad*4 + i;
      S[(size_t)(p0 + rl) * 8 + col] = leaky(an[Se[rl]*16 + col] + acc[i] + an[De[rl]*16 + 8 + col]);
    }
  }
}

// layer-1 segment softmax -> alpha. One WAVE per node; lanes = (edge-slot i0,
// head h): coalesced S reads, shfl_xor(8/16/32) segment reduce.
__global__ __launch_bounds__(256) void segalpha_pos_k(const float* __restrict__ S, const int* __restrict__ rp,
                                                      float* __restrict__ AL){
  const int node = blockIdx.x * 4 + (threadIdx.x >> 6);
  const int l = threadIdx.x & 63;
  const int h = l & 7, i0 = l >> 3;
  const int beg = rp[node], end = rp[node + 1];
  float m = -1e30f, z = 0.f;
  for (int base = beg; base < end; base += 8){
    const int idx = base + i0;
    float v = -1e30f, cc = 0.f;
    if (idx < end){ v = S[(size_t)idx * 8 + h]; cc = 1.f; }
    lse_merge(m, z, v, cc);
  }
  #pragma unroll
  for (int off = 8; off < 64; off <<= 1){
    float om = __shfl_xor(m, off), oz = __shfl_xor(z, off);
    lse_merge(m, z, om, oz);
  }
  const float rz = 1.f / fmaxf(z, 1e-9f);
  for (int base = beg; base < end; base += 8){
    const int idx = base + i0;
    if (idx < end)
      AL[(size_t)idx * 8 + h] = __expf(S[(size_t)idx * 8 + h] - m) * rz;
  }
}

// g1 — block per node; alphas by pos; bf16 output
__global__ __launch_bounds__(256) void g1b_k(const float* __restrict__ AL, const u16* __restrict__ Ub,
                                             const int* __restrict__ rp, const int* __restrict__ cidx,
                                             u16* __restrict__ G1b){
  const int n = blockIdx.x;
  const int t = threadIdx.x;
  const int d = t & 63, hh = t >> 6;
  const int beg = rp[n], end = rp[n + 1];
  float a0 = 0.f, a1 = 0.f;
  for (int idx = beg; idx < end; idx++){
    const int e = cidx[idx];
    const float uv = bf2f(Ub[(size_t)e * 64 + d]);
    a0 = fmaf(AL[(size_t)idx * 8 + hh],     uv, a0);
    a1 = fmaf(AL[(size_t)idx * 8 + hh + 4], uv, a1);
  }
  G1b[(size_t)(n * 8 + hh)     * 64 + d] = f2bf(a0);
  G1b[(size_t)(n * 8 + hh + 4) * 64 + d] = f2bf(a1);
}

// nft1 MFMA — HNA stored bf16
__global__ __launch_bounds__(256) void nft1m_k(const u16* __restrict__ G1b, const u16* __restrict__ W1T,
                                               u16* __restrict__ HNA){
  const int t = threadIdx.x;
  const int w = t >> 6, lane = t & 63;
  const int col = lane & 15, quad = lane >> 4;
  const int h = blockIdx.y;
  const int nl0 = blockIdx.x * 32;
  const int mt = (w & 1) * 16;
  const int nb = (w >> 1) * 2;
  const u16* arow = G1b + ((size_t)(nl0 + mt + col) * 8 + h) * 64;
  const bf16x8 a0 = *(const bf16x8*)(arow + quad*8);
  const bf16x8 a1 = *(const bf16x8*)(arow + 32 + quad*8);
  #pragma unroll
  for (int nn = 0; nn < 2; nn++){
    const int nt = nb + nn;
    const u16* brow = W1T + (size_t)(h*64 + nt*16 + col) * 64;
    const bf16x8 b0 = *(const bf16x8*)(brow + quad*8);
    const bf16x8 b1 = *(const bf16x8*)(brow + 32 + quad*8);
    f32x4 acc = (f32x4){0.f, 0.f, 0.f, 0.f};
    acc = __builtin_amdgcn_mfma_f32_16x16x32_bf16(a0, b0, acc, 0, 0, 0);
    acc = __builtin_amdgcn_mfma_f32_16x16x32_bf16(a1, b1, acc, 0, 0, 0);
    #pragma unroll
    for (int i = 0; i < 4; i++)
      HNA[(size_t)(nl0 + mt + quad*4 + i) * 512 + h*64 + nt*16 + col] = f2bf(eluf(acc[i]));
  }
}

// y3: pure-MFMA Y build — PAIR version (32768 edges per dispatch, grid 1024)
__global__ __launch_bounds__(256) void y3_k(const u16* __restrict__ Ub, const float* __restrict__ AL1,
                                            const u16* __restrict__ HNA, const u16* __restrict__ W1T,
                                            const int* __restrict__ src, const int* __restrict__ cidx,
                                            u16* __restrict__ Y, const int s2){
  __shared__ __align__(16) u16 Us[32][72];
  __shared__ float als[256];
  __shared__ int Es[32], Ss[32];
  const int t = threadIdx.x;
  const int w = t >> 6, lane = t & 63;
  const int col = lane & 15, quad = lane >> 4;
  const int mw = (w & 1) * 16;
  const int hw = (w >> 1) * 4;
  const int ep0 = s2 * 32768 + blockIdx.x * 32;
  if (t < 32){ const int e = cidx[ep0 + t]; Es[t] = e; Ss[t] = src[e]; }
  als[t] = AL1[(size_t)ep0 * 8 + t];
  __syncthreads();
  {
    const int r = t >> 3, seg = (t & 7) * 8;
    *(ushort4*)&Us[r][seg]     = *(const ushort4*)(Ub + (size_t)Es[r] * 64 + seg);
    *(ushort4*)&Us[r][seg + 4] = *(const ushort4*)(Ub + (size_t)Es[r] * 64 + seg + 4);
  }
  __syncthreads();
  const bf16x8 a0 = *(const bf16x8*)&Us[mw + col][quad*8];
  const bf16x8 a1 = *(const bf16x8*)&Us[mw + col][32 + quad*8];
  #pragma unroll
  for (int hh = 0; hh < 4; hh++){
    const int h = hw + hh;
    #pragma unroll
    for (int nt = 0; nt < 4; nt++){
      const u16* brow = W1T + (size_t)(h*64 + nt*16 + col) * 64;
      const bf16x8 b0 = *(const bf16x8*)(brow + quad*8);
      const bf16x8 b1 = *(const bf16x8*)(brow + 32 + quad*8);
      f32x4 acc = (f32x4){0.f, 0.f, 0.f, 0.f};
      acc = __builtin_amdgcn_mfma_f32_16x16x32_bf16(a0, b0, acc, 0, 0, 0);
      acc = __builtin_amdgcn_mfma_f32_16x16x32_bf16(a1, b1, acc, 0, 0, 0);
      #pragma unroll
      for (int i = 0; i < 4; i++){
        const int er = mw + quad*4 + i;
        const float v = eluf(als[er*8 + h] * acc[i])
                      + bf2f(HNA[(size_t)Ss[er] * 512 + h*64 + nt*16 + col]);
        Y[(size_t)(blockIdx.x*32 + er) * 512 + h*64 + nt*16 + col] = f2bf(v);
      }
    }
  }
}

// score2: layer-2 raw scores via MFMA — PAIR version (grid 512)
__global__ __launch_bounds__(256) void score2_k(const u16* __restrict__ Y, const u16* __restrict__ we2b,
                                                const float* __restrict__ AN2, const int* __restrict__ src,
                                                const int* __restrict__ dst, const int* __restrict__ cidx,
                                                float* __restrict__ SA, const int s2){
  __shared__ int Se[64], De[64];
  const int t = threadIdx.x;
  const int w = t >> 6, lane = t & 63;
  const int col = lane & 15, quad = lane >> 4;
  const int p0 = blockIdx.x * 64;            // local row in pair buffer
  const int gbase = s2 * 32768;
  if (t < 64){ const int e = cidx[gbase + p0 + t]; Se[t] = src[e]; De[t] = dst[e]; }
  __syncthreads();
  const u16* arow = Y + (size_t)(p0 + w*16 + col) * 512;
  const u16* brow = we2b + (size_t)col * 512;
  f32x4 acc = (f32x4){0.f, 0.f, 0.f, 0.f};
  #pragma unroll
  for (int ks = 0; ks < 16; ks++){
    const bf16x8 a = *(const bf16x8*)(arow + ks*32 + quad*8);
    const bf16x8 b = *(const bf16x8*)(brow + ks*32 + quad*8);
    acc = __builtin_amdgcn_mfma_f32_16x16x32_bf16(a, b, acc, 0, 0, 0);
  }
  if (col < 8){
    #pragma unroll
    for (int i = 0; i < 4; i++){
      const int rl = w*16 + quad*4 + i;
      const size_t pos = gbase + p0 + rl;
      SA[pos * 8 + col] = leaky(AN2[Se[rl]*16 + col] + acc[i] + AN2[De[rl]*16 + 8 + col]);
    }
  }
}

// sg2: softmax (from SA) + aggregation, block per node; Y indexed in pair buf
__global__ __launch_bounds__(256) void sg2_k(const u16* __restrict__ Y, const int* __restrict__ rp,
                                             const float* __restrict__ SA, u16* __restrict__ G2,
                                             const int s){
  __shared__ float sc[64][8];
  __shared__ float mh[8], rzh[8];
  const int t = threadIdx.x;
  const int nl = blockIdx.x;
  const int n = s * 2048 + nl;
  const int beg = rp[n], end = rp[n + 1], m = end - beg;
  const int base = (s >> 1) * 32768;         // pair-buffer global-pos base
  const bool small = (m <= 64);
  {
    const int h = t >> 5, l32 = t & 31;
    float mm = -1e30f, zz = 0.f;
    for (int i = l32; i < m; i += 32)
      lse_merge(mm, zz, SA[(size_t)(beg + i) * 8 + h], 1.f);
    #pragma unroll
    for (int off = 1; off < 32; off <<= 1){
      const float om = __shfl_xor(mm, off), oz = __shfl_xor(zz, off);
      lse_merge(mm, zz, om, oz);
    }
    if (l32 == 0){ mh[h] = mm; rzh[h] = 1.f / fmaxf(zz, 1e-9f); }
  }
  __syncthreads();
  if (small){
    for (int idx = t; idx < m * 8; idx += 256){
      const int i = idx >> 3, h = idx & 7;
      sc[i][h] = __expf(SA[(size_t)(beg + i) * 8 + h] - mh[h]) * rzh[h];
    }
  }
  __syncthreads();
  {
    const int d0 = t * 2;
    float ac[8][2] = {{0.f}};
    for (int i = 0; i < m; i++){
      const int epl = beg + i - base;
      const u32 yv = *(const u32*)(Y + (size_t)epl * 512 + d0);
      const float y0 = bf2f((u16)(yv & 0xffffu)), y1 = bf2f((u16)(yv >> 16));
      float al[8];
      if (small){
        #pragma unroll
        for (int h = 0; h < 8; h++) al[h] = sc[i][h];
      } else {
        #pragma unroll
        for (int h = 0; h < 8; h++)
          al[h] = __expf(SA[(size_t)(beg + i) * 8 + h] - mh[h]) * rzh[h];
      }
      #pragma unroll
      for (int h = 0; h < 8; h++){
        ac[h][0] = fmaf(al[h], y0, ac[h][0]);
        ac[h][1] = fmaf(al[h], y1, ac[h][1]);
      }
    }
    #pragma unroll
    for (int h = 0; h < 8; h++){
      const u32 o = (u32)f2bf(ac[h][0]) | ((u32)f2bf(ac[h][1]) << 16);
      *(u32*)(G2 + ((size_t)nl * 8 + h) * 512 + d0) = o;
    }
  }
}

// nft2 MFMA
__global__ __launch_bounds__(256) void nft2m_k(const u16* __restrict__ G2, const u16* __restrict__ W2T,
                                               u16* __restrict__ HNB, const int s){
  const int t = threadIdx.x;
  const int w = t >> 6, lane = t & 63;
  const int col = lane & 15, quad = lane >> 4;
  const int h = blockIdx.y;
  const int nl0 = blockIdx.x * 32;
  const int mt = (w & 1) * 16;
  const int nb = (w >> 1) * 2;
  const u16* arow = G2 + ((size_t)((nl0 + mt + col) * 8) + h) * 512;
  #pragma unroll
  for (int nn = 0; nn < 2; nn++){
    const int nt = nb + nn;
    const u16* brow = W2T + (size_t)(h*64 + nt*16 + col) * 512;
    f32x4 acc = (f32x4){0.f, 0.f, 0.f, 0.f};
    #pragma unroll
    for (int ks = 0; ks < 16; ks++){
      const bf16x8 a = *(const bf16x8*)(arow + ks*32 + quad*8);
      const bf16x8 b = *(const bf16x8*)(brow + ks*32 + quad*8);
      acc = __builtin_amdgcn_mfma_f32_16x16x32_bf16(a, b, acc, 0, 0, 0);
    }
    #pragma unroll
    for (int i = 0; i < 4; i++)
      HNB[(size_t)(s*2048 + nl0 + mt + quad*4 + i) * 512 + h*64 + nt*16 + col] = f2bf(eluf(acc[i]));
  }
}

// ---------------------------------- CSR -------------------------------------
__global__ __launch_bounds__(256) void hist_k(const int* __restrict__ dst, int* __restrict__ deg){
  const int e = blockIdx.x * 256 + threadIdx.x;
  if (e < NEd) atomicAdd(&deg[dst[e]], 1);
}
// parallel prefix: per-thread chunk sum -> shfl_up wave scan -> wave combine
__global__ __launch_bounds__(256) void scan_k(const int* __restrict__ deg, int* __restrict__ rp,
                                              int* __restrict__ fill){
  __shared__ int wsum[4];
  const int t = threadIdx.x;
  const int lane = t & 63, wid = t >> 6;
  const int base = t * 64;
  int s = 0;
  for (int i = 0; i < 64; i++) s += deg[base + i];
  int v = s;
  #pragma unroll
  for (int off = 1; off < 64; off <<= 1){
    const int u = __shfl_up(v, off);
    if (lane >= off) v += u;
  }
  if (lane == 63) wsum[wid] = v;
  __syncthreads();
  int add = 0;
  #pragma unroll
  for (int wq = 0; wq < 4; wq++) if (wq < wid) add += wsum[wq];
  int off0 = add + v - s;   // exclusive prefix for this thread's 64-chunk
  for (int i = 0; i < 64; i++){
    rp[base + i] = off0; fill[base + i] = off0;
    off0 += deg[base + i];
  }
  if (t == 255) rp[NNd] = off0;
}
__global__ __launch_bounds__(256) void scatter_k(const int* __restrict__ dst, int* __restrict__ fill,
                                                 int* __restrict__ cidx){
  const int e = blockIdx.x * 256 + threadIdx.x;
  if (e < NEd){
    int pos = atomicAdd(&fill[dst[e]], 1);
    cidx[pos] = e;
  }
}

// ------------------------------- readout ------------------------------------
// mean via atomics: 256 blocks (sg x 8 chunks of 64 rows); xcat pre-zeroed
__global__ __launch_bounds__(256) void mean_k(const u16* __restrict__ HNB, float* __restrict__ xcat){
  const int sg = blockIdx.x >> 3, chunk = blockIdx.x & 7;
  const int t = threadIdx.x;
  const int g = (sg < 16) ? sg : sg - 16;
  const int half = (sg < 16) ? 0 : 1;
  const int c0 = t * 2;
  float s0 = 0.f, s1 = 0.f;
  const u16* base = HNB + ((size_t)sg * 512 + chunk * 64) * 512;
  for (int n = 0; n < 64; n++){
    const u32 u = *(const u32*)(base + (size_t)n * 512 + c0);
    s0 += bf2f((u16)(u & 0xffffu));
    s1 += bf2f((u16)(u >> 16));
  }
  atomicAdd(&xcat[g * 1024 + half * 512 + c0],     s0 * (1.f / 512.f));
  atomicAdd(&xcat[g * 1024 + half * 512 + c0 + 1], s1 * (1.f / 512.f));
}

// FC1 with BN1 fused (per-block recomputed column stats; xcat stays raw means)
__global__ __launch_bounds__(256) void fc1_k(const float* __restrict__ xcat, const float* __restrict__ wf,
                                             float* __restrict__ y1g){
  __shared__ float xs[1024];
  __shared__ float ps[4][64];
  const int t = threadIdx.x, g = blockIdx.x;
  for (int j = t; j < 1024; j += 256){
    float mu = 0.f;
    #pragma unroll
    for (int gg = 0; gg < 16; gg++) mu += xcat[gg * 1024 + j];
    mu *= (1.f / 16.f);
    float var = 0.f;
    #pragma unroll
    for (int gg = 0; gg < 16; gg++){ const float d = xcat[gg * 1024 + j] - mu; var += d * d; }
    var *= (1.f / 16.f);
    const float sc = rsqrtf(var + 1e-5f) * wf[WO_B1G + j];
    xs[j] = (xcat[g * 1024 + j] - mu) * sc + wf[WO_B1B + j];
  }
  __syncthreads();
  const int c = t & 63, kq = t >> 6;
  float acc = 0.f;
  #pragma unroll 4
  for (int k = kq * 256; k < kq * 256 + 256; k++)
    acc = fmaf(xs[k], wf[WO_F1W + k * 64 + c], acc);
  ps[kq][c] = acc;
  __syncthreads();
  if (t < 64){
    const float a = ps[0][t] + ps[1][t] + ps[2][t] + ps[3][t] + wf[WO_F1B + t];
    y1g[g * 64 + t] = fmaxf(a, 0.f);
  }
}

// BN2 + FC2 tail (tiny)
__global__ __launch_bounds__(256) void head2_k(const float* __restrict__ y1g, const float* __restrict__ wf,
                                               void* __restrict__ outp, const int* __restrict__ flagp){
  __shared__ float y1s[16][64];
  __shared__ float mu2s[64], sc2s[64];
  const int t = threadIdx.x;
  for (int i = t; i < 1024; i += 256) y1s[i >> 6][i & 63] = y1g[i];
  __syncthreads();
  if (t < 64){
    float mu = 0.f;
    #pragma unroll
    for (int g = 0; g < 16; g++) mu += y1s[g][t];
    mu *= (1.f / 16.f);
    float var = 0.f;
    #pragma unroll
    for (int g = 0; g < 16; g++){ const float d = y1s[g][t] - mu; var += d * d; }
    var *= (1.f / 16.f);
    mu2s[t] = mu; sc2s[t] = rsqrtf(var + 1e-5f) * wf[WO_B2G + t];
  }
  __syncthreads();
  if (t < 48){
    const int gg = t / 3, c = t % 3;
    float acc = wf[WO_F2B + c];
    #pragma unroll
    for (int k = 0; k < 64; k++){
      const float y2 = (y1s[gg][k] - mu2s[k]) * sc2s[k] + wf[WO_B2B + k];
      acc = fmaf(y2, wf[WO_F2W + k * 3 + c], acc);
    }
    if (*flagp) ((u16*)outp)[t] = f2bf(acc);
    else        ((float*)outp)[t] = acc;
  }
}

// --------------------------------- launch -----------------------------------
extern "C" void kernel_launch(void* const* d_in, const int* in_sizes, int n_in,
                              void* d_out, int out_size, void* d_ws, size_t ws_size,
                              hipStream_t stream) {
  (void)in_sizes; (void)n_in; (void)out_size;
  if (ws_size < WS_NEED) return;

  const int* src = (const int*)d_in[3];
  const int* dst = (const int*)d_in[4];
  char* w = (char*)d_ws;

  float* wf   = (float*)(w + OFF_WF);
  float* cb   = (float*)(w + OFF_CB);
  u16*   Ub   = (u16*)(w + OFF_U);
  u16*   W1T  = (u16*)(w + OFF_W1B);
  u16*   W2T  = (u16*)(w + OFF_W2B);
  u16*   we2b = (u16*)(w + OFF_WE2B);
  u16*   we1b = (u16*)(w + OFF_WE1B);
  float* AL1  = (float*)(w + OFF_AL1);
  float* SA   = (float*)(w + OFF_SA);
  u16*   HNA  = (u16*)(w + OFF_HNA);
  float* AN2  = (float*)(w + OFF_AN2);
  int*   deg  = (int*)(w + OFF_DEG);
  int*   rp   = (int*)(w + OFF_RP);
  int*   fill = (int*)(w + OFF_FILL);
  int*   cidx = (int*)(w + OFF_CIDX);
  float* rbig = (float*)(w + OFF_RBIG);
  float* xcat = (float*)(w + OFF_XCAT);
  int*   flag = (int*)(w + OFF_FLAG);

  float* x1a  = (float*)(w + OFF_T + T_X1A);
  float* x2a  = (float*)(w + OFF_T + T_X2A);
  float* hn0  = (float*)(w + OFF_T + T_HN0);
  float* AN1  = (float*)(w + OFF_T + T_AN1);
  float* S    = (float*)(w + OFF_T + T_S);
  u16*   Y    = (u16*)(w + OFF_T + T_Y);       // pair buffer, 32768 rows
  float* y1g  = (float*)(w + OFF_T + T_Y1G);   // readout scratch (after slices)

  float* pacc = rbig;                           // 8*8192*64*4 = 16.7MB
  float* pz   = (float*)(w + OFF_T + T_PZ);     // in hn0 slot during flash
  u16*   G1b  = (u16*)(w + OFF_RBIG);
  u16*   HNB  = (u16*)(w + OFF_RBIG);           // [0, 16.78MB)
  u16*   G2   = (u16*)(w + OFF_RBIG + R_G2);    // [16.78, 33.55MB) — exact fit

  // 0. detect + weights + combos
  detect_k<<<1, 256, 0, stream>>>((const u16*)d_in[0], flag);
  P17 ps;
  for (int i = 0; i < 17; i++) ps.p[i] = d_in[6 + i];
  convw_k<<<(WO_END + 255) / 256, 256, 0, stream>>>(ps, wf, flag);
  wprep_k<<<(294912 + CB_END + 4096 + 512 + 255) / 256, 256, 0, stream>>>(wf, W1T, W2T, cb, we2b, we1b);

  // 1. CSR over dst
  hipMemsetAsync(deg, 0, NNd * sizeof(int), stream);
  hist_k<<<NEd / 256, 256, 0, stream>>>(dst, deg);
  scan_k<<<1, 256, 0, stream>>>(deg, rp, fill);
  scatter_k<<<NEd / 256, 256, 0, stream>>>(dst, fill, cidx);

  // 2. alignment (swapped 32x32 MFMA flash, 8 key-splits)
  flash_mfma_k<<<dim3(64, KSPLIT), 256, 0, stream>>>(d_in[0], d_in[1], flag, pacc, pz);
  flash_merge_k<<<NSd / 4, 256, 0, stream>>>(pacc, pz, x1a);
  flash_mfma_k<<<dim3(64, KSPLIT), 256, 0, stream>>>(d_in[1], d_in[0], flag, pacc, pz);
  flash_merge_k<<<NSd / 4, 256, 0, stream>>>(pacc, pz, x2a);

  // 3. projection
  proj_k<<<NNd / 64, 256, 0, stream>>>(d_in[0], d_in[1], x1a, x2a, wf, hn0, flag);

  // 4. GAT layer 1 (usan merge; MFMA scores; wave-softmax; g1 aggregation)
  usan_k<<<8192 + 1024, 256, 0, stream>>>(d_in[2], hn0, src, Ub, cb + CB_WC1, AN1, flag);
  score1_k<<<NEd / 64, 256, 0, stream>>>(d_in[2], we1b, AN1, src, dst, cidx, S, flag);
  segalpha_pos_k<<<NNd / 4, 256, 0, stream>>>(S, rp, AL1);
  g1b_k<<<NNd, 256, 0, stream>>>(AL1, Ub, rp, cidx, G1b);
  nft1m_k<<<dim3(NNd / 32, 8), 256, 0, stream>>>(G1b, W1T, HNA);

  // 5. layer-2 per-node combos
  anw_k<<<NNd / 64, 256, 0, stream>>>(HNA, cb + CB_WC2, AN2);

  // 6. layer-2: 4 slice-pairs x (y3, score2) + per-slice (sg2, nft2m)
  for (int s2 = 0; s2 < 4; s2++){
    y3_k<<<1024, 256, 0, stream>>>(Ub, AL1, HNA, W1T, src, cidx, Y, s2);
    score2_k<<<512, 256, 0, stream>>>(Y, we2b, AN2, src, dst, cidx, SA, s2);
    for (int sub = 0; sub < 2; sub++){
      const int s = s2 * 2 + sub;
      sg2_k<<<2048, 256, 0, stream>>>(Y, rp, SA, G2, s);
      nft2m_k<<<dim3(64, 8), 256, 0, stream>>>(G2, W2T, HNB, s);
    }
  }

  // 7. readout (mean via atomics -> fused BN1+FC1 -> BN2+FC2)
  hipMemsetAsync(xcat, 0, 16 * 1024 * sizeof(float), stream);
  mean_k<<<256, 256, 0, stream>>>(HNB, xcat);
  fc1_k<<<16, 256, 0, stream>>>(xcat, wf, y1g);
  head2_k<<<1, 256, 0, stream>>>(y1g, wf, d_out, flag);
}

// Round 11
// 803.912 us; speedup vs baseline: 1.0747x; 1.0187x over previous
//
#include <hip/hip_runtime.h>

// GATClassifier on MI355X — round 20: merge the two independent flash
// directions into ONE dispatch (blockIdx.z picks Q/K roles + pacc half).
// 1024 blocks = 4/CU: dispatch tails amortize and barrier stalls of the two
// directions interleave — the co-residency r12 chased, without r12's
// doubled-write confound (per-block work/traffic unchanged). Merges also
// combined (dim3(2048,2)). 2x pacc = exactly RBIG (G2/HNB live later).
// xcat memset hoisted. Everything else = r19/r17 proven structure.

#define NSd 8192
#define NNd 16384
#define NEd 131072
#define KSPLIT 8

typedef unsigned short u16;
typedef unsigned int   u32;
typedef short bf16x8 __attribute__((ext_vector_type(8)));
typedef float f32x4  __attribute__((ext_vector_type(4)));
typedef float f32x16 __attribute__((ext_vector_type(16)));

__device__ __forceinline__ float bf2f(u16 u){ return __uint_as_float(((u32)u) << 16); }
__device__ __forceinline__ u16 f2bf(float f){
  u32 u = __float_as_uint(f);
  u += 0x7fffu + ((u >> 16) & 1u);
  return (u16)(u >> 16);
}
__device__ __forceinline__ u32 pkbf(float a, float b){
  u32 r;
  asm("v_cvt_pk_bf16_f32 %0, %1, %2" : "=v"(r) : "v"(a), "v"(b));
  return r;
}
__device__ __forceinline__ void pl32swap(u32& a, u32& b){
  auto r = __builtin_amdgcn_permlane32_swap(a, b, false, false);
  a = r[0]; b = r[1];
}
__device__ __forceinline__ float eluf(float x){ return x > 0.f ? x : expm1f(x); }
__device__ __forceinline__ float leaky(float x){ return x > 0.f ? x : 0.2f * x; }
__device__ __forceinline__ float ldin(const void* p, size_t i, int fl){
  return fl ? bf2f(((const u16*)p)[i]) : ((const float*)p)[i];
}
__device__ __forceinline__ void lse_merge(float& m, float& z, float om, float oz){
  float M = fmaxf(m, om);
  z = z * __expf(m - M) + oz * __expf(om - M);
  m = M;
}

// ------------------------- workspace layout (bytes) -------------------------
static constexpr size_t OFF_WF   = 0;
static constexpr size_t OFF_CB   = 1529600;
static constexpr size_t OFF_U    = 1584896;      // 131072*64 bf16 (Ub)
static constexpr size_t OFF_W1B  = 18362112;     // W1T bf16
static constexpr size_t OFF_W2B  = 18427648;     // W2T bf16
static constexpr size_t OFF_WE2B = 18951936;     // 16*512 bf16 (padded WE2)
static constexpr size_t OFF_WE1B = 18968320;     // 16*64 bf16 (padded WE1)
static constexpr size_t OFF_AL1  = 35139328;     // 131072*8 f32 (by CSR pos)
static constexpr size_t OFF_SA   = 39333632;     // 131072*8 f32 (layer-2 scores)
static constexpr size_t OFF_HNA  = 43527936;     // 16384*512 bf16 (16.78MB)
static constexpr size_t OFF_AN2  = 60305152;     // 16384*16 f32 (in freed HNA tail)
static constexpr size_t OFF_DEG  = 77082368;
static constexpr size_t OFF_RP   = 77147904;
static constexpr size_t OFF_FILL = 77213696;
static constexpr size_t OFF_CIDX = 77279232;
static constexpr size_t OFF_RBIG = 77803520;     // pacc x2 (33.55M) | G1b | HNB+G2
static constexpr size_t OFF_T    = 111357952;    // 32MB union (Y pair in layer 2)
static constexpr size_t OFF_XCAT = 144912384;
static constexpr size_t OFF_FLAG = 144977920;
static constexpr size_t WS_NEED  = 144978176;

static constexpr size_t T_X1A = 0;
static constexpr size_t T_X2A = 2097152;
static constexpr size_t T_HN0 = 4194304;
static constexpr size_t T_PZ  = 4194304;         // pz x2 during flash (hn0 slot)
static constexpr size_t T_AN1 = 8388608;
static constexpr size_t T_S   = 9437184;
static constexpr size_t T_Y   = 0;               // 32768*512 bf16 (slice PAIR, full T)
static constexpr size_t T_Y1G = 0;               // 16*64 f32 (readout, after slices)
static constexpr size_t R_G2  = 16777216;        // RBIG-relative, 2048*8*512 bf16

static constexpr size_t PACC_STRIDE = (size_t)KSPLIT * NSd * 64;   // floats per dir
static constexpr size_t PZ_STRIDE   = (size_t)KSPLIT * NSd;        // floats per dir

static constexpr int WO_PROJ = 0,      WO_W1 = 16384;
static constexpr int WO_AL1 = 49152,   WO_AR1 = 49664,  WO_AE1 = 50176;
static constexpr int WO_W2  = 50688;
static constexpr int WO_AL2 = 312832,  WO_AR2 = 313344, WO_AE2 = 313856;
static constexpr int WO_B1G = 314368,  WO_B1B = 315392;
static constexpr int WO_F1W = 316416,  WO_F1B = 381952;
static constexpr int WO_B2G = 382016,  WO_B2B = 382080;
static constexpr int WO_F2W = 382144,  WO_F2B = 382336;
static constexpr int WO_END = 382339;

static constexpr int CB_WC1 = 0;
static constexpr int CB_WE1 = 1024;
static constexpr int CB_WC2 = 1536;   // rows 0..7 = W2*(al2-ae2)
static constexpr int CB_WE2 = 9728;
static constexpr int CB_END = 13824;

// ------------------------------- dtype detect -------------------------------
__global__ __launch_bounds__(256) void detect_k(const u16* __restrict__ p, int* __restrict__ flag){
  __shared__ int bad;
  if (threadIdx.x == 0) bad = 0;
  __syncthreads();
  int b = 0;
  for (int i = threadIdx.x; i < 1024; i += 256){
    float f = bf2f(p[i]);
    if (!(fabsf(f) <= 100.f)) b++;
  }
  atomicAdd(&bad, b);
  __syncthreads();
  if (threadIdx.x == 0) *flag = (bad == 0) ? 1 : 0;
}

struct P17 { const void* p[17]; };

__global__ __launch_bounds__(256) void convw_k(P17 ps, float* __restrict__ wf, const int* __restrict__ flagp){
  const int i = blockIdx.x * 256 + threadIdx.x;
  if (i >= WO_END) return;
  const int fl = *flagp;
  const int ends[17] = {16384,49152,49664,50176,50688,312832,313344,313856,314368,
                        315392,316416,381952,382016,382080,382144,382336,382339};
  int seg = 0;
  while (i >= ends[seg]) seg++;
  const int start = seg ? ends[seg-1] : 0;
  wf[i] = ldin(ps.p[seg], i - start, fl);
}

// merged: W1T + W2T transposes, combos, WE pads — one dispatch after convw
__global__ __launch_bounds__(256) void wprep_k(const float* __restrict__ wf, u16* __restrict__ w1t,
                                               u16* __restrict__ w2t, float* __restrict__ cb,
                                               u16* __restrict__ we2b, u16* __restrict__ we1b){
  const int i = blockIdx.x * 256 + threadIdx.x;
  if (i < 32768){
    const int c = i >> 6, k = i & 63;
    w1t[i] = f2bf(wf[WO_W1 + k * 512 + c]);
    return;
  }
  if (i < 294912){
    const int j = i - 32768;
    const int c = j >> 9, k = j & 511;
    w2t[j] = f2bf(wf[WO_W2 + k * 512 + c]);
    return;
  }
  const int j = i - 294912;
  if (j >= CB_END + 4096 + 512) return;
  if (j >= CB_END + 4096){ we1b[512 + (j - CB_END - 4096)] = 0; return; }
  if (j >= CB_END){ we2b[4096 + (j - CB_END)] = 0; return; }
  float acc = 0.f;
  if (j < 1024){
    const int o = j >> 6, d = j & 63, h = o & 7;
    const float* a = wf + ((o >> 3) ? WO_AR1 : WO_AL1) + h * 64;
    for (int dp = 0; dp < 64; dp++) acc += wf[WO_W1 + d * 512 + h * 64 + dp] * a[dp];
    cb[CB_WC1 + j] = acc;
  } else if (j < 1536){
    const int jj = j - 1024, h = jj >> 6, d = jj & 63;
    for (int dp = 0; dp < 64; dp++) acc += wf[WO_W1 + d * 512 + h * 64 + dp] * wf[WO_AE1 + h * 64 + dp];
    cb[CB_WE1 + jj] = acc;
    we1b[jj] = f2bf(acc);
  } else if (j < 9728){
    const int jj = j - 1536, o = jj >> 9, c = jj & 511, h = o & 7;
    for (int dp = 0; dp < 64; dp++){
      const float av = (o >> 3) ? wf[WO_AR2 + h * 64 + dp]
                                : (wf[WO_AL2 + h * 64 + dp] - wf[WO_AE2 + h * 64 + dp]);
      acc += wf[WO_W2 + c * 512 + h * 64 + dp] * av;
    }
    cb[CB_WC2 + jj] = acc;
  } else {
    const int jj = j - 9728, h = jj >> 9, c = jj & 511;
    for (int dp = 0; dp < 64; dp++) acc += wf[WO_W2 + c * 512 + h * 64 + dp] * wf[WO_AE2 + h * 64 + dp];
    cb[CB_WE2 + jj] = acc;
    we2b[jj] = f2bf(acc);
  }
}

// --------------------------- flash alignment (MFMA) -------------------------
// Swapped-operand 32x32x16 flash (r11 body). BOTH directions in one dispatch:
// blockIdx.z = dir picks Q/K roles and the pacc/pz half. 1024 blocks = 4/CU.
__global__ __launch_bounds__(256) void flash_mfma_k(const void* __restrict__ p0, const void* __restrict__ p1,
                                                    const int* __restrict__ flagp, float* __restrict__ pacc,
                                                    float* __restrict__ pz){
  const int fl = *flagp;
  const int dir = blockIdx.z;
  const void* Qp = dir ? p1 : p0;
  const void* Kp = dir ? p0 : p1;
  pacc += (size_t)dir * PACC_STRIDE;
  pz   += (size_t)dir * PZ_STRIDE;
  __shared__ __align__(16) u16 Ks[2][32][64];   // row-major, 16B slots XOR (row&7)
  __shared__ __align__(16) u16 Kt[2][64][40];   // transposed [d][kc], pitch 40 (16B aligned)
  const int t = threadIdx.x;
  const int w = t >> 6, l = t & 63;
  const int hi = l >> 5, ql = l & 31;
  const int q0 = blockIdx.x * 128;
  const int kbeg = blockIdx.y * 1024;
  // staging roles
  const int sr = t & 31, scg = t >> 5;   // Ks: row sr, cols scg*8..+7
  const int kp = t & 15, dq = t >> 4;    // Kt: k-rows 2kp,2kp+1, d 4dq..+3

  // Q fragments (B operand), held in registers for the whole kernel
  bf16x8 bq[4];
  {
    const int qrow = q0 + w * 32 + ql;
    if (fl){
      const u16* qp = (const u16*)Qp + (size_t)qrow * 64 + hi * 8;
      #pragma unroll
      for (int s = 0; s < 4; s++) bq[s] = *(const bf16x8*)(qp + s * 16);
    } else {
      const float* qp = (const float*)Qp + (size_t)qrow * 64 + hi * 8;
      #pragma unroll
      for (int s = 0; s < 4; s++){
        union { u32 w_[4]; bf16x8 v; } u;
        #pragma unroll
        for (int i = 0; i < 4; i++) u.w_[i] = pkbf(qp[s*16 + 2*i], qp[s*16 + 2*i + 1]);
        bq[s] = u.v;
      }
    }
  }

  f32x16 accO0, accO1;
  #pragma unroll
  for (int i = 0; i < 16; i++){ accO0[i] = 0.f; accO1[i] = 0.f; }
  float lsum = 0.f;

  // prologue: stage tile 0 -> buffer 0
  {
    const int kr = kbeg;
    if (fl){
      const u16* kb = (const u16*)Kp + (size_t)kr * 64;
      const uint4 s0 = *(const uint4*)(kb + (size_t)sr * 64 + scg * 8);
      const uint2 a0 = *(const uint2*)(kb + (size_t)(2*kp) * 64 + dq * 4);
      const uint2 b0 = *(const uint2*)(kb + (size_t)(2*kp + 1) * 64 + dq * 4);
      *(uint4*)((char*)&Ks[0][sr][0] + ((scg * 16) ^ ((sr & 7) << 4))) = s0;
      const u16* pa = (const u16*)&a0; const u16* pb = (const u16*)&b0;
      #pragma unroll
      for (int i = 0; i < 4; i++)
        *(u32*)&Kt[0][4*dq + i][2*kp] = (u32)pa[i] | ((u32)pb[i] << 16);
    } else {
      const float* kf = (const float*)Kp + (size_t)kr * 64;
      const float4 f0 = *(const float4*)(kf + (size_t)sr * 64 + scg * 8);
      const float4 f1 = *(const float4*)(kf + (size_t)sr * 64 + scg * 8 + 4);
      const float4 fa = *(const float4*)(kf + (size_t)(2*kp) * 64 + dq * 4);
      const float4 fb = *(const float4*)(kf + (size_t)(2*kp + 1) * 64 + dq * 4);
      union { u32 w_[4]; uint4 q; } uu;
      uu.w_[0] = pkbf(f0.x, f0.y); uu.w_[1] = pkbf(f0.z, f0.w);
      uu.w_[2] = pkbf(f1.x, f1.y); uu.w_[3] = pkbf(f1.z, f1.w);
      *(uint4*)((char*)&Ks[0][sr][0] + ((scg * 16) ^ ((sr & 7) << 4))) = uu.q;
      const float* faf = &fa.x; const float* fbf = &fb.x;
      #pragma unroll
      for (int i = 0; i < 4; i++)
        *(u32*)&Kt[0][4*dq + i][2*kp] = pkbf(faf[i], fbf[i]);
    }
  }

  for (int it = 0; it < 32; it++){
    const int cur = it & 1;
    __syncthreads();   // staged tile `it` visible; previous compute done

    // T14: issue next-tile global loads early (latency hides under compute)
    uint4 nKs; uint2 nKa, nKb;
    float4 nKsf0, nKsf1, nKaf, nKbf;
    const bool nx = (it + 1 < 32);
    if (nx){
      const int kr = kbeg + (it + 1) * 32;
      if (fl){
        const u16* kb = (const u16*)Kp + (size_t)kr * 64;
        nKs = *(const uint4*)(kb + (size_t)sr * 64 + scg * 8);
        nKa = *(const uint2*)(kb + (size_t)(2*kp) * 64 + dq * 4);
        nKb = *(const uint2*)(kb + (size_t)(2*kp + 1) * 64 + dq * 4);
      } else {
        const float* kf = (const float*)Kp + (size_t)kr * 64;
        nKsf0 = *(const float4*)(kf + (size_t)sr * 64 + scg * 8);
        nKsf1 = *(const float4*)(kf + (size_t)sr * 64 + scg * 8 + 4);
        nKaf  = *(const float4*)(kf + (size_t)(2*kp) * 64 + dq * 4);
        nKbf  = *(const float4*)(kf + (size_t)(2*kp + 1) * 64 + dq * 4);
      }
    }

    // ---- S^T = K . Q^T over this 32-k-col tile ----
    f32x16 accS;
    #pragma unroll
    for (int i = 0; i < 16; i++) accS[i] = 0.f;
    #pragma unroll
    for (int s = 0; s < 4; s++){
      const int byo = (s * 32 + hi * 16) ^ ((ql & 7) << 4);
      const bf16x8 a = *(const bf16x8*)((const char*)&Ks[cur][ql][0] + byo);
      accS = __builtin_amdgcn_mfma_f32_32x32x16_bf16(a, bq[s], accS, 0, 0, 0);
    }
    // p = exp(s-32) = exp2(s*log2e - 46.166); lane-local denominator
    float p[16];
    #pragma unroll
    for (int r = 0; r < 16; r++) p[r] = exp2f(fmaf(accS[r], 1.44269504f, -46.1662413f));
    {
      const float s0 = (p[0] + p[1]) + (p[2] + p[3]);
      const float s1 = (p[4] + p[5]) + (p[6] + p[7]);
      const float s2 = (p[8] + p[9]) + (p[10] + p[11]);
      const float s3 = (p[12] + p[13]) + (p[14] + p[15]);
      lsum += (s0 + s1) + (s2 + s3);
    }
    // in-register P -> bf16 A-fragments (T12: cvt_pk + permlane32_swap)
    u32 pk_[8];
    #pragma unroll
    for (int j = 0; j < 4; j++){
      pk_[2*j]     = pkbf(p[4*j],     p[4*j + 1]);
      pk_[2*j + 1] = pkbf(p[4*j + 2], p[4*j + 3]);
    }
    pl32swap(pk_[0], pk_[2]); pl32swap(pk_[1], pk_[3]);
    pl32swap(pk_[4], pk_[6]); pl32swap(pk_[5], pk_[7]);
    union { u32 w_[4]; bf16x8 v; } ua, ub;
    ua.w_[0] = pk_[0]; ua.w_[1] = pk_[1]; ua.w_[2] = pk_[2]; ua.w_[3] = pk_[3];
    ub.w_[0] = pk_[4]; ub.w_[1] = pk_[5]; ub.w_[2] = pk_[6]; ub.w_[3] = pk_[7];
    // ---- O += P V ----
    {
      const u16* kt0 = &Kt[cur][ql][hi * 8];
      accO0 = __builtin_amdgcn_mfma_f32_32x32x16_bf16(ua.v, *(const bf16x8*)kt0, accO0, 0, 0, 0);
      accO0 = __builtin_amdgcn_mfma_f32_32x32x16_bf16(ub.v, *(const bf16x8*)(kt0 + 16), accO0, 0, 0, 0);
      const u16* kt1 = &Kt[cur][32 + ql][hi * 8];
      accO1 = __builtin_amdgcn_mfma_f32_32x32x16_bf16(ua.v, *(const bf16x8*)kt1, accO1, 0, 0, 0);
      accO1 = __builtin_amdgcn_mfma_f32_32x32x16_bf16(ub.v, *(const bf16x8*)(kt1 + 16), accO1, 0, 0, 0);
    }

    // store staged next tile into the other buffer (vmcnt lands here)
    if (nx){
      char* kd = (char*)&Ks[cur ^ 1][sr][0];
      const int byo = (scg * 16) ^ ((sr & 7) << 4);
      if (fl){
        *(uint4*)(kd + byo) = nKs;
        const u16* pa = (const u16*)&nKa; const u16* pb = (const u16*)&nKb;
        #pragma unroll
        for (int i = 0; i < 4; i++)
          *(u32*)&Kt[cur ^ 1][4*dq + i][2*kp] = (u32)pa[i] | ((u32)pb[i] << 16);
      } else {
        union { u32 w_[4]; uint4 q; } uu;
        uu.w_[0] = pkbf(nKsf0.x, nKsf0.y); uu.w_[1] = pkbf(nKsf0.z, nKsf0.w);
        uu.w_[2] = pkbf(nKsf1.x, nKsf1.y); uu.w_[3] = pkbf(nKsf1.z, nKsf1.w);
        *(uint4*)(kd + byo) = uu.q;
        const float* faf = &nKaf.x; const float* fbf = &nKbf.x;
        #pragma unroll
        for (int i = 0; i < 4; i++)
          *(u32*)&Kt[cur ^ 1][4*dq + i][2*kp] = pkbf(faf[i], fbf[i]);
      }
    }
  }

  // epilogue: O rows m = (r&3)+8*(r>>2)+4*hi; cols = 32*nt + ql
  const float zq = lsum + __shfl_xor(lsum, 32);
  const int rowb = q0 + w * 32;
  #pragma unroll
  for (int r = 0; r < 16; r++){
    const int m = (r & 3) + 8 * (r >> 2) + 4 * hi;
    float* pr = pacc + ((size_t)blockIdx.y * NSd + rowb + m) * 64;
    pr[ql]      = accO0[r];
    pr[32 + ql] = accO1[r];
  }
  if (hi == 0) pz[blockIdx.y * NSd + rowb + ql] = zq;
}

// merge both directions: blockIdx.y = dir
__global__ __launch_bounds__(256) void flash_merge_k(const float* __restrict__ pacc,
                                                     const float* __restrict__ pz,
                                                     float* __restrict__ x1a, float* __restrict__ x2a){
  const int t = threadIdx.x;
  const int dir = blockIdx.y;
  const float* pa = pacc + (size_t)dir * PACC_STRIDE;
  const float* pzd = pz + (size_t)dir * PZ_STRIDE;
  float* outp = dir ? x2a : x1a;
  const int r = blockIdx.x * 4 + (t >> 6);
  const int d = t & 63;
  float Zt = 0.f, v = 0.f;
  #pragma unroll
  for (int s = 0; s < KSPLIT; s++){
    Zt += pzd[s * NSd + r];
    v  += pa[((size_t)s * NSd + r) * 64 + d];
  }
  outp[(size_t)r * 64 + d] = v / Zt;
}

// ------------------------------- projection ---------------------------------
__global__ __launch_bounds__(256) void proj_k(const void* __restrict__ nbd1, const void* __restrict__ nbd2,
                                              const float* __restrict__ x1a, const float* __restrict__ x2a,
                                              const float* __restrict__ wf, float* __restrict__ hn0,
                                              const int* __restrict__ flagp){
  const int fl = *flagp;
  __shared__ float At[64][65], Bt[64][65];
  const int t = threadIdx.x, tx = t & 15, ty = t >> 4;
  const int m0 = blockIdx.x * 64;
  float acc[4][4] = {{0.f}};
  for (int kt = 0; kt < 256; kt += 64){
    __syncthreads();
    {
      const int i = t >> 2, c0 = (t & 3) * 16;
      const int mrow = m0 + i;
      const int side = mrow < NSd;
      const int mr = side ? mrow : mrow - NSd;
      const void* nb = side ? nbd1 : nbd2;
      const float* xa = side ? x1a : x2a;
      const int seg = kt >> 6;
      for (int c = 0; c < 16; c++){
        const int kk = c0 + c;
        const float nv = ldin(nb, (size_t)mr * 64 + kk, fl);
        const float av = xa[(size_t)mr * 64 + kk];
        At[i][kk] = (seg == 0) ? nv : (seg == 1) ? av : (seg == 2) ? (nv - av) : (nv * av);
      }
      const int kk = t >> 2;
      for (int c = 0; c < 16; c++) Bt[kk][c0 + c] = wf[WO_PROJ + (kt + kk) * 64 + c0 + c];
    }
    __syncthreads();
    #pragma unroll
    for (int k = 0; k < 64; k++){
      float a0 = At[ty*4+0][k], a1 = At[ty*4+1][k], a2 = At[ty*4+2][k], a3 = At[ty*4+3][k];
      float b0 = Bt[k][tx*4+0], b1 = Bt[k][tx*4+1], b2 = Bt[k][tx*4+2], b3 = Bt[k][tx*4+3];
      acc[0][0] = fmaf(a0,b0,acc[0][0]); acc[0][1] = fmaf(a0,b1,acc[0][1]); acc[0][2] = fmaf(a0,b2,acc[0][2]); acc[0][3] = fmaf(a0,b3,acc[0][3]);
      acc[1][0] = fmaf(a1,b0,acc[1][0]); acc[1][1] = fmaf(a1,b1,acc[1][1]); acc[1][2] = fmaf(a1,b2,acc[1][2]); acc[1][3] = fmaf(a1,b3,acc[1][3]);
      acc[2][0] = fmaf(a2,b0,acc[2][0]); acc[2][1] = fmaf(a2,b1,acc[2][1]); acc[2][2] = fmaf(a2,b2,acc[2][2]); acc[2][3] = fmaf(a2,b3,acc[2][3]);
      acc[3][0] = fmaf(a3,b0,acc[3][0]); acc[3][1] = fmaf(a3,b1,acc[3][1]); acc[3][2] = fmaf(a3,b2,acc[3][2]); acc[3][3] = fmaf(a3,b3,acc[3][3]);
    }
  }
  #pragma unroll
  for (int i = 0; i < 4; i++)
    #pragma unroll
    for (int j = 0; j < 4; j++)
      hn0[(size_t)(m0 + ty*4 + i) * 64 + tx*4 + j] = fmaxf(acc[i][j], 0.f);
}

// ---------------- merged U build + AN1 combos (grid branch) -----------------
__global__ __launch_bounds__(256) void usan_k(const void* __restrict__ ebd, const float* __restrict__ hn0,
                                              const int* __restrict__ src, u16* __restrict__ Ub,
                                              const float* __restrict__ wc, float* __restrict__ an,
                                              const int* __restrict__ flagp){
  const int b = blockIdx.x, t = threadIdx.x;
  if (b < 8192){
    const int fl = *flagp;
    const int id = b * 256 + t;
    const int e = id >> 4, q = id & 15, d0 = q * 4;
    const int sn = src[e];
    float ev[4];
    if (fl){
      const uint2 u = *(const uint2*)((const u16*)ebd + (size_t)e * 64 + d0);
      ev[0] = bf2f((u16)(u.x & 0xffffu)); ev[1] = bf2f((u16)(u.x >> 16));
      ev[2] = bf2f((u16)(u.y & 0xffffu)); ev[3] = bf2f((u16)(u.y >> 16));
    } else {
      const float4 f = *(const float4*)((const float*)ebd + (size_t)e * 64 + d0);
      ev[0] = f.x; ev[1] = f.y; ev[2] = f.z; ev[3] = f.w;
    }
    const float4 hv = *(const float4*)(hn0 + (size_t)sn * 64 + d0);
    ushort4 o;
    o.x = f2bf(ev[0] + hv.x); o.y = f2bf(ev[1] + hv.y);
    o.z = f2bf(ev[2] + hv.z); o.w = f2bf(ev[3] + hv.w);
    *(ushort4*)(Ub + (size_t)e * 64 + d0) = o;
  } else {
    const int id = (b - 8192) * 256 + t;   // < 262144
    const int n = id >> 4, o = id & 15;
    const float* row = hn0 + (size_t)n * 64;
    const float* wp = wc + o * 64;
    float acc = 0.f;
    for (int k = 0; k < 64; k += 4){
      const float4 r4 = *(const float4*)(row + k);
      const float4 w4 = *(const float4*)(wp + k);
      acc += r4.x*w4.x + r4.y*w4.y + r4.z*w4.z + r4.w*w4.w;
    }
    an[id] = acc;
  }
}

// AN2 tiled: 64 nodes/block, WC2 staged in LDS; HNA is bf16
__global__ __launch_bounds__(256) void anw_k(const u16* __restrict__ HNA, const float* __restrict__ wc,
                                             float* __restrict__ an){
  __shared__ float W[16][516];
  const int t = threadIdx.x;
  for (int i = t; i < 8192; i += 256) W[i >> 9][i & 511] = wc[i];
  __syncthreads();
  const int node = blockIdx.x * 64 + (t >> 2);
  const int cb0 = (t & 3) * 4;
  const u16* row = HNA + (size_t)node * 512;
  float acc[4] = {0.f, 0.f, 0.f, 0.f};
  for (int k = 0; k < 512; k += 4){
    const uint2 u = *(const uint2*)(row + k);
    const float r0 = bf2f((u16)(u.x & 0xffffu)), r1 = bf2f((u16)(u.x >> 16));
    const float r2 = bf2f((u16)(u.y & 0xffffu)), r3 = bf2f((u16)(u.y >> 16));
    #pragma unroll
    for (int j = 0; j < 4; j++){
      const float* wr = &W[cb0 + j][k];
      acc[j] += r0 * wr[0] + r1 * wr[1] + r2 * wr[2] + r3 * wr[3];
    }
  }
  #pragma unroll
  for (int j = 0; j < 4; j++) an[node * 16 + cb0 + j] = acc[j];
}

// score1: layer-1 raw scores via MFMA — S[pos][h] = leaky(AN1 + ebd.WE1)
__global__ __launch_bounds__(256) void score1_k(const void* __restrict__ ebd, const u16* __restrict__ we1b,
                                                const float* __restrict__ an, const int* __restrict__ src,
                                                const int* __restrict__ dst, const int* __restrict__ cidx,
                                                float* __restrict__ S, const int* __restrict__ flagp){
  __shared__ int Se[64], De[64], Ee[64];
  const int t = threadIdx.x;
  const int w = t >> 6, lane = t & 63;
  const int col = lane & 15, quad = lane >> 4;
  const int p0 = blockIdx.x * 64;
  if (t < 64){ const int e = cidx[p0 + t]; Ee[t] = e; Se[t] = src[e]; De[t] = dst[e]; }
  __syncthreads();
  const int fl = *flagp;
  const int ea = Ee[w*16 + col];
  bf16x8 a0, a1;
  if (fl){
    const u16* ap = (const u16*)ebd + (size_t)ea * 64;
    a0 = *(const bf16x8*)(ap + quad*8);
    a1 = *(const bf16x8*)(ap + 32 + quad*8);
  } else {
    const float* ap = (const float*)ebd + (size_t)ea * 64;
    union { u32 w_[4]; bf16x8 v; } u0, u1;
    #pragma unroll
    for (int i = 0; i < 4; i++){
      u0.w_[i] = pkbf(ap[quad*8 + 2*i],      ap[quad*8 + 2*i + 1]);
      u1.w_[i] = pkbf(ap[32 + quad*8 + 2*i], ap[32 + quad*8 + 2*i + 1]);
    }
    a0 = u0.v; a1 = u1.v;
  }
  const u16* brow = we1b + (size_t)col * 64;
  const bf16x8 b0 = *(const bf16x8*)(brow + quad*8);
  const bf16x8 b1 = *(const bf16x8*)(brow + 32 + quad*8);
  f32x4 acc = (f32x4){0.f, 0.f, 0.f, 0.f};
  acc = __builtin_amdgcn_mfma_f32_16x16x32_bf16(a0, b0, acc, 0, 0, 0);
  acc = __builtin_amdgcn_mfma_f32_16x16x32_bf16(a1, b1, acc, 0, 0, 0);
  if (col < 8){
    #pragma unroll
    for (int i = 0; i < 4; i++){
      const int rl = w*16 + quad*4 + i;
      S[(size_t)(p0 + rl) * 8 + col] = leaky(an[Se[rl]*16 + col] + acc[i] + an[De[rl]*16 + 8 + col]);
    }
  }
}

// layer-1 segment softmax -> alpha. One WAVE per node; lanes = (edge-slot i0,
// head h): coalesced S reads, shfl_xor(8/16/32) segment reduce.
__global__ __launch_bounds__(256) void segalpha_pos_k(const float* __restrict__ S, const int* __restrict__ rp,
                                                      float* __restrict__ AL){
  const int node = blockIdx.x * 4 + (threadIdx.x >> 6);
  const int l = threadIdx.x & 63;
  const int h = l & 7, i0 = l >> 3;
  const int beg = rp[node], end = rp[node + 1];
  float m = -1e30f, z = 0.f;
  for (int base = beg; base < end; base += 8){
    const int idx = base + i0;
    float v = -1e30f, cc = 0.f;
    if (idx < end){ v = S[(size_t)idx * 8 + h]; cc = 1.f; }
    lse_merge(m, z, v, cc);
  }
  #pragma unroll
  for (int off = 8; off < 64; off <<= 1){
    float om = __shfl_xor(m, off), oz = __shfl_xor(z, off);
    lse_merge(m, z, om, oz);
  }
  const float rz = 1.f / fmaxf(z, 1e-9f);
  for (int base = beg; base < end; base += 8){
    const int idx = base + i0;
    if (idx < end)
      AL[(size_t)idx * 8 + h] = __expf(S[(size_t)idx * 8 + h] - m) * rz;
  }
}

// g1 — block per node; alphas by pos; bf16 output
__global__ __launch_bounds__(256) void g1b_k(const float* __restrict__ AL, const u16* __restrict__ Ub,
                                             const int* __restrict__ rp, const int* __restrict__ cidx,
                                             u16* __restrict__ G1b){
  const int n = blockIdx.x;
  const int t = threadIdx.x;
  const int d = t & 63, hh = t >> 6;
  const int beg = rp[n], end = rp[n + 1];
  float a0 = 0.f, a1 = 0.f;
  for (int idx = beg; idx < end; idx++){
    const int e = cidx[idx];
    const float uv = bf2f(Ub[(size_t)e * 64 + d]);
    a0 = fmaf(AL[(size_t)idx * 8 + hh],     uv, a0);
    a1 = fmaf(AL[(size_t)idx * 8 + hh + 4], uv, a1);
  }
  G1b[(size_t)(n * 8 + hh)     * 64 + d] = f2bf(a0);
  G1b[(size_t)(n * 8 + hh + 4) * 64 + d] = f2bf(a1);
}

// nft1 MFMA — HNA stored bf16
__global__ __launch_bounds__(256) void nft1m_k(const u16* __restrict__ G1b, const u16* __restrict__ W1T,
                                               u16* __restrict__ HNA){
  const int t = threadIdx.x;
  const int w = t >> 6, lane = t & 63;
  const int col = lane & 15, quad = lane >> 4;
  const int h = blockIdx.y;
  const int nl0 = blockIdx.x * 32;
  const int mt = (w & 1) * 16;
  const int nb = (w >> 1) * 2;
  const u16* arow = G1b + ((size_t)(nl0 + mt + col) * 8 + h) * 64;
  const bf16x8 a0 = *(const bf16x8*)(arow + quad*8);
  const bf16x8 a1 = *(const bf16x8*)(arow + 32 + quad*8);
  #pragma unroll
  for (int nn = 0; nn < 2; nn++){
    const int nt = nb + nn;
    const u16* brow = W1T + (size_t)(h*64 + nt*16 + col) * 64;
    const bf16x8 b0 = *(const bf16x8*)(brow + quad*8);
    const bf16x8 b1 = *(const bf16x8*)(brow + 32 + quad*8);
    f32x4 acc = (f32x4){0.f, 0.f, 0.f, 0.f};
    acc = __builtin_amdgcn_mfma_f32_16x16x32_bf16(a0, b0, acc, 0, 0, 0);
    acc = __builtin_amdgcn_mfma_f32_16x16x32_bf16(a1, b1, acc, 0, 0, 0);
    #pragma unroll
    for (int i = 0; i < 4; i++)
      HNA[(size_t)(nl0 + mt + quad*4 + i) * 512 + h*64 + nt*16 + col] = f2bf(eluf(acc[i]));
  }
}

// y3: pure-MFMA Y build — PAIR version (32768 edges per dispatch, grid 1024)
__global__ __launch_bounds__(256) void y3_k(const u16* __restrict__ Ub, const float* __restrict__ AL1,
                                            const u16* __restrict__ HNA, const u16* __restrict__ W1T,
                                            const int* __restrict__ src, const int* __restrict__ cidx,
                                            u16* __restrict__ Y, const int s2){
  __shared__ __align__(16) u16 Us[32][72];
  __shared__ float als[256];
  __shared__ int Es[32], Ss[32];
  const int t = threadIdx.x;
  const int w = t >> 6, lane = t & 63;
  const int col = lane & 15, quad = lane >> 4;
  const int mw = (w & 1) * 16;
  const int hw = (w >> 1) * 4;
  const int ep0 = s2 * 32768 + blockIdx.x * 32;
  if (t < 32){ const int e = cidx[ep0 + t]; Es[t] = e; Ss[t] = src[e]; }
  als[t] = AL1[(size_t)ep0 * 8 + t];
  __syncthreads();
  {
    const int r = t >> 3, seg = (t & 7) * 8;
    *(ushort4*)&Us[r][seg]     = *(const ushort4*)(Ub + (size_t)Es[r] * 64 + seg);
    *(ushort4*)&Us[r][seg + 4] = *(const ushort4*)(Ub + (size_t)Es[r] * 64 + seg + 4);
  }
  __syncthreads();
  const bf16x8 a0 = *(const bf16x8*)&Us[mw + col][quad*8];
  const bf16x8 a1 = *(const bf16x8*)&Us[mw + col][32 + quad*8];
  #pragma unroll
  for (int hh = 0; hh < 4; hh++){
    const int h = hw + hh;
    #pragma unroll
    for (int nt = 0; nt < 4; nt++){
      const u16* brow = W1T + (size_t)(h*64 + nt*16 + col) * 64;
      const bf16x8 b0 = *(const bf16x8*)(brow + quad*8);
      const bf16x8 b1 = *(const bf16x8*)(brow + 32 + quad*8);
      f32x4 acc = (f32x4){0.f, 0.f, 0.f, 0.f};
      acc = __builtin_amdgcn_mfma_f32_16x16x32_bf16(a0, b0, acc, 0, 0, 0);
      acc = __builtin_amdgcn_mfma_f32_16x16x32_bf16(a1, b1, acc, 0, 0, 0);
      #pragma unroll
      for (int i = 0; i < 4; i++){
        const int er = mw + quad*4 + i;
        const float v = eluf(als[er*8 + h] * acc[i])
                      + bf2f(HNA[(size_t)Ss[er] * 512 + h*64 + nt*16 + col]);
        Y[(size_t)(blockIdx.x*32 + er) * 512 + h*64 + nt*16 + col] = f2bf(v);
      }
    }
  }
}

// score2: layer-2 raw scores via MFMA — PAIR version (grid 512)
__global__ __launch_bounds__(256) void score2_k(const u16* __restrict__ Y, const u16* __restrict__ we2b,
                                                const float* __restrict__ AN2, const int* __restrict__ src,
                                                const int* __restrict__ dst, const int* __restrict__ cidx,
                                                float* __restrict__ SA, const int s2){
  __shared__ int Se[64], De[64];
  const int t = threadIdx.x;
  const int w = t >> 6, lane = t & 63;
  const int col = lane & 15, quad = lane >> 4;
  const int p0 = blockIdx.x * 64;            // local row in pair buffer
  const int gbase = s2 * 32768;
  if (t < 64){ const int e = cidx[gbase + p0 + t]; Se[t] = src[e]; De[t] = dst[e]; }
  __syncthreads();
  const u16* arow = Y + (size_t)(p0 + w*16 + col) * 512;
  const u16* brow = we2b + (size_t)col * 512;
  f32x4 acc = (f32x4){0.f, 0.f, 0.f, 0.f};
  #pragma unroll
  for (int ks = 0; ks < 16; ks++){
    const bf16x8 a = *(const bf16x8*)(arow + ks*32 + quad*8);
    const bf16x8 b = *(const bf16x8*)(brow + ks*32 + quad*8);
    acc = __builtin_amdgcn_mfma_f32_16x16x32_bf16(a, b, acc, 0, 0, 0);
  }
  if (col < 8){
    #pragma unroll
    for (int i = 0; i < 4; i++){
      const int rl = w*16 + quad*4 + i;
      const size_t pos = gbase + p0 + rl;
      SA[pos * 8 + col] = leaky(AN2[Se[rl]*16 + col] + acc[i] + AN2[De[rl]*16 + 8 + col]);
    }
  }
}

// sg2: softmax (from SA) + aggregation, block per node; Y indexed in pair buf
__global__ __launch_bounds__(256) void sg2_k(const u16* __restrict__ Y, const int* __restrict__ rp,
                                             const float* __restrict__ SA, u16* __restrict__ G2,
                                             const int s){
  __shared__ float sc[64][8];
  __shared__ float mh[8], rzh[8];
  const int t = threadIdx.x;
  const int nl = blockIdx.x;
  const int n = s * 2048 + nl;
  const int beg = rp[n], end = rp[n + 1], m = end - beg;
  const int base = (s >> 1) * 32768;         // pair-buffer global-pos base
  const bool small = (m <= 64);
  {
    const int h = t >> 5, l32 = t & 31;
    float mm = -1e30f, zz = 0.f;
    for (int i = l32; i < m; i += 32)
      lse_merge(mm, zz, SA[(size_t)(beg + i) * 8 + h], 1.f);
    #pragma unroll
    for (int off = 1; off < 32; off <<= 1){
      const float om = __shfl_xor(mm, off), oz = __shfl_xor(zz, off);
      lse_merge(mm, zz, om, oz);
    }
    if (l32 == 0){ mh[h] = mm; rzh[h] = 1.f / fmaxf(zz, 1e-9f); }
  }
  __syncthreads();
  if (small){
    for (int idx = t; idx < m * 8; idx += 256){
      const int i = idx >> 3, h = idx & 7;
      sc[i][h] = __expf(SA[(size_t)(beg + i) * 8 + h] - mh[h]) * rzh[h];
    }
  }
  __syncthreads();
  {
    const int d0 = t * 2;
    float ac[8][2] = {{0.f}};
    for (int i = 0; i < m; i++){
      const int epl = beg + i - base;
      const u32 yv = *(const u32*)(Y + (size_t)epl * 512 + d0);
      const float y0 = bf2f((u16)(yv & 0xffffu)), y1 = bf2f((u16)(yv >> 16));
      float al[8];
      if (small){
        #pragma unroll
        for (int h = 0; h < 8; h++) al[h] = sc[i][h];
      } else {
        #pragma unroll
        for (int h = 0; h < 8; h++)
          al[h] = __expf(SA[(size_t)(beg + i) * 8 + h] - mh[h]) * rzh[h];
      }
      #pragma unroll
      for (int h = 0; h < 8; h++){
        ac[h][0] = fmaf(al[h], y0, ac[h][0]);
        ac[h][1] = fmaf(al[h], y1, ac[h][1]);
      }
    }
    #pragma unroll
    for (int h = 0; h < 8; h++){
      const u32 o = (u32)f2bf(ac[h][0]) | ((u32)f2bf(ac[h][1]) << 16);
      *(u32*)(G2 + ((size_t)nl * 8 + h) * 512 + d0) = o;
    }
  }
}

// nft2 MFMA
__global__ __launch_bounds__(256) void nft2m_k(const u16* __restrict__ G2, const u16* __restrict__ W2T,
                                               u16* __restrict__ HNB, const int s){
  const int t = threadIdx.x;
  const int w = t >> 6, lane = t & 63;
  const int col = lane & 15, quad = lane >> 4;
  const int h = blockIdx.y;
  const int nl0 = blockIdx.x * 32;
  const int mt = (w & 1) * 16;
  const int nb = (w >> 1) * 2;
  const u16* arow = G2 + ((size_t)((nl0 + mt + col) * 8) + h) * 512;
  #pragma unroll
  for (int nn = 0; nn < 2; nn++){
    const int nt = nb + nn;
    const u16* brow = W2T + (size_t)(h*64 + nt*16 + col) * 512;
    f32x4 acc = (f32x4){0.f, 0.f, 0.f, 0.f};
    #pragma unroll
    for (int ks = 0; ks < 16; ks++){
      const bf16x8 a = *(const bf16x8*)(arow + ks*32 + quad*8);
      const bf16x8 b = *(const bf16x8*)(brow + ks*32 + quad*8);
      acc = __builtin_amdgcn_mfma_f32_16x16x32_bf16(a, b, acc, 0, 0, 0);
    }
    #pragma unroll
    for (int i = 0; i < 4; i++)
      HNB[(size_t)(s*2048 + nl0 + mt + quad*4 + i) * 512 + h*64 + nt*16 + col] = f2bf(eluf(acc[i]));
  }
}

// ---------------------------------- CSR -------------------------------------
__global__ __launch_bounds__(256) void hist_k(const int* __restrict__ dst, int* __restrict__ deg){
  const int e = blockIdx.x * 256 + threadIdx.x;
  if (e < NEd) atomicAdd(&deg[dst[e]], 1);
}
// parallel prefix: per-thread chunk sum -> shfl_up wave scan -> wave combine
__global__ __launch_bounds__(256) void scan_k(const int* __restrict__ deg, int* __restrict__ rp,
                                              int* __restrict__ fill){
  __shared__ int wsum[4];
  const int t = threadIdx.x;
  const int lane = t & 63, wid = t >> 6;
  const int base = t * 64;
  int s = 0;
  for (int i = 0; i < 64; i++) s += deg[base + i];
  int v = s;
  #pragma unroll
  for (int off = 1; off < 64; off <<= 1){
    const int u = __shfl_up(v, off);
    if (lane >= off) v += u;
  }
  if (lane == 63) wsum[wid] = v;
  __syncthreads();
  int add = 0;
  #pragma unroll
  for (int wq = 0; wq < 4; wq++) if (wq < wid) add += wsum[wq];
  int off0 = add + v - s;   // exclusive prefix for this thread's 64-chunk
  for (int i = 0; i < 64; i++){
    rp[base + i] = off0; fill[base + i] = off0;
    off0 += deg[base + i];
  }
  if (t == 255) rp[NNd] = off0;
}
__global__ __launch_bounds__(256) void scatter_k(const int* __restrict__ dst, int* __restrict__ fill,
                                                 int* __restrict__ cidx){
  const int e = blockIdx.x * 256 + threadIdx.x;
  if (e < NEd){
    int pos = atomicAdd(&fill[dst[e]], 1);
    cidx[pos] = e;
  }
}

// ------------------------------- readout ------------------------------------
// mean via atomics: 256 blocks (sg x 8 chunks of 64 rows); xcat pre-zeroed
__global__ __launch_bounds__(256) void mean_k(const u16* __restrict__ HNB, float* __restrict__ xcat){
  const int sg = blockIdx.x >> 3, chunk = blockIdx.x & 7;
  const int t = threadIdx.x;
  const int g = (sg < 16) ? sg : sg - 16;
  const int half = (sg < 16) ? 0 : 1;
  const int c0 = t * 2;
  float s0 = 0.f, s1 = 0.f;
  const u16* base = HNB + ((size_t)sg * 512 + chunk * 64) * 512;
  for (int n = 0; n < 64; n++){
    const u32 u = *(const u32*)(base + (size_t)n * 512 + c0);
    s0 += bf2f((u16)(u & 0xffffu));
    s1 += bf2f((u16)(u >> 16));
  }
  atomicAdd(&xcat[g * 1024 + half * 512 + c0],     s0 * (1.f / 512.f));
  atomicAdd(&xcat[g * 1024 + half * 512 + c0 + 1], s1 * (1.f / 512.f));
}

// FC1 with BN1 fused (per-block recomputed column stats; xcat stays raw means)
__global__ __launch_bounds__(256) void fc1_k(const float* __restrict__ xcat, const float* __restrict__ wf,
                                             float* __restrict__ y1g){
  __shared__ float xs[1024];
  __shared__ float ps[4][64];
  const int t = threadIdx.x, g = blockIdx.x;
  for (int j = t; j < 1024; j += 256){
    float mu = 0.f;
    #pragma unroll
    for (int gg = 0; gg < 16; gg++) mu += xcat[gg * 1024 + j];
    mu *= (1.f / 16.f);
    float var = 0.f;
    #pragma unroll
    for (int gg = 0; gg < 16; gg++){ const float d = xcat[gg * 1024 + j] - mu; var += d * d; }
    var *= (1.f / 16.f);
    const float sc = rsqrtf(var + 1e-5f) * wf[WO_B1G + j];
    xs[j] = (xcat[g * 1024 + j] - mu) * sc + wf[WO_B1B + j];
  }
  __syncthreads();
  const int c = t & 63, kq = t >> 6;
  float acc = 0.f;
  #pragma unroll 4
  for (int k = kq * 256; k < kq * 256 + 256; k++)
    acc = fmaf(xs[k], wf[WO_F1W + k * 64 + c], acc);
  ps[kq][c] = acc;
  __syncthreads();
  if (t < 64){
    const float a = ps[0][t] + ps[1][t] + ps[2][t] + ps[3][t] + wf[WO_F1B + t];
    y1g[g * 64 + t] = fmaxf(a, 0.f);
  }
}

// BN2 + FC2 tail (tiny)
__global__ __launch_bounds__(256) void head2_k(const float* __restrict__ y1g, const float* __restrict__ wf,
                                               void* __restrict__ outp, const int* __restrict__ flagp){
  __shared__ float y1s[16][64];
  __shared__ float mu2s[64], sc2s[64];
  const int t = threadIdx.x;
  for (int i = t; i < 1024; i += 256) y1s[i >> 6][i & 63] = y1g[i];
  __syncthreads();
  if (t < 64){
    float mu = 0.f;
    #pragma unroll
    for (int g = 0; g < 16; g++) mu += y1s[g][t];
    mu *= (1.f / 16.f);
    float var = 0.f;
    #pragma unroll
    for (int g = 0; g < 16; g++){ const float d = y1s[g][t] - mu; var += d * d; }
    var *= (1.f / 16.f);
    mu2s[t] = mu; sc2s[t] = rsqrtf(var + 1e-5f) * wf[WO_B2G + t];
  }
  __syncthreads();
  if (t < 48){
    const int gg = t / 3, c = t % 3;
    float acc = wf[WO_F2B + c];
    #pragma unroll
    for (int k = 0; k < 64; k++){
      const float y2 = (y1s[gg][k] - mu2s[k]) * sc2s[k] + wf[WO_B2B + k];
      acc = fmaf(y2, wf[WO_F2W + k * 3 + c], acc);
    }
    if (*flagp) ((u16*)outp)[t] = f2bf(acc);
    else        ((float*)outp)[t] = acc;
  }
}

// --------------------------------- launch -----------------------------------
extern "C" void kernel_launch(void* const* d_in, const int* in_sizes, int n_in,
                              void* d_out, int out_size, void* d_ws, size_t ws_size,
                              hipStream_t stream) {
  (void)in_sizes; (void)n_in; (void)out_size;
  if (ws_size < WS_NEED) return;

  const int* src = (const int*)d_in[3];
  const int* dst = (const int*)d_in[4];
  char* w = (char*)d_ws;

  float* wf   = (float*)(w + OFF_WF);
  float* cb   = (float*)(w + OFF_CB);
  u16*   Ub   = (u16*)(w + OFF_U);
  u16*   W1T  = (u16*)(w + OFF_W1B);
  u16*   W2T  = (u16*)(w + OFF_W2B);
  u16*   we2b = (u16*)(w + OFF_WE2B);
  u16*   we1b = (u16*)(w + OFF_WE1B);
  float* AL1  = (float*)(w + OFF_AL1);
  float* SA   = (float*)(w + OFF_SA);
  u16*   HNA  = (u16*)(w + OFF_HNA);
  float* AN2  = (float*)(w + OFF_AN2);
  int*   deg  = (int*)(w + OFF_DEG);
  int*   rp   = (int*)(w + OFF_RP);
  int*   fill = (int*)(w + OFF_FILL);
  int*   cidx = (int*)(w + OFF_CIDX);
  float* rbig = (float*)(w + OFF_RBIG);
  float* xcat = (float*)(w + OFF_XCAT);
  int*   flag = (int*)(w + OFF_FLAG);

  float* x1a  = (float*)(w + OFF_T + T_X1A);
  float* x2a  = (float*)(w + OFF_T + T_X2A);
  float* hn0  = (float*)(w + OFF_T + T_HN0);
  float* AN1  = (float*)(w + OFF_T + T_AN1);
  float* S    = (float*)(w + OFF_T + T_S);
  u16*   Y    = (u16*)(w + OFF_T + T_Y);       // pair buffer, 32768 rows
  float* y1g  = (float*)(w + OFF_T + T_Y1G);   // readout scratch (after slices)

  float* pacc = rbig;                           // 2 x 16.78MB = full RBIG during flash
  float* pz   = (float*)(w + OFF_T + T_PZ);     // 2 x 256KB in hn0 slot during flash
  u16*   G1b  = (u16*)(w + OFF_RBIG);
  u16*   HNB  = (u16*)(w + OFF_RBIG);           // [0, 16.78MB)
  u16*   G2   = (u16*)(w + OFF_RBIG + R_G2);    // [16.78, 33.55MB)

  // 0. detect + weights + combos
  detect_k<<<1, 256, 0, stream>>>((const u16*)d_in[0], flag);
  P17 ps;
  for (int i = 0; i < 17; i++) ps.p[i] = d_in[6 + i];
  convw_k<<<(WO_END + 255) / 256, 256, 0, stream>>>(ps, wf, flag);
  wprep_k<<<(294912 + CB_END + 4096 + 512 + 255) / 256, 256, 0, stream>>>(wf, W1T, W2T, cb, we2b, we1b);

  // 1. CSR over dst
  hipMemsetAsync(deg, 0, NNd * sizeof(int), stream);
  hist_k<<<NEd / 256, 256, 0, stream>>>(dst, deg);
  scan_k<<<1, 256, 0, stream>>>(deg, rp, fill);
  scatter_k<<<NEd / 256, 256, 0, stream>>>(dst, fill, cidx);

  // 2. alignment: BOTH directions in one dispatch (z = dir), one merged merge
  flash_mfma_k<<<dim3(64, KSPLIT, 2), 256, 0, stream>>>(d_in[0], d_in[1], flag, pacc, pz);
  flash_merge_k<<<dim3(NSd / 4, 2), 256, 0, stream>>>(pacc, pz, x1a, x2a);

  // 3. projection
  proj_k<<<NNd / 64, 256, 0, stream>>>(d_in[0], d_in[1], x1a, x2a, wf, hn0, flag);

  // 4. GAT layer 1 (usan merge; MFMA scores; wave-softmax; g1 aggregation)
  usan_k<<<8192 + 1024, 256, 0, stream>>>(d_in[2], hn0, src, Ub, cb + CB_WC1, AN1, flag);
  score1_k<<<NEd / 64, 256, 0, stream>>>(d_in[2], we1b, AN1, src, dst, cidx, S, flag);
  segalpha_pos_k<<<NNd / 4, 256, 0, stream>>>(S, rp, AL1);
  g1b_k<<<NNd, 256, 0, stream>>>(AL1, Ub, rp, cidx, G1b);
  nft1m_k<<<dim3(NNd / 32, 8), 256, 0, stream>>>(G1b, W1T, HNA);

  // 5. layer-2 per-node combos (+ hoisted xcat clear)
  anw_k<<<NNd / 64, 256, 0, stream>>>(HNA, cb + CB_WC2, AN2);
  hipMemsetAsync(xcat, 0, 16 * 1024 * sizeof(float), stream);

  // 6. layer-2: 4 slice-pairs x (y3, score2) + per-slice (sg2, nft2m)
  for (int s2 = 0; s2 < 4; s2++){
    y3_k<<<1024, 256, 0, stream>>>(Ub, AL1, HNA, W1T, src, cidx, Y, s2);
    score2_k<<<512, 256, 0, stream>>>(Y, we2b, AN2, src, dst, cidx, SA, s2);
    for (int sub = 0; sub < 2; sub++){
      const int s = s2 * 2 + sub;
      sg2_k<<<2048, 256, 0, stream>>>(Y, rp, SA, G2, s);
      nft2m_k<<<dim3(64, 8), 256, 0, stream>>>(G2, W2T, HNB, s);
    }
  }

  // 7. readout (mean via atomics -> fused BN1+FC1 -> BN2+FC2)
  mean_k<<<256, 256, 0, stream>>>(HNB, xcat);
  fc1_k<<<16, 256, 0, stream>>>(xcat, wf, y1g);
  head2_k<<<1, 256, 0, stream>>>(y1g, wf, d_out, flag);
}

// Round 12
// 781.709 us; speedup vs baseline: 1.1052x; 1.0284x over previous
//
#include <hip/hip_runtime.h>

// GATClassifier on MI355X — round 21: proj -> MFMA (projm_k). Last VALU
// GEMM (M=16384,N=64,K=256, 537 MFLOP) converted to the verified score2/nft
// fragment pattern: wave = 16 rows x 64 cols, 8x mfma_16x16x32_bf16, A built
// in-register from nv/av segment combos (exact ks->segment mapping), B =
// projW^T bf16 (32KB, L1-hot; emitted by wprep). Flash merged-dispatch (r20,
// 117us confirmed) + rest frozen.

#define NSd 8192
#define NNd 16384
#define NEd 131072
#define KSPLIT 8

typedef unsigned short u16;
typedef unsigned int   u32;
typedef short bf16x8 __attribute__((ext_vector_type(8)));
typedef float f32x4  __attribute__((ext_vector_type(4)));
typedef float f32x16 __attribute__((ext_vector_type(16)));

__device__ __forceinline__ float bf2f(u16 u){ return __uint_as_float(((u32)u) << 16); }
__device__ __forceinline__ u16 f2bf(float f){
  u32 u = __float_as_uint(f);
  u += 0x7fffu + ((u >> 16) & 1u);
  return (u16)(u >> 16);
}
__device__ __forceinline__ u32 pkbf(float a, float b){
  u32 r;
  asm("v_cvt_pk_bf16_f32 %0, %1, %2" : "=v"(r) : "v"(a), "v"(b));
  return r;
}
__device__ __forceinline__ void pl32swap(u32& a, u32& b){
  auto r = __builtin_amdgcn_permlane32_swap(a, b, false, false);
  a = r[0]; b = r[1];
}
__device__ __forceinline__ float eluf(float x){ return x > 0.f ? x : expm1f(x); }
__device__ __forceinline__ float leaky(float x){ return x > 0.f ? x : 0.2f * x; }
__device__ __forceinline__ float ldin(const void* p, size_t i, int fl){
  return fl ? bf2f(((const u16*)p)[i]) : ((const float*)p)[i];
}
__device__ __forceinline__ void lse_merge(float& m, float& z, float om, float oz){
  float M = fmaxf(m, om);
  z = z * __expf(m - M) + oz * __expf(om - M);
  m = M;
}

// ------------------------- workspace layout (bytes) -------------------------
static constexpr size_t OFF_WF   = 0;
static constexpr size_t OFF_CB   = 1529600;
static constexpr size_t OFF_U    = 1584896;      // 131072*64 bf16 (Ub)
static constexpr size_t OFF_W1B  = 18362112;     // W1T bf16
static constexpr size_t OFF_W2B  = 18427648;     // W2T bf16
static constexpr size_t OFF_WE2B = 18951936;     // 16*512 bf16 (padded WE2)
static constexpr size_t OFF_WE1B = 18968320;     // 16*64 bf16 (padded WE1)
static constexpr size_t OFF_PWT  = 18970368;     // 64*256 bf16 (projW^T)
static constexpr size_t OFF_AL1  = 35139328;     // 131072*8 f32 (by CSR pos)
static constexpr size_t OFF_SA   = 39333632;     // 131072*8 f32 (layer-2 scores)
static constexpr size_t OFF_HNA  = 43527936;     // 16384*512 bf16 (16.78MB)
static constexpr size_t OFF_AN2  = 60305152;     // 16384*16 f32 (in freed HNA tail)
static constexpr size_t OFF_DEG  = 77082368;
static constexpr size_t OFF_RP   = 77147904;
static constexpr size_t OFF_FILL = 77213696;
static constexpr size_t OFF_CIDX = 77279232;
static constexpr size_t OFF_RBIG = 77803520;     // pacc x2 (33.55M) | G1b | HNB+G2
static constexpr size_t OFF_T    = 111357952;    // 32MB union (Y pair in layer 2)
static constexpr size_t OFF_XCAT = 144912384;
static constexpr size_t OFF_FLAG = 144977920;
static constexpr size_t WS_NEED  = 144978176;

static constexpr size_t T_X1A = 0;
static constexpr size_t T_X2A = 2097152;
static constexpr size_t T_HN0 = 4194304;
static constexpr size_t T_PZ  = 4194304;         // pz x2 during flash (hn0 slot)
static constexpr size_t T_AN1 = 8388608;
static constexpr size_t T_S   = 9437184;
static constexpr size_t T_Y   = 0;               // 32768*512 bf16 (slice PAIR, full T)
static constexpr size_t T_Y1G = 0;               // 16*64 f32 (readout, after slices)
static constexpr size_t R_G2  = 16777216;        // RBIG-relative, 2048*8*512 bf16

static constexpr size_t PACC_STRIDE = (size_t)KSPLIT * NSd * 64;   // floats per dir
static constexpr size_t PZ_STRIDE   = (size_t)KSPLIT * NSd;        // floats per dir

static constexpr int WO_PROJ = 0,      WO_W1 = 16384;
static constexpr int WO_AL1 = 49152,   WO_AR1 = 49664,  WO_AE1 = 50176;
static constexpr int WO_W2  = 50688;
static constexpr int WO_AL2 = 312832,  WO_AR2 = 313344, WO_AE2 = 313856;
static constexpr int WO_B1G = 314368,  WO_B1B = 315392;
static constexpr int WO_F1W = 316416,  WO_F1B = 381952;
static constexpr int WO_B2G = 382016,  WO_B2B = 382080;
static constexpr int WO_F2W = 382144,  WO_F2B = 382336;
static constexpr int WO_END = 382339;

static constexpr int CB_WC1 = 0;
static constexpr int CB_WE1 = 1024;
static constexpr int CB_WC2 = 1536;   // rows 0..7 = W2*(al2-ae2)
static constexpr int CB_WE2 = 9728;
static constexpr int CB_END = 13824;

// ------------------------------- dtype detect -------------------------------
__global__ __launch_bounds__(256) void detect_k(const u16* __restrict__ p, int* __restrict__ flag){
  __shared__ int bad;
  if (threadIdx.x == 0) bad = 0;
  __syncthreads();
  int b = 0;
  for (int i = threadIdx.x; i < 1024; i += 256){
    float f = bf2f(p[i]);
    if (!(fabsf(f) <= 100.f)) b++;
  }
  atomicAdd(&bad, b);
  __syncthreads();
  if (threadIdx.x == 0) *flag = (bad == 0) ? 1 : 0;
}

struct P17 { const void* p[17]; };

__global__ __launch_bounds__(256) void convw_k(P17 ps, float* __restrict__ wf, const int* __restrict__ flagp){
  const int i = blockIdx.x * 256 + threadIdx.x;
  if (i >= WO_END) return;
  const int fl = *flagp;
  const int ends[17] = {16384,49152,49664,50176,50688,312832,313344,313856,314368,
                        315392,316416,381952,382016,382080,382144,382336,382339};
  int seg = 0;
  while (i >= ends[seg]) seg++;
  const int start = seg ? ends[seg-1] : 0;
  wf[i] = ldin(ps.p[seg], i - start, fl);
}

// merged: transposes (W1T, W2T, projW^T), combos, WE pads — one dispatch
__global__ __launch_bounds__(256) void wprep_k(const float* __restrict__ wf, u16* __restrict__ w1t,
                                               u16* __restrict__ w2t, float* __restrict__ cb,
                                               u16* __restrict__ we2b, u16* __restrict__ we1b,
                                               u16* __restrict__ pwt){
  const int i = blockIdx.x * 256 + threadIdx.x;
  if (i < 32768){
    const int c = i >> 6, k = i & 63;
    w1t[i] = f2bf(wf[WO_W1 + k * 512 + c]);
    return;
  }
  if (i < 294912){
    const int j = i - 32768;
    const int c = j >> 9, k = j & 511;
    w2t[j] = f2bf(wf[WO_W2 + k * 512 + c]);
    return;
  }
  const int j = i - 294912;
  if (j >= 18432 + 16384) return;
  if (j >= 18432){
    const int p = j - 18432;          // pwt[c*256+k] = projW[k][c]
    const int c = p >> 8, k = p & 255;
    pwt[p] = f2bf(wf[WO_PROJ + k * 64 + c]);
    return;
  }
  if (j >= CB_END + 4096){ we1b[512 + (j - CB_END - 4096)] = 0; return; }
  if (j >= CB_END){ we2b[4096 + (j - CB_END)] = 0; return; }
  float acc = 0.f;
  if (j < 1024){
    const int o = j >> 6, d = j & 63, h = o & 7;
    const float* a = wf + ((o >> 3) ? WO_AR1 : WO_AL1) + h * 64;
    for (int dp = 0; dp < 64; dp++) acc += wf[WO_W1 + d * 512 + h * 64 + dp] * a[dp];
    cb[CB_WC1 + j] = acc;
  } else if (j < 1536){
    const int jj = j - 1024, h = jj >> 6, d = jj & 63;
    for (int dp = 0; dp < 64; dp++) acc += wf[WO_W1 + d * 512 + h * 64 + dp] * wf[WO_AE1 + h * 64 + dp];
    cb[CB_WE1 + jj] = acc;
    we1b[jj] = f2bf(acc);
  } else if (j < 9728){
    const int jj = j - 1536, o = jj >> 9, c = jj & 511, h = o & 7;
    for (int dp = 0; dp < 64; dp++){
      const float av = (o >> 3) ? wf[WO_AR2 + h * 64 + dp]
                                : (wf[WO_AL2 + h * 64 + dp] - wf[WO_AE2 + h * 64 + dp]);
      acc += wf[WO_W2 + c * 512 + h * 64 + dp] * av;
    }
    cb[CB_WC2 + jj] = acc;
  } else {
    const int jj = j - 9728, h = jj >> 9, c = jj & 511;
    for (int dp = 0; dp < 64; dp++) acc += wf[WO_W2 + c * 512 + h * 64 + dp] * wf[WO_AE2 + h * 64 + dp];
    cb[CB_WE2 + jj] = acc;
    we2b[jj] = f2bf(acc);
  }
}

// --------------------------- flash alignment (MFMA) -------------------------
// Swapped-operand 32x32x16 flash (r11 body). Both dirs in one dispatch (r20).
__global__ __launch_bounds__(256) void flash_mfma_k(const void* __restrict__ p0, const void* __restrict__ p1,
                                                    const int* __restrict__ flagp, float* __restrict__ pacc,
                                                    float* __restrict__ pz){
  const int fl = *flagp;
  const int dir = blockIdx.z;
  const void* Qp = dir ? p1 : p0;
  const void* Kp = dir ? p0 : p1;
  pacc += (size_t)dir * PACC_STRIDE;
  pz   += (size_t)dir * PZ_STRIDE;
  __shared__ __align__(16) u16 Ks[2][32][64];   // row-major, 16B slots XOR (row&7)
  __shared__ __align__(16) u16 Kt[2][64][40];   // transposed [d][kc], pitch 40 (16B aligned)
  const int t = threadIdx.x;
  const int w = t >> 6, l = t & 63;
  const int hi = l >> 5, ql = l & 31;
  const int q0 = blockIdx.x * 128;
  const int kbeg = blockIdx.y * 1024;
  // staging roles
  const int sr = t & 31, scg = t >> 5;   // Ks: row sr, cols scg*8..+7
  const int kp = t & 15, dq = t >> 4;    // Kt: k-rows 2kp,2kp+1, d 4dq..+3

  // Q fragments (B operand), held in registers for the whole kernel
  bf16x8 bq[4];
  {
    const int qrow = q0 + w * 32 + ql;
    if (fl){
      const u16* qp = (const u16*)Qp + (size_t)qrow * 64 + hi * 8;
      #pragma unroll
      for (int s = 0; s < 4; s++) bq[s] = *(const bf16x8*)(qp + s * 16);
    } else {
      const float* qp = (const float*)Qp + (size_t)qrow * 64 + hi * 8;
      #pragma unroll
      for (int s = 0; s < 4; s++){
        union { u32 w_[4]; bf16x8 v; } u;
        #pragma unroll
        for (int i = 0; i < 4; i++) u.w_[i] = pkbf(qp[s*16 + 2*i], qp[s*16 + 2*i + 1]);
        bq[s] = u.v;
      }
    }
  }

  f32x16 accO0, accO1;
  #pragma unroll
  for (int i = 0; i < 16; i++){ accO0[i] = 0.f; accO1[i] = 0.f; }
  float lsum = 0.f;

  // prologue: stage tile 0 -> buffer 0
  {
    const int kr = kbeg;
    if (fl){
      const u16* kb = (const u16*)Kp + (size_t)kr * 64;
      const uint4 s0 = *(const uint4*)(kb + (size_t)sr * 64 + scg * 8);
      const uint2 a0 = *(const uint2*)(kb + (size_t)(2*kp) * 64 + dq * 4);
      const uint2 b0 = *(const uint2*)(kb + (size_t)(2*kp + 1) * 64 + dq * 4);
      *(uint4*)((char*)&Ks[0][sr][0] + ((scg * 16) ^ ((sr & 7) << 4))) = s0;
      const u16* pa = (const u16*)&a0; const u16* pb = (const u16*)&b0;
      #pragma unroll
      for (int i = 0; i < 4; i++)
        *(u32*)&Kt[0][4*dq + i][2*kp] = (u32)pa[i] | ((u32)pb[i] << 16);
    } else {
      const float* kf = (const float*)Kp + (size_t)kr * 64;
      const float4 f0 = *(const float4*)(kf + (size_t)sr * 64 + scg * 8);
      const float4 f1 = *(const float4*)(kf + (size_t)sr * 64 + scg * 8 + 4);
      const float4 fa = *(const float4*)(kf + (size_t)(2*kp) * 64 + dq * 4);
      const float4 fb = *(const float4*)(kf + (size_t)(2*kp + 1) * 64 + dq * 4);
      union { u32 w_[4]; uint4 q; } uu;
      uu.w_[0] = pkbf(f0.x, f0.y); uu.w_[1] = pkbf(f0.z, f0.w);
      uu.w_[2] = pkbf(f1.x, f1.y); uu.w_[3] = pkbf(f1.z, f1.w);
      *(uint4*)((char*)&Ks[0][sr][0] + ((scg * 16) ^ ((sr & 7) << 4))) = uu.q;
      const float* faf = &fa.x; const float* fbf = &fb.x;
      #pragma unroll
      for (int i = 0; i < 4; i++)
        *(u32*)&Kt[0][4*dq + i][2*kp] = pkbf(faf[i], fbf[i]);
    }
  }

  for (int it = 0; it < 32; it++){
    const int cur = it & 1;
    __syncthreads();   // staged tile `it` visible; previous compute done

    // T14: issue next-tile global loads early (latency hides under compute)
    uint4 nKs; uint2 nKa, nKb;
    float4 nKsf0, nKsf1, nKaf, nKbf;
    const bool nx = (it + 1 < 32);
    if (nx){
      const int kr = kbeg + (it + 1) * 32;
      if (fl){
        const u16* kb = (const u16*)Kp + (size_t)kr * 64;
        nKs = *(const uint4*)(kb + (size_t)sr * 64 + scg * 8);
        nKa = *(const uint2*)(kb + (size_t)(2*kp) * 64 + dq * 4);
        nKb = *(const uint2*)(kb + (size_t)(2*kp + 1) * 64 + dq * 4);
      } else {
        const float* kf = (const float*)Kp + (size_t)kr * 64;
        nKsf0 = *(const float4*)(kf + (size_t)sr * 64 + scg * 8);
        nKsf1 = *(const float4*)(kf + (size_t)sr * 64 + scg * 8 + 4);
        nKaf  = *(const float4*)(kf + (size_t)(2*kp) * 64 + dq * 4);
        nKbf  = *(const float4*)(kf + (size_t)(2*kp + 1) * 64 + dq * 4);
      }
    }

    // ---- S^T = K . Q^T over this 32-k-col tile ----
    f32x16 accS;
    #pragma unroll
    for (int i = 0; i < 16; i++) accS[i] = 0.f;
    #pragma unroll
    for (int s = 0; s < 4; s++){
      const int byo = (s * 32 + hi * 16) ^ ((ql & 7) << 4);
      const bf16x8 a = *(const bf16x8*)((const char*)&Ks[cur][ql][0] + byo);
      accS = __builtin_amdgcn_mfma_f32_32x32x16_bf16(a, bq[s], accS, 0, 0, 0);
    }
    // p = exp(s-32) = exp2(s*log2e - 46.166); lane-local denominator
    float p[16];
    #pragma unroll
    for (int r = 0; r < 16; r++) p[r] = exp2f(fmaf(accS[r], 1.44269504f, -46.1662413f));
    {
      const float s0 = (p[0] + p[1]) + (p[2] + p[3]);
      const float s1 = (p[4] + p[5]) + (p[6] + p[7]);
      const float s2 = (p[8] + p[9]) + (p[10] + p[11]);
      const float s3 = (p[12] + p[13]) + (p[14] + p[15]);
      lsum += (s0 + s1) + (s2 + s3);
    }
    // in-register P -> bf16 A-fragments (T12: cvt_pk + permlane32_swap)
    u32 pk_[8];
    #pragma unroll
    for (int j = 0; j < 4; j++){
      pk_[2*j]     = pkbf(p[4*j],     p[4*j + 1]);
      pk_[2*j + 1] = pkbf(p[4*j + 2], p[4*j + 3]);
    }
    pl32swap(pk_[0], pk_[2]); pl32swap(pk_[1], pk_[3]);
    pl32swap(pk_[4], pk_[6]); pl32swap(pk_[5], pk_[7]);
    union { u32 w_[4]; bf16x8 v; } ua, ub;
    ua.w_[0] = pk_[0]; ua.w_[1] = pk_[1]; ua.w_[2] = pk_[2]; ua.w_[3] = pk_[3];
    ub.w_[0] = pk_[4]; ub.w_[1] = pk_[5]; ub.w_[2] = pk_[6]; ub.w_[3] = pk_[7];
    // ---- O += P V ----
    {
      const u16* kt0 = &Kt[cur][ql][hi * 8];
      accO0 = __builtin_amdgcn_mfma_f32_32x32x16_bf16(ua.v, *(const bf16x8*)kt0, accO0, 0, 0, 0);
      accO0 = __builtin_amdgcn_mfma_f32_32x32x16_bf16(ub.v, *(const bf16x8*)(kt0 + 16), accO0, 0, 0, 0);
      const u16* kt1 = &Kt[cur][32 + ql][hi * 8];
      accO1 = __builtin_amdgcn_mfma_f32_32x32x16_bf16(ua.v, *(const bf16x8*)kt1, accO1, 0, 0, 0);
      accO1 = __builtin_amdgcn_mfma_f32_32x32x16_bf16(ub.v, *(const bf16x8*)(kt1 + 16), accO1, 0, 0, 0);
    }

    // store staged next tile into the other buffer (vmcnt lands here)
    if (nx){
      char* kd = (char*)&Ks[cur ^ 1][sr][0];
      const int byo = (scg * 16) ^ ((sr & 7) << 4);
      if (fl){
        *(uint4*)(kd + byo) = nKs;
        const u16* pa = (const u16*)&nKa; const u16* pb = (const u16*)&nKb;
        #pragma unroll
        for (int i = 0; i < 4; i++)
          *(u32*)&Kt[cur ^ 1][4*dq + i][2*kp] = (u32)pa[i] | ((u32)pb[i] << 16);
      } else {
        union { u32 w_[4]; uint4 q; } uu;
        uu.w_[0] = pkbf(nKsf0.x, nKsf0.y); uu.w_[1] = pkbf(nKsf0.z, nKsf0.w);
        uu.w_[2] = pkbf(nKsf1.x, nKsf1.y); uu.w_[3] = pkbf(nKsf1.z, nKsf1.w);
        *(uint4*)(kd + byo) = uu.q;
        const float* faf = &nKaf.x; const float* fbf = &nKbf.x;
        #pragma unroll
        for (int i = 0; i < 4; i++)
          *(u32*)&Kt[cur ^ 1][4*dq + i][2*kp] = pkbf(faf[i], fbf[i]);
      }
    }
  }

  // epilogue: O rows m = (r&3)+8*(r>>2)+4*hi; cols = 32*nt + ql
  const float zq = lsum + __shfl_xor(lsum, 32);
  const int rowb = q0 + w * 32;
  #pragma unroll
  for (int r = 0; r < 16; r++){
    const int m = (r & 3) + 8 * (r >> 2) + 4 * hi;
    float* pr = pacc + ((size_t)blockIdx.y * NSd + rowb + m) * 64;
    pr[ql]      = accO0[r];
    pr[32 + ql] = accO1[r];
  }
  if (hi == 0) pz[blockIdx.y * NSd + rowb + ql] = zq;
}

// merge both directions: blockIdx.y = dir
__global__ __launch_bounds__(256) void flash_merge_k(const float* __restrict__ pacc,
                                                     const float* __restrict__ pz,
                                                     float* __restrict__ x1a, float* __restrict__ x2a){
  const int t = threadIdx.x;
  const int dir = blockIdx.y;
  const float* pa = pacc + (size_t)dir * PACC_STRIDE;
  const float* pzd = pz + (size_t)dir * PZ_STRIDE;
  float* outp = dir ? x2a : x1a;
  const int r = blockIdx.x * 4 + (t >> 6);
  const int d = t & 63;
  float Zt = 0.f, v = 0.f;
  #pragma unroll
  for (int s = 0; s < KSPLIT; s++){
    Zt += pzd[s * NSd + r];
    v  += pa[((size_t)s * NSd + r) * 64 + d];
  }
  outp[(size_t)r * 64 + d] = v / Zt;
}

// ------------------- projection via MFMA (M=16384,N=64,K=256) ---------------
// A built in-register: k segments [nv | av | nv-av | nv*av], fragments ks=0..7
// map exactly onto segments (32-chunks never cross 64-boundaries). B = projW^T
// bf16 (32KB, L1-hot). Same verified fragment pattern as score2/nft kernels.
__global__ __launch_bounds__(256) void projm_k(const void* __restrict__ nbd1, const void* __restrict__ nbd2,
                                               const float* __restrict__ x1a, const float* __restrict__ x2a,
                                               const u16* __restrict__ pwt, float* __restrict__ hn0,
                                               const int* __restrict__ flagp){
  const int fl = *flagp;
  const int t = threadIdx.x;
  const int w = t >> 6, lane = t & 63;
  const int col = lane & 15, quad = lane >> 4;
  const int m0 = blockIdx.x * 64;
  const int mrow = m0 + w * 16 + col;
  const int side = (mrow < NSd) ? 1 : 0;
  const int mr = side ? mrow : mrow - NSd;
  const float* xa = (side ? x1a : x2a) + (size_t)mr * 64;
  float nv[16], av[16];
  union { u32 w_[4]; bf16x8 v; uint4 q; } af[8];
  if (fl){
    const u16* np = (const u16*)(side ? nbd1 : nbd2) + (size_t)mr * 64;
    af[0].q = *(const uint4*)(np + quad * 8);
    af[1].q = *(const uint4*)(np + 32 + quad * 8);
    const u16* s0 = (const u16*)&af[0].q;
    const u16* s1 = (const u16*)&af[1].q;
    #pragma unroll
    for (int j = 0; j < 8; j++){ nv[j] = bf2f(s0[j]); nv[8 + j] = bf2f(s1[j]); }
  } else {
    const float* np = (const float*)(side ? nbd1 : nbd2) + (size_t)mr * 64;
    #pragma unroll
    for (int j = 0; j < 8; j++){ nv[j] = np[quad*8 + j]; nv[8 + j] = np[32 + quad*8 + j]; }
    #pragma unroll
    for (int j = 0; j < 4; j++){
      af[0].w_[j] = pkbf(nv[2*j], nv[2*j + 1]);
      af[1].w_[j] = pkbf(nv[8 + 2*j], nv[8 + 2*j + 1]);
    }
  }
  #pragma unroll
  for (int j = 0; j < 8; j++){ av[j] = xa[quad*8 + j]; av[8 + j] = xa[32 + quad*8 + j]; }
  #pragma unroll
  for (int j = 0; j < 4; j++){
    af[2].w_[j] = pkbf(av[2*j], av[2*j + 1]);
    af[3].w_[j] = pkbf(av[8 + 2*j], av[8 + 2*j + 1]);
    af[4].w_[j] = pkbf(nv[2*j] - av[2*j], nv[2*j + 1] - av[2*j + 1]);
    af[5].w_[j] = pkbf(nv[8 + 2*j] - av[8 + 2*j], nv[8 + 2*j + 1] - av[8 + 2*j + 1]);
    af[6].w_[j] = pkbf(nv[2*j] * av[2*j], nv[2*j + 1] * av[2*j + 1]);
    af[7].w_[j] = pkbf(nv[8 + 2*j] * av[8 + 2*j], nv[8 + 2*j + 1] * av[8 + 2*j + 1]);
  }
  #pragma unroll
  for (int nt = 0; nt < 4; nt++){
    const u16* brow = pwt + (size_t)(nt * 16 + col) * 256;
    f32x4 acc = (f32x4){0.f, 0.f, 0.f, 0.f};
    #pragma unroll
    for (int ks = 0; ks < 8; ks++){
      const bf16x8 b = *(const bf16x8*)(brow + ks * 32 + quad * 8);
      acc = __builtin_amdgcn_mfma_f32_16x16x32_bf16(af[ks].v, b, acc, 0, 0, 0);
    }
    #pragma unroll
    for (int i = 0; i < 4; i++)
      hn0[(size_t)(m0 + w*16 + quad*4 + i) * 64 + nt*16 + col] = fmaxf(acc[i], 0.f);
  }
}

// ---------------- merged U build + AN1 combos (grid branch) -----------------
__global__ __launch_bounds__(256) void usan_k(const void* __restrict__ ebd, const float* __restrict__ hn0,
                                              const int* __restrict__ src, u16* __restrict__ Ub,
                                              const float* __restrict__ wc, float* __restrict__ an,
                                              const int* __restrict__ flagp){
  const int b = blockIdx.x, t = threadIdx.x;
  if (b < 8192){
    const int fl = *flagp;
    const int id = b * 256 + t;
    const int e = id >> 4, q = id & 15, d0 = q * 4;
    const int sn = src[e];
    float ev[4];
    if (fl){
      const uint2 u = *(const uint2*)((const u16*)ebd + (size_t)e * 64 + d0);
      ev[0] = bf2f((u16)(u.x & 0xffffu)); ev[1] = bf2f((u16)(u.x >> 16));
      ev[2] = bf2f((u16)(u.y & 0xffffu)); ev[3] = bf2f((u16)(u.y >> 16));
    } else {
      const float4 f = *(const float4*)((const float*)ebd + (size_t)e * 64 + d0);
      ev[0] = f.x; ev[1] = f.y; ev[2] = f.z; ev[3] = f.w;
    }
    const float4 hv = *(const float4*)(hn0 + (size_t)sn * 64 + d0);
    ushort4 o;
    o.x = f2bf(ev[0] + hv.x); o.y = f2bf(ev[1] + hv.y);
    o.z = f2bf(ev[2] + hv.z); o.w = f2bf(ev[3] + hv.w);
    *(ushort4*)(Ub + (size_t)e * 64 + d0) = o;
  } else {
    const int id = (b - 8192) * 256 + t;   // < 262144
    const int n = id >> 4, o = id & 15;
    const float* row = hn0 + (size_t)n * 64;
    const float* wp = wc + o * 64;
    float acc = 0.f;
    for (int k = 0; k < 64; k += 4){
      const float4 r4 = *(const float4*)(row + k);
      const float4 w4 = *(const float4*)(wp + k);
      acc += r4.x*w4.x + r4.y*w4.y + r4.z*w4.z + r4.w*w4.w;
    }
    an[id] = acc;
  }
}

// AN2 tiled: 64 nodes/block, WC2 staged in LDS; HNA is bf16
__global__ __launch_bounds__(256) void anw_k(const u16* __restrict__ HNA, const float* __restrict__ wc,
                                             float* __restrict__ an){
  __shared__ float W[16][516];
  const int t = threadIdx.x;
  for (int i = t; i < 8192; i += 256) W[i >> 9][i & 511] = wc[i];
  __syncthreads();
  const int node = blockIdx.x * 64 + (t >> 2);
  const int cb0 = (t & 3) * 4;
  const u16* row = HNA + (size_t)node * 512;
  float acc[4] = {0.f, 0.f, 0.f, 0.f};
  for (int k = 0; k < 512; k += 4){
    const uint2 u = *(const uint2*)(row + k);
    const float r0 = bf2f((u16)(u.x & 0xffffu)), r1 = bf2f((u16)(u.x >> 16));
    const float r2 = bf2f((u16)(u.y & 0xffffu)), r3 = bf2f((u16)(u.y >> 16));
    #pragma unroll
    for (int j = 0; j < 4; j++){
      const float* wr = &W[cb0 + j][k];
      acc[j] += r0 * wr[0] + r1 * wr[1] + r2 * wr[2] + r3 * wr[3];
    }
  }
  #pragma unroll
  for (int j = 0; j < 4; j++) an[node * 16 + cb0 + j] = acc[j];
}

// score1: layer-1 raw scores via MFMA — S[pos][h] = leaky(AN1 + ebd.WE1)
__global__ __launch_bounds__(256) void score1_k(const void* __restrict__ ebd, const u16* __restrict__ we1b,
                                                const float* __restrict__ an, const int* __restrict__ src,
                                                const int* __restrict__ dst, const int* __restrict__ cidx,
                                                float* __restrict__ S, const int* __restrict__ flagp){
  __shared__ int Se[64], De[64], Ee[64];
  const int t = threadIdx.x;
  const int w = t >> 6, lane = t & 63;
  const int col = lane & 15, quad = lane >> 4;
  const int p0 = blockIdx.x * 64;
  if (t < 64){ const int e = cidx[p0 + t]; Ee[t] = e; Se[t] = src[e]; De[t] = dst[e]; }
  __syncthreads();
  const int fl = *flagp;
  const int ea = Ee[w*16 + col];
  bf16x8 a0, a1;
  if (fl){
    const u16* ap = (const u16*)ebd + (size_t)ea * 64;
    a0 = *(const bf16x8*)(ap + quad*8);
    a1 = *(const bf16x8*)(ap + 32 + quad*8);
  } else {
    const float* ap = (const float*)ebd + (size_t)ea * 64;
    union { u32 w_[4]; bf16x8 v; } u0, u1;
    #pragma unroll
    for (int i = 0; i < 4; i++){
      u0.w_[i] = pkbf(ap[quad*8 + 2*i],      ap[quad*8 + 2*i + 1]);
      u1.w_[i] = pkbf(ap[32 + quad*8 + 2*i], ap[32 + quad*8 + 2*i + 1]);
    }
    a0 = u0.v; a1 = u1.v;
  }
  const u16* brow = we1b + (size_t)col * 64;
  const bf16x8 b0 = *(const bf16x8*)(brow + quad*8);
  const bf16x8 b1 = *(const bf16x8*)(brow + 32 + quad*8);
  f32x4 acc = (f32x4){0.f, 0.f, 0.f, 0.f};
  acc = __builtin_amdgcn_mfma_f32_16x16x32_bf16(a0, b0, acc, 0, 0, 0);
  acc = __builtin_amdgcn_mfma_f32_16x16x32_bf16(a1, b1, acc, 0, 0, 0);
  if (col < 8){
    #pragma unroll
    for (int i = 0; i < 4; i++){
      const int rl = w*16 + quad*4 + i;
      S[(size_t)(p0 + rl) * 8 + col] = leaky(an[Se[rl]*16 + col] + acc[i] + an[De[rl]*16 + 8 + col]);
    }
  }
}

// layer-1 segment softmax -> alpha. One WAVE per node; lanes = (edge-slot i0,
// head h): coalesced S reads, shfl_xor(8/16/32) segment reduce.
__global__ __launch_bounds__(256) void segalpha_pos_k(const float* __restrict__ S, const int* __restrict__ rp,
                                                      float* __restrict__ AL){
  const int node = blockIdx.x * 4 + (threadIdx.x >> 6);
  const int l = threadIdx.x & 63;
  const int h = l & 7, i0 = l >> 3;
  const int beg = rp[node], end = rp[node + 1];
  float m = -1e30f, z = 0.f;
  for (int base = beg; base < end; base += 8){
    const int idx = base + i0;
    float v = -1e30f, cc = 0.f;
    if (idx < end){ v = S[(size_t)idx * 8 + h]; cc = 1.f; }
    lse_merge(m, z, v, cc);
  }
  #pragma unroll
  for (int off = 8; off < 64; off <<= 1){
    float om = __shfl_xor(m, off), oz = __shfl_xor(z, off);
    lse_merge(m, z, om, oz);
  }
  const float rz = 1.f / fmaxf(z, 1e-9f);
  for (int base = beg; base < end; base += 8){
    const int idx = base + i0;
    if (idx < end)
      AL[(size_t)idx * 8 + h] = __expf(S[(size_t)idx * 8 + h] - m) * rz;
  }
}

// g1 — block per node; alphas by pos; bf16 output
__global__ __launch_bounds__(256) void g1b_k(const float* __restrict__ AL, const u16* __restrict__ Ub,
                                             const int* __restrict__ rp, const int* __restrict__ cidx,
                                             u16* __restrict__ G1b){
  const int n = blockIdx.x;
  const int t = threadIdx.x;
  const int d = t & 63, hh = t >> 6;
  const int beg = rp[n], end = rp[n + 1];
  float a0 = 0.f, a1 = 0.f;
  for (int idx = beg; idx < end; idx++){
    const int e = cidx[idx];
    const float uv = bf2f(Ub[(size_t)e * 64 + d]);
    a0 = fmaf(AL[(size_t)idx * 8 + hh],     uv, a0);
    a1 = fmaf(AL[(size_t)idx * 8 + hh + 4], uv, a1);
  }
  G1b[(size_t)(n * 8 + hh)     * 64 + d] = f2bf(a0);
  G1b[(size_t)(n * 8 + hh + 4) * 64 + d] = f2bf(a1);
}

// nft1 MFMA — HNA stored bf16
__global__ __launch_bounds__(256) void nft1m_k(const u16* __restrict__ G1b, const u16* __restrict__ W1T,
                                               u16* __restrict__ HNA){
  const int t = threadIdx.x;
  const int w = t >> 6, lane = t & 63;
  const int col = lane & 15, quad = lane >> 4;
  const int h = blockIdx.y;
  const int nl0 = blockIdx.x * 32;
  const int mt = (w & 1) * 16;
  const int nb = (w >> 1) * 2;
  const u16* arow = G1b + ((size_t)(nl0 + mt + col) * 8 + h) * 64;
  const bf16x8 a0 = *(const bf16x8*)(arow + quad*8);
  const bf16x8 a1 = *(const bf16x8*)(arow + 32 + quad*8);
  #pragma unroll
  for (int nn = 0; nn < 2; nn++){
    const int nt = nb + nn;
    const u16* brow = W1T + (size_t)(h*64 + nt*16 + col) * 64;
    const bf16x8 b0 = *(const bf16x8*)(brow + quad*8);
    const bf16x8 b1 = *(const bf16x8*)(brow + 32 + quad*8);
    f32x4 acc = (f32x4){0.f, 0.f, 0.f, 0.f};
    acc = __builtin_amdgcn_mfma_f32_16x16x32_bf16(a0, b0, acc, 0, 0, 0);
    acc = __builtin_amdgcn_mfma_f32_16x16x32_bf16(a1, b1, acc, 0, 0, 0);
    #pragma unroll
    for (int i = 0; i < 4; i++)
      HNA[(size_t)(nl0 + mt + quad*4 + i) * 512 + h*64 + nt*16 + col] = f2bf(eluf(acc[i]));
  }
}

// y3: pure-MFMA Y build — PAIR version (32768 edges per dispatch, grid 1024)
__global__ __launch_bounds__(256) void y3_k(const u16* __restrict__ Ub, const float* __restrict__ AL1,
                                            const u16* __restrict__ HNA, const u16* __restrict__ W1T,
                                            const int* __restrict__ src, const int* __restrict__ cidx,
                                            u16* __restrict__ Y, const int s2){
  __shared__ __align__(16) u16 Us[32][72];
  __shared__ float als[256];
  __shared__ int Es[32], Ss[32];
  const int t = threadIdx.x;
  const int w = t >> 6, lane = t & 63;
  const int col = lane & 15, quad = lane >> 4;
  const int mw = (w & 1) * 16;
  const int hw = (w >> 1) * 4;
  const int ep0 = s2 * 32768 + blockIdx.x * 32;
  if (t < 32){ const int e = cidx[ep0 + t]; Es[t] = e; Ss[t] = src[e]; }
  als[t] = AL1[(size_t)ep0 * 8 + t];
  __syncthreads();
  {
    const int r = t >> 3, seg = (t & 7) * 8;
    *(ushort4*)&Us[r][seg]     = *(const ushort4*)(Ub + (size_t)Es[r] * 64 + seg);
    *(ushort4*)&Us[r][seg + 4] = *(const ushort4*)(Ub + (size_t)Es[r] * 64 + seg + 4);
  }
  __syncthreads();
  const bf16x8 a0 = *(const bf16x8*)&Us[mw + col][quad*8];
  const bf16x8 a1 = *(const bf16x8*)&Us[mw + col][32 + quad*8];
  #pragma unroll
  for (int hh = 0; hh < 4; hh++){
    const int h = hw + hh;
    #pragma unroll
    for (int nt = 0; nt < 4; nt++){
      const u16* brow = W1T + (size_t)(h*64 + nt*16 + col) * 64;
      const bf16x8 b0 = *(const bf16x8*)(brow + quad*8);
      const bf16x8 b1 = *(const bf16x8*)(brow + 32 + quad*8);
      f32x4 acc = (f32x4){0.f, 0.f, 0.f, 0.f};
      acc = __builtin_amdgcn_mfma_f32_16x16x32_bf16(a0, b0, acc, 0, 0, 0);
      acc = __builtin_amdgcn_mfma_f32_16x16x32_bf16(a1, b1, acc, 0, 0, 0);
      #pragma unroll
      for (int i = 0; i < 4; i++){
        const int er = mw + quad*4 + i;
        const float v = eluf(als[er*8 + h] * acc[i])
                      + bf2f(HNA[(size_t)Ss[er] * 512 + h*64 + nt*16 + col]);
        Y[(size_t)(blockIdx.x*32 + er) * 512 + h*64 + nt*16 + col] = f2bf(v);
      }
    }
  }
}

// score2: layer-2 raw scores via MFMA — PAIR version (grid 512)
__global__ __launch_bounds__(256) void score2_k(const u16* __restrict__ Y, const u16* __restrict__ we2b,
                                                const float* __restrict__ AN2, const int* __restrict__ src,
                                                const int* __restrict__ dst, const int* __restrict__ cidx,
                                                float* __restrict__ SA, const int s2){
  __shared__ int Se[64], De[64];
  const int t = threadIdx.x;
  const int w = t >> 6, lane = t & 63;
  const int col = lane & 15, quad = lane >> 4;
  const int p0 = blockIdx.x * 64;            // local row in pair buffer
  const int gbase = s2 * 32768;
  if (t < 64){ const int e = cidx[gbase + p0 + t]; Se[t] = src[e]; De[t] = dst[e]; }
  __syncthreads();
  const u16* arow = Y + (size_t)(p0 + w*16 + col) * 512;
  const u16* brow = we2b + (size_t)col * 512;
  f32x4 acc = (f32x4){0.f, 0.f, 0.f, 0.f};
  #pragma unroll
  for (int ks = 0; ks < 16; ks++){
    const bf16x8 a = *(const bf16x8*)(arow + ks*32 + quad*8);
    const bf16x8 b = *(const bf16x8*)(brow + ks*32 + quad*8);
    acc = __builtin_amdgcn_mfma_f32_16x16x32_bf16(a, b, acc, 0, 0, 0);
  }
  if (col < 8){
    #pragma unroll
    for (int i = 0; i < 4; i++){
      const int rl = w*16 + quad*4 + i;
      const size_t pos = gbase + p0 + rl;
      SA[pos * 8 + col] = leaky(AN2[Se[rl]*16 + col] + acc[i] + AN2[De[rl]*16 + 8 + col]);
    }
  }
}

// sg2: softmax (from SA) + aggregation, block per node; Y indexed in pair buf
__global__ __launch_bounds__(256) void sg2_k(const u16* __restrict__ Y, const int* __restrict__ rp,
                                             const float* __restrict__ SA, u16* __restrict__ G2,
                                             const int s){
  __shared__ float sc[64][8];
  __shared__ float mh[8], rzh[8];
  const int t = threadIdx.x;
  const int nl = blockIdx.x;
  const int n = s * 2048 + nl;
  const int beg = rp[n], end = rp[n + 1], m = end - beg;
  const int base = (s >> 1) * 32768;         // pair-buffer global-pos base
  const bool small = (m <= 64);
  {
    const int h = t >> 5, l32 = t & 31;
    float mm = -1e30f, zz = 0.f;
    for (int i = l32; i < m; i += 32)
      lse_merge(mm, zz, SA[(size_t)(beg + i) * 8 + h], 1.f);
    #pragma unroll
    for (int off = 1; off < 32; off <<= 1){
      const float om = __shfl_xor(mm, off), oz = __shfl_xor(zz, off);
      lse_merge(mm, zz, om, oz);
    }
    if (l32 == 0){ mh[h] = mm; rzh[h] = 1.f / fmaxf(zz, 1e-9f); }
  }
  __syncthreads();
  if (small){
    for (int idx = t; idx < m * 8; idx += 256){
      const int i = idx >> 3, h = idx & 7;
      sc[i][h] = __expf(SA[(size_t)(beg + i) * 8 + h] - mh[h]) * rzh[h];
    }
  }
  __syncthreads();
  {
    const int d0 = t * 2;
    float ac[8][2] = {{0.f}};
    for (int i = 0; i < m; i++){
      const int epl = beg + i - base;
      const u32 yv = *(const u32*)(Y + (size_t)epl * 512 + d0);
      const float y0 = bf2f((u16)(yv & 0xffffu)), y1 = bf2f((u16)(yv >> 16));
      float al[8];
      if (small){
        #pragma unroll
        for (int h = 0; h < 8; h++) al[h] = sc[i][h];
      } else {
        #pragma unroll
        for (int h = 0; h < 8; h++)
          al[h] = __expf(SA[(size_t)(beg + i) * 8 + h] - mh[h]) * rzh[h];
      }
      #pragma unroll
      for (int h = 0; h < 8; h++){
        ac[h][0] = fmaf(al[h], y0, ac[h][0]);
        ac[h][1] = fmaf(al[h], y1, ac[h][1]);
      }
    }
    #pragma unroll
    for (int h = 0; h < 8; h++){
      const u32 o = (u32)f2bf(ac[h][0]) | ((u32)f2bf(ac[h][1]) << 16);
      *(u32*)(G2 + ((size_t)nl * 8 + h) * 512 + d0) = o;
    }
  }
}

// nft2 MFMA
__global__ __launch_bounds__(256) void nft2m_k(const u16* __restrict__ G2, const u16* __restrict__ W2T,
                                               u16* __restrict__ HNB, const int s){
  const int t = threadIdx.x;
  const int w = t >> 6, lane = t & 63;
  const int col = lane & 15, quad = lane >> 4;
  const int h = blockIdx.y;
  const int nl0 = blockIdx.x * 32;
  const int mt = (w & 1) * 16;
  const int nb = (w >> 1) * 2;
  const u16* arow = G2 + ((size_t)((nl0 + mt + col) * 8) + h) * 512;
  #pragma unroll
  for (int nn = 0; nn < 2; nn++){
    const int nt = nb + nn;
    const u16* brow = W2T + (size_t)(h*64 + nt*16 + col) * 512;
    f32x4 acc = (f32x4){0.f, 0.f, 0.f, 0.f};
    #pragma unroll
    for (int ks = 0; ks < 16; ks++){
      const bf16x8 a = *(const bf16x8*)(arow + ks*32 + quad*8);
      const bf16x8 b = *(const bf16x8*)(brow + ks*32 + quad*8);
      acc = __builtin_amdgcn_mfma_f32_16x16x32_bf16(a, b, acc, 0, 0, 0);
    }
    #pragma unroll
    for (int i = 0; i < 4; i++)
      HNB[(size_t)(s*2048 + nl0 + mt + quad*4 + i) * 512 + h*64 + nt*16 + col] = f2bf(eluf(acc[i]));
  }
}

// ---------------------------------- CSR -------------------------------------
__global__ __launch_bounds__(256) void hist_k(const int* __restrict__ dst, int* __restrict__ deg){
  const int e = blockIdx.x * 256 + threadIdx.x;
  if (e < NEd) atomicAdd(&deg[dst[e]], 1);
}
// parallel prefix: per-thread chunk sum -> shfl_up wave scan -> wave combine
__global__ __launch_bounds__(256) void scan_k(const int* __restrict__ deg, int* __restrict__ rp,
                                              int* __restrict__ fill){
  __shared__ int wsum[4];
  const int t = threadIdx.x;
  const int lane = t & 63, wid = t >> 6;
  const int base = t * 64;
  int s = 0;
  for (int i = 0; i < 64; i++) s += deg[base + i];
  int v = s;
  #pragma unroll
  for (int off = 1; off < 64; off <<= 1){
    const int u = __shfl_up(v, off);
    if (lane >= off) v += u;
  }
  if (lane == 63) wsum[wid] = v;
  __syncthreads();
  int add = 0;
  #pragma unroll
  for (int wq = 0; wq < 4; wq++) if (wq < wid) add += wsum[wq];
  int off0 = add + v - s;   // exclusive prefix for this thread's 64-chunk
  for (int i = 0; i < 64; i++){
    rp[base + i] = off0; fill[base + i] = off0;
    off0 += deg[base + i];
  }
  if (t == 255) rp[NNd] = off0;
}
__global__ __launch_bounds__(256) void scatter_k(const int* __restrict__ dst, int* __restrict__ fill,
                                                 int* __restrict__ cidx){
  const int e = blockIdx.x * 256 + threadIdx.x;
  if (e < NEd){
    int pos = atomicAdd(&fill[dst[e]], 1);
    cidx[pos] = e;
  }
}

// ------------------------------- readout ------------------------------------
// mean via atomics: 256 blocks (sg x 8 chunks of 64 rows); xcat pre-zeroed
__global__ __launch_bounds__(256) void mean_k(const u16* __restrict__ HNB, float* __restrict__ xcat){
  const int sg = blockIdx.x >> 3, chunk = blockIdx.x & 7;
  const int t = threadIdx.x;
  const int g = (sg < 16) ? sg : sg - 16;
  const int half = (sg < 16) ? 0 : 1;
  const int c0 = t * 2;
  float s0 = 0.f, s1 = 0.f;
  const u16* base = HNB + ((size_t)sg * 512 + chunk * 64) * 512;
  for (int n = 0; n < 64; n++){
    const u32 u = *(const u32*)(base + (size_t)n * 512 + c0);
    s0 += bf2f((u16)(u & 0xffffu));
    s1 += bf2f((u16)(u >> 16));
  }
  atomicAdd(&xcat[g * 1024 + half * 512 + c0],     s0 * (1.f / 512.f));
  atomicAdd(&xcat[g * 1024 + half * 512 + c0 + 1], s1 * (1.f / 512.f));
}

// FC1 with BN1 fused (per-block recomputed column stats; xcat stays raw means)
__global__ __launch_bounds__(256) void fc1_k(const float* __restrict__ xcat, const float* __restrict__ wf,
                                             float* __restrict__ y1g){
  __shared__ float xs[1024];
  __shared__ float ps[4][64];
  const int t = threadIdx.x, g = blockIdx.x;
  for (int j = t; j < 1024; j += 256){
    float mu = 0.f;
    #pragma unroll
    for (int gg = 0; gg < 16; gg++) mu += xcat[gg * 1024 + j];
    mu *= (1.f / 16.f);
    float var = 0.f;
    #pragma unroll
    for (int gg = 0; gg < 16; gg++){ const float d = xcat[gg * 1024 + j] - mu; var += d * d; }
    var *= (1.f / 16.f);
    const float sc = rsqrtf(var + 1e-5f) * wf[WO_B1G + j];
    xs[j] = (xcat[g * 1024 + j] - mu) * sc + wf[WO_B1B + j];
  }
  __syncthreads();
  const int c = t & 63, kq = t >> 6;
  float acc = 0.f;
  #pragma unroll 4
  for (int k = kq * 256; k < kq * 256 + 256; k++)
    acc = fmaf(xs[k], wf[WO_F1W + k * 64 + c], acc);
  ps[kq][c] = acc;
  __syncthreads();
  if (t < 64){
    const float a = ps[0][t] + ps[1][t] + ps[2][t] + ps[3][t] + wf[WO_F1B + t];
    y1g[g * 64 + t] = fmaxf(a, 0.f);
  }
}

// BN2 + FC2 tail (tiny)
__global__ __launch_bounds__(256) void head2_k(const float* __restrict__ y1g, const float* __restrict__ wf,
                                               void* __restrict__ outp, const int* __restrict__ flagp){
  __shared__ float y1s[16][64];
  __shared__ float mu2s[64], sc2s[64];
  const int t = threadIdx.x;
  for (int i = t; i < 1024; i += 256) y1s[i >> 6][i & 63] = y1g[i];
  __syncthreads();
  if (t < 64){
    float mu = 0.f;
    #pragma unroll
    for (int g = 0; g < 16; g++) mu += y1s[g][t];
    mu *= (1.f / 16.f);
    float var = 0.f;
    #pragma unroll
    for (int g = 0; g < 16; g++){ const float d = y1s[g][t] - mu; var += d * d; }
    var *= (1.f / 16.f);
    mu2s[t] = mu; sc2s[t] = rsqrtf(var + 1e-5f) * wf[WO_B2G + t];
  }
  __syncthreads();
  if (t < 48){
    const int gg = t / 3, c = t % 3;
    float acc = wf[WO_F2B + c];
    #pragma unroll
    for (int k = 0; k < 64; k++){
      const float y2 = (y1s[gg][k] - mu2s[k]) * sc2s[k] + wf[WO_B2B + k];
      acc = fmaf(y2, wf[WO_F2W + k * 3 + c], acc);
    }
    if (*flagp) ((u16*)outp)[t] = f2bf(acc);
    else        ((float*)outp)[t] = acc;
  }
}

// --------------------------------- launch -----------------------------------
extern "C" void kernel_launch(void* const* d_in, const int* in_sizes, int n_in,
                              void* d_out, int out_size, void* d_ws, size_t ws_size,
                              hipStream_t stream) {
  (void)in_sizes; (void)n_in; (void)out_size;
  if (ws_size < WS_NEED) return;

  const int* src = (const int*)d_in[3];
  const int* dst = (const int*)d_in[4];
  char* w = (char*)d_ws;

  float* wf   = (float*)(w + OFF_WF);
  float* cb   = (float*)(w + OFF_CB);
  u16*   Ub   = (u16*)(w + OFF_U);
  u16*   W1T  = (u16*)(w + OFF_W1B);
  u16*   W2T  = (u16*)(w + OFF_W2B);
  u16*   we2b = (u16*)(w + OFF_WE2B);
  u16*   we1b = (u16*)(w + OFF_WE1B);
  u16*   pwt  = (u16*)(w + OFF_PWT);
  float* AL1  = (float*)(w + OFF_AL1);
  float* SA   = (float*)(w + OFF_SA);
  u16*   HNA  = (u16*)(w + OFF_HNA);
  float* AN2  = (float*)(w + OFF_AN2);
  int*   deg  = (int*)(w + OFF_DEG);
  int*   rp   = (int*)(w + OFF_RP);
  int*   fill = (int*)(w + OFF_FILL);
  int*   cidx = (int*)(w + OFF_CIDX);
  float* rbig = (float*)(w + OFF_RBIG);
  float* xcat = (float*)(w + OFF_XCAT);
  int*   flag = (int*)(w + OFF_FLAG);

  float* x1a  = (float*)(w + OFF_T + T_X1A);
  float* x2a  = (float*)(w + OFF_T + T_X2A);
  float* hn0  = (float*)(w + OFF_T + T_HN0);
  float* AN1  = (float*)(w + OFF_T + T_AN1);
  float* S    = (float*)(w + OFF_T + T_S);
  u16*   Y    = (u16*)(w + OFF_T + T_Y);       // pair buffer, 32768 rows
  float* y1g  = (float*)(w + OFF_T + T_Y1G);   // readout scratch (after slices)

  float* pacc = rbig;                           // 2 x 16.78MB = full RBIG during flash
  float* pz   = (float*)(w + OFF_T + T_PZ);     // 2 x 256KB in hn0 slot during flash
  u16*   G1b  = (u16*)(w + OFF_RBIG);
  u16*   HNB  = (u16*)(w + OFF_RBIG);           // [0, 16.78MB)
  u16*   G2   = (u16*)(w + OFF_RBIG + R_G2);    // [16.78, 33.55MB)

  // 0. detect + weights + combos
  detect_k<<<1, 256, 0, stream>>>((const u16*)d_in[0], flag);
  P17 ps;
  for (int i = 0; i < 17; i++) ps.p[i] = d_in[6 + i];
  convw_k<<<(WO_END + 255) / 256, 256, 0, stream>>>(ps, wf, flag);
  wprep_k<<<(294912 + 18432 + 16384 + 255) / 256, 256, 0, stream>>>(wf, W1T, W2T, cb, we2b, we1b, pwt);

  // 1. CSR over dst
  hipMemsetAsync(deg, 0, NNd * sizeof(int), stream);
  hist_k<<<NEd / 256, 256, 0, stream>>>(dst, deg);
  scan_k<<<1, 256, 0, stream>>>(deg, rp, fill);
  scatter_k<<<NEd / 256, 256, 0, stream>>>(dst, fill, cidx);

  // 2. alignment: BOTH directions in one dispatch (z = dir), one merged merge
  flash_mfma_k<<<dim3(64, KSPLIT, 2), 256, 0, stream>>>(d_in[0], d_in[1], flag, pacc, pz);
  flash_merge_k<<<dim3(NSd / 4, 2), 256, 0, stream>>>(pacc, pz, x1a, x2a);

  // 3. projection (MFMA)
  projm_k<<<NNd / 64, 256, 0, stream>>>(d_in[0], d_in[1], x1a, x2a, pwt, hn0, flag);

  // 4. GAT layer 1 (usan merge; MFMA scores; wave-softmax; g1 aggregation)
  usan_k<<<8192 + 1024, 256, 0, stream>>>(d_in[2], hn0, src, Ub, cb + CB_WC1, AN1, flag);
  score1_k<<<NEd / 64, 256, 0, stream>>>(d_in[2], we1b, AN1, src, dst, cidx, S, flag);
  segalpha_pos_k<<<NNd / 4, 256, 0, stream>>>(S, rp, AL1);
  g1b_k<<<NNd, 256, 0, stream>>>(AL1, Ub, rp, cidx, G1b);
  nft1m_k<<<dim3(NNd / 32, 8), 256, 0, stream>>>(G1b, W1T, HNA);

  // 5. layer-2 per-node combos (+ hoisted xcat clear)
  anw_k<<<NNd / 64, 256, 0, stream>>>(HNA, cb + CB_WC2, AN2);
  hipMemsetAsync(xcat, 0, 16 * 1024 * sizeof(float), stream);

  // 6. layer-2: 4 slice-pairs x (y3, score2) + per-slice (sg2, nft2m)
  for (int s2 = 0; s2 < 4; s2++){
    y3_k<<<1024, 256, 0, stream>>>(Ub, AL1, HNA, W1T, src, cidx, Y, s2);
    score2_k<<<512, 256, 0, stream>>>(Y, we2b, AN2, src, dst, cidx, SA, s2);
    for (int sub = 0; sub < 2; sub++){
      const int s = s2 * 2 + sub;
      sg2_k<<<2048, 256, 0, stream>>>(Y, rp, SA, G2, s);
      nft2m_k<<<dim3(64, 8), 256, 0, stream>>>(G2, W2T, HNB, s);
    }
  }

  // 7. readout (mean via atomics -> fused BN1+FC1 -> BN2+FC2)
  mean_k<<<256, 256, 0, stream>>>(HNB, xcat);
  fc1_k<<<16, 256, 0, stream>>>(xcat, wf, y1g);
  head2_k<<<1, 256, 0, stream>>>(y1g, wf, d_out, flag);
}